// Round 1
// baseline (1416.207 us; speedup 1.0000x reference)
//
#include <hip/hip_runtime.h>

#define EPS 1e-5f

// ---------------- block reduction (256 threads = 4 waves) ----------------
__device__ __forceinline__ float block_sum(float v, float* tmp) {
#pragma unroll
  for (int off = 32; off > 0; off >>= 1) v += __shfl_down(v, off);
  __syncthreads();
  if ((threadIdx.x & 63) == 0) tmp[threadIdx.x >> 6] = v;
  __syncthreads();
  return tmp[0] + tmp[1] + tmp[2] + tmp[3];
}

// ---------------- GEMM: C(MxN) = A(MxK) * B(NxK)^T, optional bias+silu ----------------
// tile 64x64, K-chunk 16, 256 threads, 4x4 per thread
template <int SILU, int BIAS>
__global__ __launch_bounds__(256) void gemm_abt(
    const float* __restrict__ A, const float* __restrict__ B,
    const float* __restrict__ bias, float* __restrict__ C,
    int M, int N, int K, float scale) {
  __shared__ float As[64][17];
  __shared__ float Bs[64][17];
  const int tid = threadIdx.x;
  const int bn = blockIdx.x << 6, bm = blockIdx.y << 6;
  const int tx = tid & 15, ty = tid >> 4;
  const int lr = tid >> 2, lc = (tid & 3) << 2;
  const float* Ap = A + (size_t)(bm + lr) * K + lc;
  const float* Bp = B + (size_t)(bn + lr) * K + lc;
  float acc[4][4] = {};
  for (int k0 = 0; k0 < K; k0 += 16) {
    float4 av = *(const float4*)(Ap + k0);
    float4 bv = *(const float4*)(Bp + k0);
    __syncthreads();
    As[lr][lc] = av.x; As[lr][lc + 1] = av.y; As[lr][lc + 2] = av.z; As[lr][lc + 3] = av.w;
    Bs[lr][lc] = bv.x; Bs[lr][lc + 1] = bv.y; Bs[lr][lc + 2] = bv.z; Bs[lr][lc + 3] = bv.w;
    __syncthreads();
#pragma unroll
    for (int kk = 0; kk < 16; ++kk) {
      float a[4], b[4];
#pragma unroll
      for (int i = 0; i < 4; ++i) a[i] = As[(ty << 2) + i][kk];
#pragma unroll
      for (int j = 0; j < 4; ++j) b[j] = Bs[(tx << 2) + j][kk];
#pragma unroll
      for (int i = 0; i < 4; ++i)
#pragma unroll
        for (int j = 0; j < 4; ++j) acc[i][j] += a[i] * b[j];
    }
  }
#pragma unroll
  for (int i = 0; i < 4; ++i) {
    int m = bm + (ty << 2) + i;
#pragma unroll
    for (int j = 0; j < 4; ++j) {
      int n = bn + (tx << 2) + j;
      float c = acc[i][j] * scale;
      if (BIAS) c += bias[n];
      if (SILU) c = c / (1.f + __expf(-c));
      C[(size_t)m * N + n] = c;
    }
  }
}

// ---------------- batched GEMM: C(MxN) = A(MxK) * B(KxN), per-z strides ----------------
__global__ __launch_bounds__(256) void gemm_ab_bat(
    const float* __restrict__ A, const float* __restrict__ B, float* __restrict__ C,
    int M, int N, int K, long sA, long sB, long sC) {
  __shared__ float As[64][17];
  __shared__ float Bs[16][65];
  const int z = blockIdx.z;
  const float* Az = A + (size_t)z * sA;
  const float* Bz = B + (size_t)z * sB;
  float* Cz = C + (size_t)z * sC;
  const int tid = threadIdx.x;
  const int bn = blockIdx.x << 6, bm = blockIdx.y << 6;
  const int tx = tid & 15, ty = tid >> 4;
  const int lr = tid >> 2, lc = (tid & 3) << 2;   // A-tile load coords
  const int br = tid >> 4, bc = (tid & 15) << 2;  // B-tile load coords
  float acc[4][4] = {};
  for (int k0 = 0; k0 < K; k0 += 16) {
    float4 av = *(const float4*)(Az + (size_t)(bm + lr) * K + k0 + lc);
    float4 bv = *(const float4*)(Bz + (size_t)(k0 + br) * N + bn + bc);
    __syncthreads();
    As[lr][lc] = av.x; As[lr][lc + 1] = av.y; As[lr][lc + 2] = av.z; As[lr][lc + 3] = av.w;
    Bs[br][bc] = bv.x; Bs[br][bc + 1] = bv.y; Bs[br][bc + 2] = bv.z; Bs[br][bc + 3] = bv.w;
    __syncthreads();
#pragma unroll
    for (int kk = 0; kk < 16; ++kk) {
      float a[4], b[4];
#pragma unroll
      for (int i = 0; i < 4; ++i) a[i] = As[(ty << 2) + i][kk];
#pragma unroll
      for (int j = 0; j < 4; ++j) b[j] = Bs[kk][(tx << 2) + j];
#pragma unroll
      for (int i = 0; i < 4; ++i)
#pragma unroll
        for (int j = 0; j < 4; ++j) acc[i][j] += a[i] * b[j];
    }
  }
#pragma unroll
  for (int i = 0; i < 4; ++i) {
    int m = bm + (ty << 2) + i;
#pragma unroll
    for (int j = 0; j < 4; ++j) {
      int n = bn + (tx << 2) + j;
      Cz[(size_t)m * N + n] = acc[i][j];
    }
  }
}

// ---------------- LayerNorm over rows = concat(X1row[L1], X2row[L2]) ----------------
__global__ __launch_bounds__(256) void ln_rows(
    const float* __restrict__ X1, const float* __restrict__ X2, int L1, int L2,
    const float* __restrict__ g, const float* __restrict__ bta, float* __restrict__ Y) {
  __shared__ float tmp[4];
  const int row = blockIdx.x;
  const int L = L1 + L2;
  const float* x1 = X1 + (size_t)row * L1;
  const float* x2 = X2 ? X2 + (size_t)row * L2 : nullptr;
  float s = 0.f, ss = 0.f;
  for (int i = threadIdx.x * 4; i < L1; i += 1024) {
    float4 v = *(const float4*)(x1 + i);
    s += v.x + v.y + v.z + v.w;
    ss += v.x * v.x + v.y * v.y + v.z * v.z + v.w * v.w;
  }
  for (int i = threadIdx.x * 4; i < L2; i += 1024) {
    float4 v = *(const float4*)(x2 + i);
    s += v.x + v.y + v.z + v.w;
    ss += v.x * v.x + v.y * v.y + v.z * v.z + v.w * v.w;
  }
  s = block_sum(s, tmp);
  ss = block_sum(ss, tmp);
  const float mu = s / (float)L;
  const float inv = rsqrtf(ss / (float)L - mu * mu + EPS);
  float* y = Y + (size_t)row * L;
  for (int i = threadIdx.x * 4; i < L1; i += 1024) {
    float4 v = *(const float4*)(x1 + i);
    float4 gv = *(const float4*)(g + i);
    float4 bv = *(const float4*)(bta + i);
    float4 o;
    o.x = (v.x - mu) * inv * gv.x + bv.x;
    o.y = (v.y - mu) * inv * gv.y + bv.y;
    o.z = (v.z - mu) * inv * gv.z + bv.z;
    o.w = (v.w - mu) * inv * gv.w + bv.w;
    *(float4*)(y + i) = o;
  }
  for (int i = threadIdx.x * 4; i < L2; i += 1024) {
    float4 v = *(const float4*)(x2 + i);
    float4 gv = *(const float4*)(g + L1 + i);
    float4 bv = *(const float4*)(bta + L1 + i);
    float4 o;
    o.x = (v.x - mu) * inv * gv.x + bv.x;
    o.y = (v.y - mu) * inv * gv.y + bv.y;
    o.z = (v.z - mu) * inv * gv.z + bv.z;
    o.w = (v.w - mu) * inv * gv.w + bv.w;
    *(float4*)(y + L1 + i) = o;
  }
}

// ---------------- QW[b,k,h,c] = sum_d Q[b,k,h,d] * kW[h*64+d, c] ----------------
__global__ __launch_bounds__(256) void qw_kernel(
    const float* __restrict__ Q, const float* __restrict__ kW, float* __restrict__ QW) {
  __shared__ float q[256];
  const int bk = blockIdx.x;
  q[threadIdx.x] = Q[(size_t)bk * 256 + threadIdx.x];
  __syncthreads();
  const int c = threadIdx.x;
#pragma unroll
  for (int h = 0; h < 4; ++h) {
    float s = 0.f;
#pragma unroll 8
    for (int d = 0; d < 64; ++d)
      s += q[(h << 6) + d] * kW[(size_t)(((h << 6) + d) << 8) + c];
    QW[((size_t)(bk * 4 + h) << 8) + c] = s;
  }
}

// ---------------- conv3x3 4->4 + bias + silu ----------------
__global__ __launch_bounds__(256) void conv1_k(
    const float* __restrict__ X, const float* __restrict__ W,
    const float* __restrict__ Bi, float* __restrict__ Y) {
  __shared__ float w[144];
  const int img = blockIdx.x;
  if (threadIdx.x < 144) w[threadIdx.x] = W[threadIdx.x];
  __syncthreads();
  const float* x = X + (size_t)img * 16384;
  float* y = Y + (size_t)img * 16384;
  const float b0 = Bi[0], b1 = Bi[1], b2 = Bi[2], b3 = Bi[3];
  for (int p = threadIdx.x; p < 4096; p += 256) {
    const int py = p >> 6, px = p & 63;
    float a0 = b0, a1 = b1, a2 = b2, a3 = b3;
#pragma unroll
    for (int ci = 0; ci < 4; ++ci) {
      const float* xc = x + (ci << 12);
#pragma unroll
      for (int dy = -1; dy <= 1; ++dy) {
        const int yy = py + dy;
        if ((unsigned)yy > 63u) continue;
#pragma unroll
        for (int dx = -1; dx <= 1; ++dx) {
          const int xx = px + dx;
          if ((unsigned)xx > 63u) continue;
          const float v = xc[(yy << 6) + xx];
          const int wi = ci * 9 + (dy + 1) * 3 + (dx + 1);
          a0 += w[wi] * v;
          a1 += w[36 + wi] * v;
          a2 += w[72 + wi] * v;
          a3 += w[108 + wi] * v;
        }
      }
    }
    a0 = a0 / (1.f + __expf(-a0));
    a1 = a1 / (1.f + __expf(-a1));
    a2 = a2 / (1.f + __expf(-a2));
    a3 = a3 / (1.f + __expf(-a3));
    y[p] = a0; y[4096 + p] = a1; y[8192 + p] = a2; y[12288 + p] = a3;
  }
}

// ---------------- conv3x3 4->1 + bias ----------------
__global__ __launch_bounds__(256) void conv2_k(
    const float* __restrict__ X, const float* __restrict__ W,
    const float* __restrict__ Bi, float* __restrict__ Y) {
  __shared__ float w[36];
  const int img = blockIdx.x;
  if (threadIdx.x < 36) w[threadIdx.x] = W[threadIdx.x];
  __syncthreads();
  const float* x = X + (size_t)img * 16384;
  float* y = Y + (size_t)img * 4096;
  const float b0 = Bi[0];
  for (int p = threadIdx.x; p < 4096; p += 256) {
    const int py = p >> 6, px = p & 63;
    float a = b0;
#pragma unroll
    for (int ci = 0; ci < 4; ++ci) {
      const float* xc = x + (ci << 12);
#pragma unroll
      for (int dy = -1; dy <= 1; ++dy) {
        const int yy = py + dy;
        if ((unsigned)yy > 63u) continue;
#pragma unroll
        for (int dx = -1; dx <= 1; ++dx) {
          const int xx = px + dx;
          if ((unsigned)xx > 63u) continue;
          a += w[ci * 9 + (dy + 1) * 3 + (dx + 1)] * xc[(yy << 6) + xx];
        }
      }
    }
    y[p] = a;
  }
}

// ---------------- bilinear 64->256, half-pixel centers, edge clamp ----------------
__global__ __launch_bounds__(256) void upsample_k(
    const float* __restrict__ X, float* __restrict__ O) {
  const int total = 16777216;  // 256 imgs * 256 * 256
  for (int idx = blockIdx.x * 256 + threadIdx.x; idx < total; idx += gridDim.x * 256) {
    const int img = idx >> 16;
    const int p = idx & 65535;
    const int oy = p >> 8, ox = p & 255;
    const float sy = oy * 0.25f - 0.375f;
    const float sx = ox * 0.25f - 0.375f;
    int y0 = (int)floorf(sy); const float wy = sy - y0;
    int x0 = (int)floorf(sx); const float wx = sx - x0;
    const int y1 = min(y0 + 1, 63); y0 = max(y0, 0);
    const int x1 = min(x0 + 1, 63); x0 = max(x0, 0);
    const float* xi = X + ((size_t)img << 12);
    const float v00 = xi[(y0 << 6) + x0], v01 = xi[(y0 << 6) + x1];
    const float v10 = xi[(y1 << 6) + x0], v11 = xi[(y1 << 6) + x1];
    const float v0 = v00 + wx * (v01 - v00);
    const float v1 = v10 + wx * (v11 - v10);
    O[idx] = v0 + wy * (v1 - v0);
  }
}

// ---------------- confidence: out[row] = dot(cfh_row, w2) + b2 ----------------
__global__ __launch_bounds__(256) void conf_k(
    const float* __restrict__ cfh, const float* __restrict__ w2,
    const float* __restrict__ b2, float* __restrict__ out) {
  __shared__ float tmp[4];
  const int row = blockIdx.x;
  float s = 0.f;
  for (int i = threadIdx.x; i < 2048; i += 256)
    s += cfh[(size_t)row * 2048 + i] * w2[i];
  s = block_sum(s, tmp);
  if (threadIdx.x == 0) out[row] = s + b2[0];
}

extern "C" void kernel_launch(void* const* d_in, const int* in_sizes, int n_in,
                              void* d_out, int out_size, void* d_ws, size_t ws_size,
                              hipStream_t stream) {
  const float* img    = (const float*)d_in[0];   // (8,256,64,64)
  const float* refv   = (const float*)d_in[1];   // (8,32,4096)
  const float* qs     = (const float*)d_in[2];   // (8,32,512)
  const float* qpw    = (const float*)d_in[3];   // (256,4096)
  const float* kpw    = (const float*)d_in[4];   // (256,256)
  const float* fw1    = (const float*)d_in[5];   // (4,4,3,3)
  const float* fb1    = (const float*)d_in[6];   // (4)
  const float* fw2    = (const float*)d_in[7];   // (1,4,3,3)
  const float* fb2    = (const float*)d_in[8];   // (1)
  const float* qbw    = (const float*)d_in[9];   // (4096,512)
  const float* rlg    = (const float*)d_in[10];  // (8192)
  const float* rlb    = (const float*)d_in[11];  // (8192)
  const float* rlw    = (const float*)d_in[12];  // (4096,8192)
  const float* rlbias = (const float*)d_in[13];  // (4096)
  const float* clg    = (const float*)d_in[14];  // (4096)
  const float* clb    = (const float*)d_in[15];  // (4096)
  const float* cw1    = (const float*)d_in[16];  // (2048,4096)
  const float* cb1    = (const float*)d_in[17];  // (2048)
  const float* cw2    = (const float*)d_in[18];  // (1,2048)
  const float* cb2    = (const float*)d_in[19];  // (1)
  float* out = (float*)d_out;
  float* ws = (float*)d_ws;

  // workspace layout (floats); regions reused once their producer/consumer pair is done
  float* qb    = ws + 0;        // 256x4096   (dead after ln_cat)
  float* lnfus = ws + 0;        // 256x4096   (reuses qb)
  float* catln = ws + 1048576;  // 256x8192   (dead after fused gemm)
  float* lg64  = ws + 1048576;  // 256x4096   (reuses catln lower half)
  float* cfh   = ws + 2097152;  // 256x2048   (reuses catln upper half)
  float* fus   = ws + 3145728;  // 256x4096
  float* Qb    = ws + 4194304;  // 256x256
  float* QW    = ws + 4259840;  // 256x4x256
  float* l64h  = ws + 4521984;  // 256x4x4096
  float* mid   = ws + 8716288;  // 256x4x4096

  dim3 b256(256);

  // 1. qb = querybook_slots @ qb_proj_w^T          (256,4096,K=512)
  gemm_abt<0, 0><<<dim3(64, 4), b256, 0, stream>>>(qs, qbw, nullptr, qb, 256, 4096, 512, 1.f);
  // 2. catln = LN(concat(ref_vec, qb))             rows of 8192
  ln_rows<<<dim3(256), b256, 0, stream>>>(refv, qb, 4096, 4096, rlg, rlb, catln);
  // 3. fused = silu(catln @ rf_lin_w^T + b)        (256,4096,K=8192)
  gemm_abt<1, 1><<<dim3(64, 4), b256, 0, stream>>>(catln, rlw, rlbias, fus, 256, 4096, 8192, 1.f);
  // 4. Q = fused @ q_proj_w^T, scaled by 1/sqrt(DH)=1/8
  gemm_abt<0, 0><<<dim3(4, 4), b256, 0, stream>>>(fus, qpw, nullptr, Qb, 256, 256, 4096, 0.125f);
  // 5. QW = per-head Q @ k_proj (folds Kmap away)
  qw_kernel<<<dim3(256), b256, 0, stream>>>(Qb, kpw, QW);
  // 6. logits64h[b] = QW_b(128x256) @ img_b(256x4096)
  gemm_ab_bat<<<dim3(64, 2, 8), b256, 0, stream>>>(QW, img, l64h, 128, 4096, 256,
                                                   32768L, 1048576L, 524288L);
  // 7. mid = silu(conv3x3(l64h, fw1) + fb1)
  conv1_k<<<dim3(256), b256, 0, stream>>>(l64h, fw1, fb1, mid);
  // 8. lg64 = conv3x3(mid, fw2) + fb2
  conv2_k<<<dim3(256), b256, 0, stream>>>(mid, fw2, fb2, lg64);
  // 9. out[0:16777216] = bilinear upsample 64->256
  upsample_k<<<dim3(4096), b256, 0, stream>>>(lg64, out);
  // 10. lnfus = LN(fused)
  ln_rows<<<dim3(256), b256, 0, stream>>>(fus, nullptr, 4096, 0, clg, clb, lnfus);
  // 11. cfh = silu(lnfus @ cf_w1^T + cf_b1)        (256,2048,K=4096)
  gemm_abt<1, 1><<<dim3(32, 4), b256, 0, stream>>>(lnfus, cw1, cb1, cfh, 256, 2048, 4096, 1.f);
  // 12. out[16777216:+256] = cfh @ cf_w2 + cf_b2
  conf_k<<<dim3(256), b256, 0, stream>>>(cfh, cw2, cb2, out + 16777216);
}

// Round 2
// 251.823 us; speedup vs baseline: 5.6238x; 5.6238x over previous
//
#include <hip/hip_runtime.h>

#define EPS 1e-5f

typedef __bf16 bf16_t;
typedef __bf16 bf16x8 __attribute__((ext_vector_type(8)));
typedef __bf16 bf16x4 __attribute__((ext_vector_type(4)));
typedef float f32x4 __attribute__((ext_vector_type(4)));

__device__ __forceinline__ float silu_f(float x) { return x / (1.f + __expf(-x)); }

// ---------------- block reduction (256 threads = 4 waves) ----------------
__device__ __forceinline__ float block_sum(float v, float* tmp) {
#pragma unroll
  for (int off = 32; off > 0; off >>= 1) v += __shfl_down(v, off);
  __syncthreads();
  if ((threadIdx.x & 63) == 0) tmp[threadIdx.x >> 6] = v;
  __syncthreads();
  return tmp[0] + tmp[1] + tmp[2] + tmp[3];
}

// ============================================================================
// MFMA GEMM: C(M,N) = A(M,K) * B(N,K)^T   (ABT, K contiguous in both operands)
// AF32/BF32: operand dtype (1=f32 converted inline, 0=bf16 read direct)
// OUTMODE: 0 = f32 split-K partial (Cpart + s*M*N), 1 = f32 direct, 2 = bf16 direct
// block = 256 threads (4 waves), tile 64x64, K-step 64, wave tile 32x32
// ============================================================================
template <int AF32, int BF32, int OUTMODE>
__global__ __launch_bounds__(256) void gemm_mfma(
    const void* __restrict__ Av, const void* __restrict__ Bv, void* __restrict__ Cv,
    int M, int N, int K, int KS, int S,
    long sAb, long sBb, long sCb) {
  __shared__ bf16_t As[64][72];  // 144B rows: 16B-aligned, ~2-way banks
  __shared__ bf16_t Bs[64][72];
  const int t = threadIdx.x;
  const int lane = t & 63;
  const int w = t >> 6;
  const int z = blockIdx.z;
  const int s = z % S;
  const int b = z / S;
  const int n0 = blockIdx.x * 64;
  const int m0 = blockIdx.y * 64;
  const int kbeg = s * KS;

  const float* A32 = (const float*)Av;
  const bf16_t* A16 = (const bf16_t*)Av;
  const float* B32 = (const float*)Bv;
  const bf16_t* B16 = (const bf16_t*)Bv;
  const size_t aoff = (size_t)b * sAb;
  const size_t boff = (size_t)b * sBb;

  f32x4 acc[2][2];
#pragma unroll
  for (int i = 0; i < 2; ++i)
#pragma unroll
    for (int j = 0; j < 2; ++j) acc[i][j] = f32x4{0.f, 0.f, 0.f, 0.f};

  const int wm = (w & 1) * 32, wn = (w >> 1) * 32;
  const int fr = lane & 15;          // fragment row within 16
  const int kq = (lane >> 4) * 8;    // fragment k-offset

  for (int k0 = kbeg; k0 < kbeg + KS; k0 += 64) {
    // ---- issue global loads into regs (overlaps previous compute) ----
    float4 a4[4], b4[4];
    bf16x8 a8[2], b8[2];
    if constexpr (AF32) {
      const int r = t >> 4, c4 = (t & 15) * 4;
#pragma unroll
      for (int i = 0; i < 4; ++i)
        a4[i] = *(const float4*)(A32 + aoff + (size_t)(m0 + r + 16 * i) * K + k0 + c4);
    } else {
      const int r = t >> 2, c8 = (t & 3) * 8;
#pragma unroll
      for (int i = 0; i < 2; ++i)
        a8[i] = *(const bf16x8*)(A16 + aoff + (size_t)(m0 + r) * K + k0 + c8 + 32 * i);
    }
    if constexpr (BF32) {
      const int r = t >> 4, c4 = (t & 15) * 4;
#pragma unroll
      for (int i = 0; i < 4; ++i)
        b4[i] = *(const float4*)(B32 + boff + (size_t)(n0 + r + 16 * i) * K + k0 + c4);
    } else {
      const int r = t >> 2, c8 = (t & 3) * 8;
#pragma unroll
      for (int i = 0; i < 2; ++i)
        b8[i] = *(const bf16x8*)(B16 + boff + (size_t)(n0 + r) * K + k0 + c8 + 32 * i);
    }
    __syncthreads();
    if constexpr (AF32) {
      const int r = t >> 4, c4 = (t & 15) * 4;
#pragma unroll
      for (int i = 0; i < 4; ++i) {
        bf16x4 v = {(bf16_t)a4[i].x, (bf16_t)a4[i].y, (bf16_t)a4[i].z, (bf16_t)a4[i].w};
        *(bf16x4*)&As[r + 16 * i][c4] = v;
      }
    } else {
      const int r = t >> 2, c8 = (t & 3) * 8;
#pragma unroll
      for (int i = 0; i < 2; ++i) *(bf16x8*)&As[r][c8 + 32 * i] = a8[i];
    }
    if constexpr (BF32) {
      const int r = t >> 4, c4 = (t & 15) * 4;
#pragma unroll
      for (int i = 0; i < 4; ++i) {
        bf16x4 v = {(bf16_t)b4[i].x, (bf16_t)b4[i].y, (bf16_t)b4[i].z, (bf16_t)b4[i].w};
        *(bf16x4*)&Bs[r + 16 * i][c4] = v;
      }
    } else {
      const int r = t >> 2, c8 = (t & 3) * 8;
#pragma unroll
      for (int i = 0; i < 2; ++i) *(bf16x8*)&Bs[r][c8 + 32 * i] = b8[i];
    }
    __syncthreads();
#pragma unroll
    for (int kk = 0; kk < 64; kk += 32) {
      bf16x8 af[2], bfr[2];
#pragma unroll
      for (int i = 0; i < 2; ++i) {
        af[i] = *(const bf16x8*)&As[wm + 16 * i + fr][kk + kq];
        bfr[i] = *(const bf16x8*)&Bs[wn + 16 * i + fr][kk + kq];
      }
#pragma unroll
      for (int i = 0; i < 2; ++i)
#pragma unroll
        for (int j = 0; j < 2; ++j)
          acc[i][j] = __builtin_amdgcn_mfma_f32_16x16x32_bf16(af[i], bfr[j], acc[i][j], 0, 0, 0);
    }
  }

  // ---- epilogue: D[m][n], m = (lane>>4)*4 + r, n = lane&15 ----
  const int row_hi = (lane >> 4) * 4;
  const int col = lane & 15;
#pragma unroll
  for (int i = 0; i < 2; ++i)
#pragma unroll
    for (int j = 0; j < 2; ++j)
#pragma unroll
      for (int r = 0; r < 4; ++r) {
        const size_t m = m0 + wm + 16 * i + row_hi + r;
        const size_t n = n0 + wn + 16 * j + col;
        if constexpr (OUTMODE == 0) {
          ((float*)Cv)[(size_t)s * M * N + m * N + n] = acc[i][j][r];
        } else if constexpr (OUTMODE == 1) {
          ((float*)Cv)[(size_t)b * sCb + m * N + n] = acc[i][j][r];
        } else {
          ((bf16_t*)Cv)[(size_t)b * sCb + m * N + n] = (bf16_t)acc[i][j][r];
        }
      }
}

// ---------------- split-K reduce + bias + silu epilogue ----------------
template <int SILU_, int BIAS_>
__global__ __launch_bounds__(256) void reduce_k(
    const float* __restrict__ part, int S, long slice,
    const float* __restrict__ bias, float scale,
    float* __restrict__ outF, bf16_t* __restrict__ outB,
    int nmask, long total4) {
  long i4 = (long)blockIdx.x * 256 + threadIdx.x;
  if (i4 >= total4) return;
  long i = i4 * 4;
  float4 v = *(const float4*)(part + i);
  for (int s = 1; s < S; ++s) {
    float4 u = *(const float4*)(part + (size_t)s * slice + i);
    v.x += u.x; v.y += u.y; v.z += u.z; v.w += u.w;
  }
  v.x *= scale; v.y *= scale; v.z *= scale; v.w *= scale;
  if (BIAS_) {
    float4 bb = *(const float4*)(bias + (i & nmask));
    v.x += bb.x; v.y += bb.y; v.z += bb.z; v.w += bb.w;
  }
  if (SILU_) { v.x = silu_f(v.x); v.y = silu_f(v.y); v.z = silu_f(v.z); v.w = silu_f(v.w); }
  if (outF) *(float4*)(outF + i) = v;
  if (outB) {
    bf16x4 o = {(bf16_t)v.x, (bf16_t)v.y, (bf16_t)v.z, (bf16_t)v.w};
    *(bf16x4*)(outB + i) = o;
  }
}

// ---------------- LayerNorm over rows = concat(X1[L1], X2[L2]) -> bf16 ----------------
__global__ __launch_bounds__(256) void ln_rows(
    const float* __restrict__ X1, const float* __restrict__ X2, int L1, int L2,
    const float* __restrict__ g, const float* __restrict__ bta, bf16_t* __restrict__ Y) {
  __shared__ float tmp[4];
  const int row = blockIdx.x;
  const int L = L1 + L2;
  const float* x1 = X1 + (size_t)row * L1;
  const float* x2 = X2 ? X2 + (size_t)row * L2 : nullptr;
  float s = 0.f, ss = 0.f;
  for (int i = threadIdx.x * 4; i < L1; i += 1024) {
    float4 v = *(const float4*)(x1 + i);
    s += v.x + v.y + v.z + v.w;
    ss += v.x * v.x + v.y * v.y + v.z * v.z + v.w * v.w;
  }
  for (int i = threadIdx.x * 4; i < L2; i += 1024) {
    float4 v = *(const float4*)(x2 + i);
    s += v.x + v.y + v.z + v.w;
    ss += v.x * v.x + v.y * v.y + v.z * v.z + v.w * v.w;
  }
  s = block_sum(s, tmp);
  ss = block_sum(ss, tmp);
  const float mu = s / (float)L;
  const float inv = rsqrtf(ss / (float)L - mu * mu + EPS);
  bf16_t* y = Y + (size_t)row * L;
  for (int i = threadIdx.x * 4; i < L1; i += 1024) {
    float4 v = *(const float4*)(x1 + i);
    float4 gv = *(const float4*)(g + i);
    float4 bv = *(const float4*)(bta + i);
    bf16x4 o = {(bf16_t)((v.x - mu) * inv * gv.x + bv.x),
                (bf16_t)((v.y - mu) * inv * gv.y + bv.y),
                (bf16_t)((v.z - mu) * inv * gv.z + bv.z),
                (bf16_t)((v.w - mu) * inv * gv.w + bv.w)};
    *(bf16x4*)(y + i) = o;
  }
  for (int i = threadIdx.x * 4; i < L2; i += 1024) {
    float4 v = *(const float4*)(x2 + i);
    float4 gv = *(const float4*)(g + L1 + i);
    float4 bv = *(const float4*)(bta + L1 + i);
    bf16x4 o = {(bf16_t)((v.x - mu) * inv * gv.x + bv.x),
                (bf16_t)((v.y - mu) * inv * gv.y + bv.y),
                (bf16_t)((v.z - mu) * inv * gv.z + bv.z),
                (bf16_t)((v.w - mu) * inv * gv.w + bv.w)};
    *(bf16x4*)(y + L1 + i) = o;
  }
}

// ---------------- transpose img (8,256,4096) f32 -> imgT (8,4096,256) bf16 ----------------
__global__ __launch_bounds__(256) void transpose_k(
    const float* __restrict__ X, bf16_t* __restrict__ Y) {
  __shared__ bf16_t Ts[64][66];  // 132B rows (33 dwords, odd) -> ~2-way banks
  const int t = threadIdx.x;
  const int p0 = blockIdx.x * 64, c0 = blockIdx.y * 64, b = blockIdx.z;
  const float* Xb = X + (size_t)b * 1048576;
  const int cl = t >> 6, p = t & 63;
#pragma unroll
  for (int i = 0; i < 16; ++i) {
    int c = cl + i * 4;
    Ts[c][p] = (bf16_t)Xb[(size_t)(c0 + c) * 4096 + p0 + p];
  }
  __syncthreads();
  const int pl = t >> 2, cq = (t & 3) * 16;
  bf16_t* Yb = Y + (size_t)b * 1048576 + (size_t)(p0 + pl) * 256 + c0 + cq;
  bf16x8 o0, o1;
#pragma unroll
  for (int j = 0; j < 8; ++j) o0[j] = Ts[cq + j][pl];
#pragma unroll
  for (int j = 0; j < 8; ++j) o1[j] = Ts[cq + 8 + j][pl];
  *(bf16x8*)(Yb) = o0;
  *(bf16x8*)(Yb + 8) = o1;
}

// ---------------- QW[bk,h,c] = sum_d Q[bk,h*64+d] * kW[h*64+d, c] ----------------
__global__ __launch_bounds__(256) void qw_kernel(
    const float* __restrict__ Q, const float* __restrict__ kW, float* __restrict__ QW) {
  __shared__ float q[256];
  const int bk = blockIdx.x;
  q[threadIdx.x] = Q[(size_t)bk * 256 + threadIdx.x];
  __syncthreads();
  const int c = threadIdx.x;
#pragma unroll
  for (int h = 0; h < 4; ++h) {
    float s = 0.f;
#pragma unroll 8
    for (int d = 0; d < 64; ++d)
      s += q[(h << 6) + d] * kW[(size_t)(((h << 6) + d) << 8) + c];
    QW[((size_t)(bk * 4 + h) << 8) + c] = s;
  }
}

// ---------------- conv3x3 4->4 + bias + silu (per image, 4x4 patch/thread) ----------------
__global__ __launch_bounds__(256) void conv1_k(
    const bf16_t* __restrict__ X, const float* __restrict__ W,
    const float* __restrict__ Bi, bf16_t* __restrict__ Y) {
  __shared__ bf16_t lg[16384];
  __shared__ float wsh[144];
  const int t = threadIdx.x;
  const size_t base = (size_t)blockIdx.x * 16384;
#pragma unroll
  for (int i = 0; i < 8; ++i) {
    int o = (i * 256 + t) * 8;
    *(bf16x8*)&lg[o] = *(const bf16x8*)(X + base + o);
  }
  if (t < 144) wsh[t] = W[t];
  __syncthreads();
  const int px0 = (t & 15) * 4, py0 = (t >> 4) * 4;
  float acc[4][16];
#pragma unroll
  for (int oc = 0; oc < 4; ++oc) {
    float bb = Bi[oc];
#pragma unroll
    for (int p = 0; p < 16; ++p) acc[oc][p] = bb;
  }
#pragma unroll
  for (int c = 0; c < 4; ++c) {
    float p[6][6];
#pragma unroll
    for (int yy = 0; yy < 6; ++yy) {
      int gy = py0 + yy - 1;
#pragma unroll
      for (int xx = 0; xx < 6; ++xx) {
        int gx = px0 + xx - 1;
        p[yy][xx] = ((unsigned)gy < 64u && (unsigned)gx < 64u)
                        ? (float)lg[c * 4096 + gy * 64 + gx] : 0.f;
      }
    }
#pragma unroll
    for (int oc = 0; oc < 4; ++oc) {
      float wr[9];
#pragma unroll
      for (int k = 0; k < 9; ++k) wr[k] = wsh[oc * 36 + c * 9 + k];
#pragma unroll
      for (int y = 0; y < 4; ++y)
#pragma unroll
        for (int x = 0; x < 4; ++x) {
          float a = acc[oc][y * 4 + x];
          a += wr[0] * p[y][x] + wr[1] * p[y][x + 1] + wr[2] * p[y][x + 2]
             + wr[3] * p[y + 1][x] + wr[4] * p[y + 1][x + 1] + wr[5] * p[y + 1][x + 2]
             + wr[6] * p[y + 2][x] + wr[7] * p[y + 2][x + 1] + wr[8] * p[y + 2][x + 2];
          acc[oc][y * 4 + x] = a;
        }
    }
  }
#pragma unroll
  for (int oc = 0; oc < 4; ++oc)
#pragma unroll
    for (int y = 0; y < 4; ++y) {
      bf16x4 o;
#pragma unroll
      for (int x = 0; x < 4; ++x) o[x] = (bf16_t)silu_f(acc[oc][y * 4 + x]);
      *(bf16x4*)(Y + base + oc * 4096 + (py0 + y) * 64 + px0) = o;
    }
}

// ---------------- conv3x3 4->1 + bias, then bilinear 64->256 upsample ----------------
__global__ __launch_bounds__(256) void conv2up_k(
    const bf16_t* __restrict__ X, const float* __restrict__ W,
    const float* __restrict__ Bi, float* __restrict__ O) {
  __shared__ bf16_t md[16384];
  __shared__ float lg64[4096];
  __shared__ float wsh[36];
  const int t = threadIdx.x;
  const size_t base = (size_t)blockIdx.x * 16384;
#pragma unroll
  for (int i = 0; i < 8; ++i) {
    int o = (i * 256 + t) * 8;
    *(bf16x8*)&md[o] = *(const bf16x8*)(X + base + o);
  }
  if (t < 36) wsh[t] = W[t];
  __syncthreads();
  const int px0 = (t & 15) * 4, py0 = (t >> 4) * 4;
  float acc[16];
  {
    float bb = Bi[0];
#pragma unroll
    for (int p = 0; p < 16; ++p) acc[p] = bb;
  }
#pragma unroll
  for (int c = 0; c < 4; ++c) {
    float p[6][6];
#pragma unroll
    for (int yy = 0; yy < 6; ++yy) {
      int gy = py0 + yy - 1;
#pragma unroll
      for (int xx = 0; xx < 6; ++xx) {
        int gx = px0 + xx - 1;
        p[yy][xx] = ((unsigned)gy < 64u && (unsigned)gx < 64u)
                        ? (float)md[c * 4096 + gy * 64 + gx] : 0.f;
      }
    }
    float wr[9];
#pragma unroll
    for (int k = 0; k < 9; ++k) wr[k] = wsh[c * 9 + k];
#pragma unroll
    for (int y = 0; y < 4; ++y)
#pragma unroll
      for (int x = 0; x < 4; ++x)
        acc[y * 4 + x] += wr[0] * p[y][x] + wr[1] * p[y][x + 1] + wr[2] * p[y][x + 2]
                        + wr[3] * p[y + 1][x] + wr[4] * p[y + 1][x + 1] + wr[5] * p[y + 1][x + 2]
                        + wr[6] * p[y + 2][x] + wr[7] * p[y + 2][x + 1] + wr[8] * p[y + 2][x + 2];
  }
#pragma unroll
  for (int y = 0; y < 4; ++y)
#pragma unroll
    for (int x = 0; x < 4; ++x) lg64[(py0 + y) * 64 + px0 + x] = acc[y * 4 + x];
  __syncthreads();
  // bilinear upsample 64 -> 256 (half-pixel centers, edge clamp)
  float* Ob = O + (size_t)blockIdx.x * 65536;
  for (int rr = 0; rr < 64; ++rr) {
    int p4 = rr * 256 + t;
    int oy = p4 >> 6, ox0 = (p4 & 63) * 4;
    float sy = oy * 0.25f - 0.375f;
    int y0 = (int)floorf(sy);
    float wy = sy - (float)y0;
    int y1 = min(y0 + 1, 63); y0 = max(y0, 0);
    const float* r0 = &lg64[y0 * 64];
    const float* r1 = &lg64[y1 * 64];
    float4 o;
#pragma unroll
    for (int q = 0; q < 4; ++q) {
      int ox = ox0 + q;
      float sx = ox * 0.25f - 0.375f;
      int x0 = (int)floorf(sx);
      float wx = sx - (float)x0;
      int x1 = min(x0 + 1, 63); x0 = max(x0, 0);
      float v0 = r0[x0] + wx * (r0[x1] - r0[x0]);
      float v1 = r1[x0] + wx * (r1[x1] - r1[x0]);
      ((float*)&o)[q] = v0 + wy * (v1 - v0);
    }
    *(float4*)(Ob + oy * 256 + ox0) = o;
  }
}

// ---------------- confidence: out[row] = dot(cfh_row, w2) + b2 ----------------
__global__ __launch_bounds__(256) void conf_k(
    const float* __restrict__ cfh, const float* __restrict__ w2,
    const float* __restrict__ b2, float* __restrict__ out) {
  __shared__ float tmp[4];
  const int row = blockIdx.x;
  float s = 0.f;
  for (int i = threadIdx.x; i < 2048; i += 256)
    s += cfh[(size_t)row * 2048 + i] * w2[i];
  s = block_sum(s, tmp);
  if (threadIdx.x == 0) out[row] = s + b2[0];
}

extern "C" void kernel_launch(void* const* d_in, const int* in_sizes, int n_in,
                              void* d_out, int out_size, void* d_ws, size_t ws_size,
                              hipStream_t stream) {
  const float* img    = (const float*)d_in[0];   // (8,256,64,64)
  const float* refv   = (const float*)d_in[1];   // (8,32,4096)
  const float* qs     = (const float*)d_in[2];   // (8,32,512)
  const float* qpw    = (const float*)d_in[3];   // (256,4096)
  const float* kpw    = (const float*)d_in[4];   // (256,256)
  const float* fw1    = (const float*)d_in[5];   // (4,4,3,3)
  const float* fb1    = (const float*)d_in[6];   // (4)
  const float* fw2    = (const float*)d_in[7];   // (1,4,3,3)
  const float* fb2    = (const float*)d_in[8];   // (1)
  const float* qbw    = (const float*)d_in[9];   // (4096,512)
  const float* rlg    = (const float*)d_in[10];  // (8192)
  const float* rlb    = (const float*)d_in[11];  // (8192)
  const float* rlw    = (const float*)d_in[12];  // (4096,8192)
  const float* rlbias = (const float*)d_in[13];  // (4096)
  const float* clg    = (const float*)d_in[14];  // (4096)
  const float* clb    = (const float*)d_in[15];  // (4096)
  const float* cw1    = (const float*)d_in[16];  // (2048,4096)
  const float* cb1    = (const float*)d_in[17];  // (2048)
  const float* cw2    = (const float*)d_in[18];  // (1,2048)
  const float* cb2    = (const float*)d_in[19];  // (1)
  float* out = (float*)d_out;
  char* W = (char*)d_ws;

  // workspace layout (bytes), regions reused after producer/consumer pairs finish
  bf16_t* imgT  = (bf16_t*)(W + 0);          // 16.78 MB  (dead after logits gemm)
  float*  qb    = (float*)(W + 16777216);    // 4.19 MB   (dead after ln cat)
  float*  part8 = (float*)(W + 16777216);    // 2.10 MB   (reuses qb)
  float*  Qb    = (float*)(W + 18874368);    // 0.26 MB
  float*  QW    = (float*)(W + 19136512);    // 1.05 MB
  bf16_t* catln = (bf16_t*)(W + 20971520);   // 4.19 MB   (dead after fused gemm)
  bf16_t* lnf   = (bf16_t*)(W + 20971520);   // 2.10 MB   (reuses catln)
  float*  part4 = (float*)(W + 25165824);    // 16.78 MB  (dead after fused reduce)
  bf16_t* l64hb = (bf16_t*)(W + 25165824);   // 8.39 MB   (reuses part4)
  bf16_t* midb  = (bf16_t*)(W + 33554432);   // 8.39 MB   (reuses part4 tail)
  float*  fus   = (float*)(W + 41943040);    // 4.19 MB
  bf16_t* fusb  = (bf16_t*)(W + 46137344);   // 2.10 MB
  float*  part2 = (float*)(W + 0);           // 4.19 MB   (reuses imgT)
  float*  cfh   = (float*)(W + 4194304);     // 2.10 MB   (reuses imgT)

  dim3 b256(256);

  // 1. imgT = transpose(image_embed) -> (8,4096,256) bf16
  transpose_k<<<dim3(64, 4, 8), b256, 0, stream>>>(img, imgT);
  // 2. qb = querybook_slots @ qb_proj_w^T   (f32 direct out)
  gemm_mfma<1, 1, 1><<<dim3(64, 4, 1), b256, 0, stream>>>(
      qs, qbw, qb, 256, 4096, 512, 512, 1, 0, 0, 0);
  // 3. catln = LN(concat(ref_vec, qb)) -> bf16
  ln_rows<<<dim3(256), b256, 0, stream>>>(refv, qb, 4096, 4096, rlg, rlb, catln);
  // 4. fused GEMM (split-K x4): part4[s] = catln @ rlw^T (chunk)
  gemm_mfma<0, 1, 0><<<dim3(64, 4, 4), b256, 0, stream>>>(
      catln, rlw, part4, 256, 4096, 8192, 2048, 4, 0, 0, 0);
  // 5. fus = silu(sum part4 + bias) -> f32 + bf16
  reduce_k<1, 1><<<dim3(1024), b256, 0, stream>>>(
      part4, 4, 1048576L, rlbias, 1.f, fus, fusb, 4095, 262144L);
  // 6. qproj GEMM (split-K x8): part8[s] = fusb @ qpw^T (chunk)
  gemm_mfma<0, 1, 0><<<dim3(4, 4, 8), b256, 0, stream>>>(
      fusb, qpw, part8, 256, 256, 4096, 512, 8, 0, 0, 0);
  // 7. Qb = 0.125 * sum part8
  reduce_k<0, 0><<<dim3(64), b256, 0, stream>>>(
      part8, 8, 65536L, nullptr, 0.125f, Qb, nullptr, 0, 16384L);
  // 8. QW = per-head Q @ k_proj
  qw_kernel<<<dim3(256), b256, 0, stream>>>(Qb, kpw, QW);
  // 9. logits (batched, bf16 direct out): l64hb[b] = QW_b @ imgT_b^T
  gemm_mfma<1, 0, 2><<<dim3(64, 2, 8), b256, 0, stream>>>(
      QW, imgT, l64hb, 128, 4096, 256, 256, 1, 32768L, 1048576L, 524288L);
  // 10. midb = silu(conv3x3(l64hb, fw1) + fb1)
  conv1_k<<<dim3(256), b256, 0, stream>>>(l64hb, fw1, fb1, midb);
  // 11. lg64 = conv3x3(midb, fw2) + fb2 ; out = bilinear upsample
  conv2up_k<<<dim3(256), b256, 0, stream>>>(midb, fw2, fb2, out);
  // 12. lnf = LN(fus) -> bf16
  ln_rows<<<dim3(256), b256, 0, stream>>>(fus, nullptr, 4096, 0, clg, clb, lnf);
  // 13. cfh GEMM (split-K x2): part2[s] = lnf @ cw1^T (chunk)
  gemm_mfma<0, 1, 0><<<dim3(32, 4, 2), b256, 0, stream>>>(
      lnf, cw1, part2, 256, 2048, 4096, 2048, 2, 0, 0, 0);
  // 14. cfh = silu(sum part2 + cb1)
  reduce_k<1, 1><<<dim3(512), b256, 0, stream>>>(
      part2, 2, 524288L, cb1, 1.f, cfh, nullptr, 2047, 131072L);
  // 15. conf out
  conf_k<<<dim3(256), b256, 0, stream>>>(cfh, cw2, cb2, out + 16777216);
}

// Round 3
// 239.608 us; speedup vs baseline: 5.9105x; 1.0510x over previous
//
#include <hip/hip_runtime.h>

#define EPS 1e-5f

typedef __bf16 bf16_t;
typedef __bf16 bf16x8 __attribute__((ext_vector_type(8)));
typedef __bf16 bf16x4 __attribute__((ext_vector_type(4)));
typedef float f32x4 __attribute__((ext_vector_type(4)));

__device__ __forceinline__ float silu_f(float x) { return x / (1.f + __expf(-x)); }

// ---------------- block reduction (256 threads = 4 waves) ----------------
__device__ __forceinline__ float block_sum(float v, float* tmp) {
#pragma unroll
  for (int off = 32; off > 0; off >>= 1) v += __shfl_down(v, off);
  __syncthreads();
  if ((threadIdx.x & 63) == 0) tmp[threadIdx.x >> 6] = v;
  __syncthreads();
  return tmp[0] + tmp[1] + tmp[2] + tmp[3];
}

// ============================================================================
// gemm_big: Cpart[z] = A(M,K)bf16 * B(N,K)^T f32  -- the fat weight GEMMs.
// tile 128x128, BK=64, 512 threads (8 waves, wave-tile 32x64), double-buffered
// LDS, one barrier per K-step, next-tile global loads issued before MFMA phase.
// Grid: (N/128, M/128, S); each z computes K-chunk [z*KS, (z+1)*KS).
// ============================================================================
__global__ __launch_bounds__(512, 4) void gemm_big(
    const bf16_t* __restrict__ A, const float* __restrict__ B,
    float* __restrict__ Cpart, int M, int N, int K, int KS) {
  __shared__ bf16_t As[2][128][72];  // 144B rows -> frag reads are free 2-way
  __shared__ bf16_t Bs[2][128][72];
  const int t = threadIdx.x;
  const int lane = t & 63;
  const int w = t >> 6;
  const int n0 = blockIdx.x * 128;
  const int m0 = blockIdx.y * 128;
  const int kbeg = blockIdx.z * KS;
  const int r = t >> 2;          // 0..127 (staging row)
  const int cg = (t & 3) * 16;   // staging col group (elements)
  const bf16_t* Ap = A + (size_t)(m0 + r) * K + cg;
  const float* Bp = B + (size_t)(n0 + r) * K + cg;

  bf16x8 a0, a1;
  float4 b0, b1, b2, b3;

  auto LOAD = [&](int k0) {
    a0 = *(const bf16x8*)(Ap + k0);
    a1 = *(const bf16x8*)(Ap + k0 + 8);
    b0 = *(const float4*)(Bp + k0);
    b1 = *(const float4*)(Bp + k0 + 4);
    b2 = *(const float4*)(Bp + k0 + 8);
    b3 = *(const float4*)(Bp + k0 + 12);
  };
  auto STORE = [&](int buf) {
    *(bf16x8*)&As[buf][r][cg] = a0;
    *(bf16x8*)&As[buf][r][cg + 8] = a1;
    bf16x8 w0, w1;
    w0[0] = (bf16_t)b0.x; w0[1] = (bf16_t)b0.y; w0[2] = (bf16_t)b0.z; w0[3] = (bf16_t)b0.w;
    w0[4] = (bf16_t)b1.x; w0[5] = (bf16_t)b1.y; w0[6] = (bf16_t)b1.z; w0[7] = (bf16_t)b1.w;
    w1[0] = (bf16_t)b2.x; w1[1] = (bf16_t)b2.y; w1[2] = (bf16_t)b2.z; w1[3] = (bf16_t)b2.w;
    w1[4] = (bf16_t)b3.x; w1[5] = (bf16_t)b3.y; w1[6] = (bf16_t)b3.z; w1[7] = (bf16_t)b3.w;
    *(bf16x8*)&Bs[buf][r][cg] = w0;
    *(bf16x8*)&Bs[buf][r][cg + 8] = w1;
  };

  f32x4 acc[2][4];
#pragma unroll
  for (int i = 0; i < 2; ++i)
#pragma unroll
    for (int j = 0; j < 4; ++j) acc[i][j] = f32x4{0.f, 0.f, 0.f, 0.f};

  const int wm = (w & 3) * 32;   // 4 wave-rows of 32
  const int wn = (w >> 2) * 64;  // 2 wave-cols of 64
  const int fr = lane & 15;
  const int kq = (lane >> 4) * 8;

  const int nt = KS >> 6;
  LOAD(kbeg);
  STORE(0);
  __syncthreads();
  for (int st = 0; st < nt; ++st) {
    const int cur = st & 1;
    const bool pf = (st + 1 < nt);
    if (pf) LOAD(kbeg + (st + 1) * 64);  // HBM latency overlaps MFMA phase
#pragma unroll
    for (int kk = 0; kk < 64; kk += 32) {
      bf16x8 af[2], bg[4];
#pragma unroll
      for (int i = 0; i < 2; ++i)
        af[i] = *(const bf16x8*)&As[cur][wm + 16 * i + fr][kk + kq];
#pragma unroll
      for (int j = 0; j < 4; ++j)
        bg[j] = *(const bf16x8*)&Bs[cur][wn + 16 * j + fr][kk + kq];
#pragma unroll
      for (int i = 0; i < 2; ++i)
#pragma unroll
        for (int j = 0; j < 4; ++j)
          acc[i][j] = __builtin_amdgcn_mfma_f32_16x16x32_bf16(af[i], bg[j], acc[i][j], 0, 0, 0);
    }
    if (pf) STORE(cur ^ 1);  // writes other buffer; safe pre-barrier
    __syncthreads();
  }

  float* Cz = Cpart + (size_t)blockIdx.z * M * N;
  const int rh = (lane >> 4) * 4, col = lane & 15;
#pragma unroll
  for (int i = 0; i < 2; ++i)
#pragma unroll
    for (int j = 0; j < 4; ++j)
#pragma unroll
      for (int rr = 0; rr < 4; ++rr)
        Cz[(size_t)(m0 + wm + 16 * i + rh + rr) * N + n0 + wn + 16 * j + col] = acc[i][j][rr];
}

// ============================================================================
// generic MFMA GEMM (64x64 tile) for the small GEMMs
// OUTMODE: 0 = f32 split-K partial, 1 = f32 direct, 2 = bf16 direct (batched)
// ============================================================================
template <int AF32, int BF32, int OUTMODE>
__global__ __launch_bounds__(256) void gemm_mfma(
    const void* __restrict__ Av, const void* __restrict__ Bv, void* __restrict__ Cv,
    int M, int N, int K, int KS, int S,
    long sAb, long sBb, long sCb) {
  __shared__ bf16_t As[64][72];
  __shared__ bf16_t Bs[64][72];
  const int t = threadIdx.x;
  const int lane = t & 63;
  const int w = t >> 6;
  const int z = blockIdx.z;
  const int s = z % S;
  const int b = z / S;
  const int n0 = blockIdx.x * 64;
  const int m0 = blockIdx.y * 64;
  const int kbeg = s * KS;

  const float* A32 = (const float*)Av;
  const bf16_t* A16 = (const bf16_t*)Av;
  const float* B32 = (const float*)Bv;
  const bf16_t* B16 = (const bf16_t*)Bv;
  const size_t aoff = (size_t)b * sAb;
  const size_t boff = (size_t)b * sBb;

  f32x4 acc[2][2];
#pragma unroll
  for (int i = 0; i < 2; ++i)
#pragma unroll
    for (int j = 0; j < 2; ++j) acc[i][j] = f32x4{0.f, 0.f, 0.f, 0.f};

  const int wm = (w & 1) * 32, wn = (w >> 1) * 32;
  const int fr = lane & 15;
  const int kq = (lane >> 4) * 8;

  for (int k0 = kbeg; k0 < kbeg + KS; k0 += 64) {
    float4 a4[4], b4[4];
    bf16x8 a8[2], b8[2];
    if constexpr (AF32) {
      const int r = t >> 4, c4 = (t & 15) * 4;
#pragma unroll
      for (int i = 0; i < 4; ++i)
        a4[i] = *(const float4*)(A32 + aoff + (size_t)(m0 + r + 16 * i) * K + k0 + c4);
    } else {
      const int r = t >> 2, c8 = (t & 3) * 8;
#pragma unroll
      for (int i = 0; i < 2; ++i)
        a8[i] = *(const bf16x8*)(A16 + aoff + (size_t)(m0 + r) * K + k0 + c8 + 32 * i);
    }
    if constexpr (BF32) {
      const int r = t >> 4, c4 = (t & 15) * 4;
#pragma unroll
      for (int i = 0; i < 4; ++i)
        b4[i] = *(const float4*)(B32 + boff + (size_t)(n0 + r + 16 * i) * K + k0 + c4);
    } else {
      const int r = t >> 2, c8 = (t & 3) * 8;
#pragma unroll
      for (int i = 0; i < 2; ++i)
        b8[i] = *(const bf16x8*)(B16 + boff + (size_t)(n0 + r) * K + k0 + c8 + 32 * i);
    }
    __syncthreads();
    if constexpr (AF32) {
      const int r = t >> 4, c4 = (t & 15) * 4;
#pragma unroll
      for (int i = 0; i < 4; ++i) {
        bf16x4 v = {(bf16_t)a4[i].x, (bf16_t)a4[i].y, (bf16_t)a4[i].z, (bf16_t)a4[i].w};
        *(bf16x4*)&As[r + 16 * i][c4] = v;
      }
    } else {
      const int r = t >> 2, c8 = (t & 3) * 8;
#pragma unroll
      for (int i = 0; i < 2; ++i) *(bf16x8*)&As[r][c8 + 32 * i] = a8[i];
    }
    if constexpr (BF32) {
      const int r = t >> 4, c4 = (t & 15) * 4;
#pragma unroll
      for (int i = 0; i < 4; ++i) {
        bf16x4 v = {(bf16_t)b4[i].x, (bf16_t)b4[i].y, (bf16_t)b4[i].z, (bf16_t)b4[i].w};
        *(bf16x4*)&Bs[r + 16 * i][c4] = v;
      }
    } else {
      const int r = t >> 2, c8 = (t & 3) * 8;
#pragma unroll
      for (int i = 0; i < 2; ++i) *(bf16x8*)&Bs[r][c8 + 32 * i] = b8[i];
    }
    __syncthreads();
#pragma unroll
    for (int kk = 0; kk < 64; kk += 32) {
      bf16x8 af[2], bg[2];
#pragma unroll
      for (int i = 0; i < 2; ++i) {
        af[i] = *(const bf16x8*)&As[wm + 16 * i + fr][kk + kq];
        bg[i] = *(const bf16x8*)&Bs[wn + 16 * i + fr][kk + kq];
      }
#pragma unroll
      for (int i = 0; i < 2; ++i)
#pragma unroll
        for (int j = 0; j < 2; ++j)
          acc[i][j] = __builtin_amdgcn_mfma_f32_16x16x32_bf16(af[i], bg[j], acc[i][j], 0, 0, 0);
    }
    __syncthreads();
  }

  const int rh = (lane >> 4) * 4;
  const int col = lane & 15;
#pragma unroll
  for (int i = 0; i < 2; ++i)
#pragma unroll
    for (int j = 0; j < 2; ++j)
#pragma unroll
      for (int rr = 0; rr < 4; ++rr) {
        const size_t m = m0 + wm + 16 * i + rh + rr;
        const size_t n = n0 + wn + 16 * j + col;
        if constexpr (OUTMODE == 0) {
          ((float*)Cv)[(size_t)s * M * N + m * N + n] = acc[i][j][rr];
        } else if constexpr (OUTMODE == 1) {
          ((float*)Cv)[(size_t)b * sCb + m * N + n] = acc[i][j][rr];
        } else {
          ((bf16_t*)Cv)[(size_t)b * sCb + m * N + n] = (bf16_t)acc[i][j][rr];
        }
      }
}

// ---------------- split-K reduce + bias + silu epilogue ----------------
template <int SILU_, int BIAS_>
__global__ __launch_bounds__(256) void reduce_k(
    const float* __restrict__ part, int S, long slice,
    const float* __restrict__ bias, float scale,
    float* __restrict__ outF, bf16_t* __restrict__ outB,
    int nmask, long total4) {
  long i4 = (long)blockIdx.x * 256 + threadIdx.x;
  if (i4 >= total4) return;
  long i = i4 * 4;
  float4 v = *(const float4*)(part + i);
  for (int s = 1; s < S; ++s) {
    float4 u = *(const float4*)(part + (size_t)s * slice + i);
    v.x += u.x; v.y += u.y; v.z += u.z; v.w += u.w;
  }
  v.x *= scale; v.y *= scale; v.z *= scale; v.w *= scale;
  if (BIAS_) {
    float4 bb = *(const float4*)(bias + (i & nmask));
    v.x += bb.x; v.y += bb.y; v.z += bb.z; v.w += bb.w;
  }
  if (SILU_) { v.x = silu_f(v.x); v.y = silu_f(v.y); v.z = silu_f(v.z); v.w = silu_f(v.w); }
  if (outF) *(float4*)(outF + i) = v;
  if (outB) {
    bf16x4 o = {(bf16_t)v.x, (bf16_t)v.y, (bf16_t)v.z, (bf16_t)v.w};
    *(bf16x4*)(outB + i) = o;
  }
}

// ---------------- LayerNorm over rows = concat(X1[L1], X2[L2]) -> bf16 ----------------
__global__ __launch_bounds__(256) void ln_rows(
    const float* __restrict__ X1, const float* __restrict__ X2, int L1, int L2,
    const float* __restrict__ g, const float* __restrict__ bta, bf16_t* __restrict__ Y) {
  __shared__ float tmp[4];
  const int row = blockIdx.x;
  const int L = L1 + L2;
  const float* x1 = X1 + (size_t)row * L1;
  const float* x2 = X2 ? X2 + (size_t)row * L2 : nullptr;
  float s = 0.f, ss = 0.f;
  for (int i = threadIdx.x * 4; i < L1; i += 1024) {
    float4 v = *(const float4*)(x1 + i);
    s += v.x + v.y + v.z + v.w;
    ss += v.x * v.x + v.y * v.y + v.z * v.z + v.w * v.w;
  }
  for (int i = threadIdx.x * 4; i < L2; i += 1024) {
    float4 v = *(const float4*)(x2 + i);
    s += v.x + v.y + v.z + v.w;
    ss += v.x * v.x + v.y * v.y + v.z * v.z + v.w * v.w;
  }
  s = block_sum(s, tmp);
  ss = block_sum(ss, tmp);
  const float mu = s / (float)L;
  const float inv = rsqrtf(ss / (float)L - mu * mu + EPS);
  bf16_t* y = Y + (size_t)row * L;
  for (int i = threadIdx.x * 4; i < L1; i += 1024) {
    float4 v = *(const float4*)(x1 + i);
    float4 gv = *(const float4*)(g + i);
    float4 bv = *(const float4*)(bta + i);
    bf16x4 o = {(bf16_t)((v.x - mu) * inv * gv.x + bv.x),
                (bf16_t)((v.y - mu) * inv * gv.y + bv.y),
                (bf16_t)((v.z - mu) * inv * gv.z + bv.z),
                (bf16_t)((v.w - mu) * inv * gv.w + bv.w)};
    *(bf16x4*)(y + i) = o;
  }
  for (int i = threadIdx.x * 4; i < L2; i += 1024) {
    float4 v = *(const float4*)(x2 + i);
    float4 gv = *(const float4*)(g + L1 + i);
    float4 bv = *(const float4*)(bta + L1 + i);
    bf16x4 o = {(bf16_t)((v.x - mu) * inv * gv.x + bv.x),
                (bf16_t)((v.y - mu) * inv * gv.y + bv.y),
                (bf16_t)((v.z - mu) * inv * gv.z + bv.z),
                (bf16_t)((v.w - mu) * inv * gv.w + bv.w)};
    *(bf16x4*)(y + L1 + i) = o;
  }
}

// ---------------- transpose img (8,256,4096) f32 -> imgT (8,4096,256) bf16 ----------------
__global__ __launch_bounds__(256) void transpose_k(
    const float* __restrict__ X, bf16_t* __restrict__ Y) {
  __shared__ bf16_t Ts[64][66];
  const int t = threadIdx.x;
  const int p0 = blockIdx.x * 64, c0 = blockIdx.y * 64, b = blockIdx.z;
  const float* Xb = X + (size_t)b * 1048576;
  const int cl = t >> 6, p = t & 63;
#pragma unroll
  for (int i = 0; i < 16; ++i) {
    int c = cl + i * 4;
    Ts[c][p] = (bf16_t)Xb[(size_t)(c0 + c) * 4096 + p0 + p];
  }
  __syncthreads();
  const int pl = t >> 2, cq = (t & 3) * 16;
  bf16_t* Yb = Y + (size_t)b * 1048576 + (size_t)(p0 + pl) * 256 + c0 + cq;
  bf16x8 o0, o1;
#pragma unroll
  for (int j = 0; j < 8; ++j) o0[j] = Ts[cq + j][pl];
#pragma unroll
  for (int j = 0; j < 8; ++j) o1[j] = Ts[cq + 8 + j][pl];
  *(bf16x8*)(Yb) = o0;
  *(bf16x8*)(Yb + 8) = o1;
}

// ---------------- QW[bk,h,c] = sum_d Q[bk,h*64+d] * kW[h*64+d, c] ----------------
__global__ __launch_bounds__(256) void qw_kernel(
    const float* __restrict__ Q, const float* __restrict__ kW, float* __restrict__ QW) {
  __shared__ float q[256];
  const int bk = blockIdx.x;
  q[threadIdx.x] = Q[(size_t)bk * 256 + threadIdx.x];
  __syncthreads();
  const int c = threadIdx.x;
#pragma unroll
  for (int h = 0; h < 4; ++h) {
    float s = 0.f;
#pragma unroll 8
    for (int d = 0; d < 64; ++d)
      s += q[(h << 6) + d] * kW[(size_t)(((h << 6) + d) << 8) + c];
    QW[((size_t)(bk * 4 + h) << 8) + c] = s;
  }
}

// ---------------- conv3x3 4->4 + bias + silu (per image, 4x4 patch/thread) ----------------
__global__ __launch_bounds__(256) void conv1_k(
    const bf16_t* __restrict__ X, const float* __restrict__ W,
    const float* __restrict__ Bi, bf16_t* __restrict__ Y) {
  __shared__ bf16_t lg[16384];
  __shared__ float wsh[144];
  const int t = threadIdx.x;
  const size_t base = (size_t)blockIdx.x * 16384;
#pragma unroll
  for (int i = 0; i < 8; ++i) {
    int o = (i * 256 + t) * 8;
    *(bf16x8*)&lg[o] = *(const bf16x8*)(X + base + o);
  }
  if (t < 144) wsh[t] = W[t];
  __syncthreads();
  const int px0 = (t & 15) * 4, py0 = (t >> 4) * 4;
  float acc[4][16];
#pragma unroll
  for (int oc = 0; oc < 4; ++oc) {
    float bb = Bi[oc];
#pragma unroll
    for (int p = 0; p < 16; ++p) acc[oc][p] = bb;
  }
#pragma unroll
  for (int c = 0; c < 4; ++c) {
    float p[6][6];
#pragma unroll
    for (int yy = 0; yy < 6; ++yy) {
      int gy = py0 + yy - 1;
#pragma unroll
      for (int xx = 0; xx < 6; ++xx) {
        int gx = px0 + xx - 1;
        p[yy][xx] = ((unsigned)gy < 64u && (unsigned)gx < 64u)
                        ? (float)lg[c * 4096 + gy * 64 + gx] : 0.f;
      }
    }
#pragma unroll
    for (int oc = 0; oc < 4; ++oc) {
      float wr[9];
#pragma unroll
      for (int k = 0; k < 9; ++k) wr[k] = wsh[oc * 36 + c * 9 + k];
#pragma unroll
      for (int y = 0; y < 4; ++y)
#pragma unroll
        for (int x = 0; x < 4; ++x) {
          float a = acc[oc][y * 4 + x];
          a += wr[0] * p[y][x] + wr[1] * p[y][x + 1] + wr[2] * p[y][x + 2]
             + wr[3] * p[y + 1][x] + wr[4] * p[y + 1][x + 1] + wr[5] * p[y + 1][x + 2]
             + wr[6] * p[y + 2][x] + wr[7] * p[y + 2][x + 1] + wr[8] * p[y + 2][x + 2];
          acc[oc][y * 4 + x] = a;
        }
    }
  }
#pragma unroll
  for (int oc = 0; oc < 4; ++oc)
#pragma unroll
    for (int y = 0; y < 4; ++y) {
      bf16x4 o;
#pragma unroll
      for (int x = 0; x < 4; ++x) o[x] = (bf16_t)silu_f(acc[oc][y * 4 + x]);
      *(bf16x4*)(Y + base + oc * 4096 + (py0 + y) * 64 + px0) = o;
    }
}

// ---------------- conv3x3 4->1 + bias, then bilinear 64->256 upsample ----------------
__global__ __launch_bounds__(256) void conv2up_k(
    const bf16_t* __restrict__ X, const float* __restrict__ W,
    const float* __restrict__ Bi, float* __restrict__ O) {
  __shared__ bf16_t md[16384];
  __shared__ float lg64[4096];
  __shared__ float wsh[36];
  const int t = threadIdx.x;
  const size_t base = (size_t)blockIdx.x * 16384;
#pragma unroll
  for (int i = 0; i < 8; ++i) {
    int o = (i * 256 + t) * 8;
    *(bf16x8*)&md[o] = *(const bf16x8*)(X + base + o);
  }
  if (t < 36) wsh[t] = W[t];
  __syncthreads();
  const int px0 = (t & 15) * 4, py0 = (t >> 4) * 4;
  float acc[16];
  {
    float bb = Bi[0];
#pragma unroll
    for (int p = 0; p < 16; ++p) acc[p] = bb;
  }
#pragma unroll
  for (int c = 0; c < 4; ++c) {
    float p[6][6];
#pragma unroll
    for (int yy = 0; yy < 6; ++yy) {
      int gy = py0 + yy - 1;
#pragma unroll
      for (int xx = 0; xx < 6; ++xx) {
        int gx = px0 + xx - 1;
        p[yy][xx] = ((unsigned)gy < 64u && (unsigned)gx < 64u)
                        ? (float)md[c * 4096 + gy * 64 + gx] : 0.f;
      }
    }
    float wr[9];
#pragma unroll
    for (int k = 0; k < 9; ++k) wr[k] = wsh[c * 9 + k];
#pragma unroll
    for (int y = 0; y < 4; ++y)
#pragma unroll
      for (int x = 0; x < 4; ++x)
        acc[y * 4 + x] += wr[0] * p[y][x] + wr[1] * p[y][x + 1] + wr[2] * p[y][x + 2]
                        + wr[3] * p[y + 1][x] + wr[4] * p[y + 1][x + 1] + wr[5] * p[y + 1][x + 2]
                        + wr[6] * p[y + 2][x] + wr[7] * p[y + 2][x + 1] + wr[8] * p[y + 2][x + 2];
  }
#pragma unroll
  for (int y = 0; y < 4; ++y)
#pragma unroll
    for (int x = 0; x < 4; ++x) lg64[(py0 + y) * 64 + px0 + x] = acc[y * 4 + x];
  __syncthreads();
  float* Ob = O + (size_t)blockIdx.x * 65536;
  for (int rr = 0; rr < 64; ++rr) {
    int p4 = rr * 256 + t;
    int oy = p4 >> 6, ox0 = (p4 & 63) * 4;
    float sy = oy * 0.25f - 0.375f;
    int y0 = (int)floorf(sy);
    float wy = sy - (float)y0;
    int y1 = min(y0 + 1, 63); y0 = max(y0, 0);
    const float* r0 = &lg64[y0 * 64];
    const float* r1 = &lg64[y1 * 64];
    float4 o;
#pragma unroll
    for (int q = 0; q < 4; ++q) {
      int ox = ox0 + q;
      float sx = ox * 0.25f - 0.375f;
      int x0 = (int)floorf(sx);
      float wx = sx - (float)x0;
      int x1 = min(x0 + 1, 63); x0 = max(x0, 0);
      float v0 = r0[x0] + wx * (r0[x1] - r0[x0]);
      float v1 = r1[x0] + wx * (r1[x1] - r1[x0]);
      ((float*)&o)[q] = v0 + wy * (v1 - v0);
    }
    *(float4*)(Ob + oy * 256 + ox0) = o;
  }
}

// ---------------- confidence: out[row] = dot(cfh_row, w2) + b2 ----------------
__global__ __launch_bounds__(256) void conf_k(
    const float* __restrict__ cfh, const float* __restrict__ w2,
    const float* __restrict__ b2, float* __restrict__ out) {
  __shared__ float tmp[4];
  const int row = blockIdx.x;
  float s = 0.f;
  for (int i = threadIdx.x; i < 2048; i += 256)
    s += cfh[(size_t)row * 2048 + i] * w2[i];
  s = block_sum(s, tmp);
  if (threadIdx.x == 0) out[row] = s + b2[0];
}

extern "C" void kernel_launch(void* const* d_in, const int* in_sizes, int n_in,
                              void* d_out, int out_size, void* d_ws, size_t ws_size,
                              hipStream_t stream) {
  const float* img    = (const float*)d_in[0];
  const float* refv   = (const float*)d_in[1];
  const float* qs     = (const float*)d_in[2];
  const float* qpw    = (const float*)d_in[3];
  const float* kpw    = (const float*)d_in[4];
  const float* fw1    = (const float*)d_in[5];
  const float* fb1    = (const float*)d_in[6];
  const float* fw2    = (const float*)d_in[7];
  const float* fb2    = (const float*)d_in[8];
  const float* qbw    = (const float*)d_in[9];
  const float* rlg    = (const float*)d_in[10];
  const float* rlb    = (const float*)d_in[11];
  const float* rlw    = (const float*)d_in[12];
  const float* rlbias = (const float*)d_in[13];
  const float* clg    = (const float*)d_in[14];
  const float* clb    = (const float*)d_in[15];
  const float* cw1    = (const float*)d_in[16];
  const float* cb1    = (const float*)d_in[17];
  const float* cw2    = (const float*)d_in[18];
  const float* cb2    = (const float*)d_in[19];
  float* out = (float*)d_out;
  char* W = (char*)d_ws;

  // --- workspace layout (bytes); lifetimes disjoint within each region ---
  float*  partF = (float*)(W + 0);           // 33.55 MB  steps 3-4
  bf16_t* imgT  = (bf16_t*)(W + 0);          // 16.78 MB  steps 5-9  (reuses partF)
  bf16_t* midb  = (bf16_t*)(W + 16777216);   //  8.39 MB  steps 10-11
  float*  partC = (float*)(W + 0);           // 16.78 MB  steps 13-14 (imgT/midb dead)
  bf16_t* catln = (bf16_t*)(W + 33554432);   //  4.19 MB  steps 2-3
  float*  fus   = (float*)(W + 33554432);    //  4.19 MB  steps 4-12 (reuses catln)
  float*  qb    = (float*)(W + 37748736);    //  4.19 MB  steps 1-2
  bf16_t* fusb  = (bf16_t*)(W + 37748736);   //  2.10 MB  steps 4-6  (reuses qb)
  bf16_t* l64hb = (bf16_t*)(W + 37748736);   //  8.39 MB  steps 9-10
  bf16_t* lnf   = (bf16_t*)(W + 37748736);   //  2.10 MB  steps 12-13 (l64hb dead)
  float*  cfh   = (float*)(W + 39845888);    //  2.10 MB  steps 14-15
  float*  part8 = (float*)(W + 46137344);    //  2.10 MB  steps 6-7
  float*  Qb    = (float*)(W + 48234496);    //  0.26 MB  steps 7-8
  float*  QW    = (float*)(W + 48496640);    //  1.05 MB  steps 8-9

  dim3 b256(256);

  // 1. qb = querybook_slots @ qb_proj_w^T (f32 direct)
  gemm_mfma<1, 1, 1><<<dim3(64, 4, 1), b256, 0, stream>>>(
      qs, qbw, qb, 256, 4096, 512, 512, 1, 0, 0, 0);
  // 2. catln = LN(concat(ref_vec, qb)) -> bf16
  ln_rows<<<dim3(256), b256, 0, stream>>>(refv, qb, 4096, 4096, rlg, rlb, catln);
  // 3. fused GEMM (split-K x8): partF[s] = catln @ rlw^T chunk
  gemm_big<<<dim3(32, 2, 8), dim3(512), 0, stream>>>(
      catln, rlw, partF, 256, 4096, 8192, 1024);
  // 4. fus = silu(sum partF + bias) -> f32 + bf16
  reduce_k<1, 1><<<dim3(1024), b256, 0, stream>>>(
      partF, 8, 1048576L, rlbias, 1.f, fus, fusb, 4095, 262144L);
  // 5. imgT = transpose(image_embed) -> (8,4096,256) bf16
  transpose_k<<<dim3(64, 4, 8), b256, 0, stream>>>(img, imgT);
  // 6. qproj GEMM (split-K x8): part8[s] = fusb @ qpw^T chunk
  gemm_mfma<0, 1, 0><<<dim3(4, 4, 8), b256, 0, stream>>>(
      fusb, qpw, part8, 256, 256, 4096, 512, 8, 0, 0, 0);
  // 7. Qb = 0.125 * sum part8
  reduce_k<0, 0><<<dim3(64), b256, 0, stream>>>(
      part8, 8, 65536L, nullptr, 0.125f, Qb, nullptr, 0, 16384L);
  // 8. QW = per-head Q @ k_proj
  qw_kernel<<<dim3(256), b256, 0, stream>>>(Qb, kpw, QW);
  // 9. logits (batched, bf16 out): l64hb[b] = QW_b @ imgT_b^T
  gemm_mfma<1, 0, 2><<<dim3(64, 2, 8), b256, 0, stream>>>(
      QW, imgT, l64hb, 128, 4096, 256, 256, 1, 32768L, 1048576L, 524288L);
  // 10. midb = silu(conv3x3(l64hb, fw1) + fb1)
  conv1_k<<<dim3(256), b256, 0, stream>>>(l64hb, fw1, fb1, midb);
  // 11. out = upsample(conv3x3(midb, fw2) + fb2)
  conv2up_k<<<dim3(256), b256, 0, stream>>>(midb, fw2, fb2, out);
  // 12. lnf = LN(fus) -> bf16
  ln_rows<<<dim3(256), b256, 0, stream>>>(fus, nullptr, 4096, 0, clg, clb, lnf);
  // 13. cfh GEMM (split-K x8): partC[s] = lnf @ cw1^T chunk
  gemm_big<<<dim3(16, 2, 8), dim3(512), 0, stream>>>(
      lnf, cw1, partC, 256, 2048, 4096, 512);
  // 14. cfh = silu(sum partC + cb1)
  reduce_k<1, 1><<<dim3(512), b256, 0, stream>>>(
      partC, 8, 524288L, cb1, 1.f, cfh, nullptr, 2047, 131072L);
  // 15. conf out
  conf_k<<<dim3(256), b256, 0, stream>>>(cfh, cw2, cb2, out + 16777216);
}

// Round 4
// 234.061 us; speedup vs baseline: 6.0506x; 1.0237x over previous
//
#include <hip/hip_runtime.h>

#define EPS 1e-5f

typedef __bf16 bf16_t;
typedef __bf16 bf16x8 __attribute__((ext_vector_type(8)));
typedef __bf16 bf16x4 __attribute__((ext_vector_type(4)));
typedef float f32x4 __attribute__((ext_vector_type(4)));

__device__ __forceinline__ float silu_f(float x) { return x / (1.f + __expf(-x)); }

// ---------------- block reduction (256 threads = 4 waves) ----------------
__device__ __forceinline__ float block_sum(float v, float* tmp) {
#pragma unroll
  for (int off = 32; off > 0; off >>= 1) v += __shfl_down(v, off);
  __syncthreads();
  if ((threadIdx.x & 63) == 0) tmp[threadIdx.x >> 6] = v;
  __syncthreads();
  return tmp[0] + tmp[1] + tmp[2] + tmp[3];
}

// ============================================================================
// gemm_big v2: Cpart[z] = A(M,K)bf16 * B(N,K)^T f32 -- fat weight GEMMs.
// tile 128x128, BK=64, 512 threads (8 waves, wave-tile 32x64).
// 2-deep register staging pipeline (named sets, static indexing), raw
// s_barrier + explicit lgkmcnt(0) so the compiler's dependency-accurate
// waitcnt emits counted vmcnt(6) (never a full drain) before each LDS store.
// Requires nt = KS/64 even.
// ============================================================================
__global__ __launch_bounds__(512, 4) void gemm_big(
    const bf16_t* __restrict__ A, const float* __restrict__ B,
    float* __restrict__ Cpart, int M, int N, int K, int KS) {
  __shared__ bf16_t As[2][128][72];  // 144B rows
  __shared__ bf16_t Bs[2][128][72];
  const int t = threadIdx.x;
  const int lane = t & 63;
  const int w = t >> 6;
  const int n0 = blockIdx.x * 128;
  const int m0 = blockIdx.y * 128;
  const int kbeg = blockIdx.z * KS;
  const int r = t >> 2;          // 0..127 staging row
  const int cg = (t & 3) * 16;   // staging col group
  const bf16_t* Ap = A + (size_t)(m0 + r) * K + cg;
  const float* Bp = B + (size_t)(n0 + r) * K + cg;

  // two named register sets (rule #20: no runtime-indexed reg arrays)
  bf16x8 a0A, a1A, a0B, a1B;
  float4 b0A, b1A, b2A, b3A, b0B, b1B, b2B, b3B;

#define LOADSET(S, k0)                              \
  a0##S = *(const bf16x8*)(Ap + (k0));              \
  a1##S = *(const bf16x8*)(Ap + (k0) + 8);          \
  b0##S = *(const float4*)(Bp + (k0));              \
  b1##S = *(const float4*)(Bp + (k0) + 4);          \
  b2##S = *(const float4*)(Bp + (k0) + 8);          \
  b3##S = *(const float4*)(Bp + (k0) + 12);

#define STORESET(S, buf)                                                          \
  {                                                                               \
    *(bf16x8*)&As[buf][r][cg] = a0##S;                                            \
    *(bf16x8*)&As[buf][r][cg + 8] = a1##S;                                        \
    bf16x8 w0, w1;                                                                \
    w0[0] = (bf16_t)b0##S.x; w0[1] = (bf16_t)b0##S.y;                             \
    w0[2] = (bf16_t)b0##S.z; w0[3] = (bf16_t)b0##S.w;                             \
    w0[4] = (bf16_t)b1##S.x; w0[5] = (bf16_t)b1##S.y;                             \
    w0[6] = (bf16_t)b1##S.z; w0[7] = (bf16_t)b1##S.w;                             \
    w1[0] = (bf16_t)b2##S.x; w1[1] = (bf16_t)b2##S.y;                             \
    w1[2] = (bf16_t)b2##S.z; w1[3] = (bf16_t)b2##S.w;                             \
    w1[4] = (bf16_t)b3##S.x; w1[5] = (bf16_t)b3##S.y;                             \
    w1[6] = (bf16_t)b3##S.z; w1[7] = (bf16_t)b3##S.w;                             \
    *(bf16x8*)&Bs[buf][r][cg] = w0;                                               \
    *(bf16x8*)&Bs[buf][r][cg + 8] = w1;                                           \
  }

#define PHASE_SYNC                                      \
  asm volatile("s_waitcnt lgkmcnt(0)" ::: "memory");    \
  __builtin_amdgcn_sched_barrier(0);                    \
  __builtin_amdgcn_s_barrier();                         \
  __builtin_amdgcn_sched_barrier(0);

  f32x4 acc[2][4];
#pragma unroll
  for (int i = 0; i < 2; ++i)
#pragma unroll
    for (int j = 0; j < 4; ++j) acc[i][j] = f32x4{0.f, 0.f, 0.f, 0.f};

  const int wm = (w & 3) * 32;   // 4 wave-rows of 32
  const int wn = (w >> 2) * 64;  // 2 wave-cols of 64
  const int fr = lane & 15;
  const int kq = (lane >> 4) * 8;

  auto COMPUTE = [&](int buf) {
#pragma unroll
    for (int kk = 0; kk < 64; kk += 32) {
      bf16x8 af[2], bg[4];
#pragma unroll
      for (int i = 0; i < 2; ++i)
        af[i] = *(const bf16x8*)&As[buf][wm + 16 * i + fr][kk + kq];
#pragma unroll
      for (int j = 0; j < 4; ++j)
        bg[j] = *(const bf16x8*)&Bs[buf][wn + 16 * j + fr][kk + kq];
#pragma unroll
      for (int i = 0; i < 2; ++i)
#pragma unroll
        for (int j = 0; j < 4; ++j)
          acc[i][j] = __builtin_amdgcn_mfma_f32_16x16x32_bf16(af[i], bg[j], acc[i][j], 0, 0, 0);
    }
  };

  const int nt = KS >> 6;  // even
  // prologue: fill both sets, stage step0 into buf0
  LOADSET(A, kbeg)
  LOADSET(B, kbeg + 64)
  STORESET(A, 0)           // compiler: vmcnt(6) -- setB stays in flight
  PHASE_SYNC
  for (int st = 0; st < nt; st += 2) {
    const int kc = kbeg + st * 64;
    // even phase: compute buf0 (step st)
    if (st + 2 < nt) { LOADSET(A, kc + 128) }
    COMPUTE(0);
    if (st + 1 < nt) { STORESET(B, 1) }   // vmcnt(6): setA newer, in flight
    PHASE_SYNC
    // odd phase: compute buf1 (step st+1)
    if (st + 3 < nt) { LOADSET(B, kc + 192) }
    COMPUTE(1);
    if (st + 2 < nt) { STORESET(A, 0) }
    PHASE_SYNC
  }
#undef LOADSET
#undef STORESET
#undef PHASE_SYNC

  float* Cz = Cpart + (size_t)blockIdx.z * M * N;
  const int rh = (lane >> 4) * 4, col = lane & 15;
#pragma unroll
  for (int i = 0; i < 2; ++i)
#pragma unroll
    for (int j = 0; j < 4; ++j)
#pragma unroll
      for (int rr = 0; rr < 4; ++rr)
        Cz[(size_t)(m0 + wm + 16 * i + rh + rr) * N + n0 + wn + 16 * j + col] = acc[i][j][rr];
}

// ============================================================================
// generic MFMA GEMM (64x64 tile) for the small GEMMs (ABT, K-contiguous)
// OUTMODE: 0 = f32 split-K partial, 1 = f32 direct
// ============================================================================
template <int AF32, int BF32, int OUTMODE>
__global__ __launch_bounds__(256) void gemm_mfma(
    const void* __restrict__ Av, const void* __restrict__ Bv, void* __restrict__ Cv,
    int M, int N, int K, int KS, int S) {
  __shared__ bf16_t As[64][72];
  __shared__ bf16_t Bs[64][72];
  const int t = threadIdx.x;
  const int lane = t & 63;
  const int w = t >> 6;
  const int s = blockIdx.z;
  const int n0 = blockIdx.x * 64;
  const int m0 = blockIdx.y * 64;
  const int kbeg = s * KS;

  const float* A32 = (const float*)Av;
  const bf16_t* A16 = (const bf16_t*)Av;
  const float* B32 = (const float*)Bv;
  const bf16_t* B16 = (const bf16_t*)Bv;

  f32x4 acc[2][2];
#pragma unroll
  for (int i = 0; i < 2; ++i)
#pragma unroll
    for (int j = 0; j < 2; ++j) acc[i][j] = f32x4{0.f, 0.f, 0.f, 0.f};

  const int wm = (w & 1) * 32, wn = (w >> 1) * 32;
  const int fr = lane & 15;
  const int kq = (lane >> 4) * 8;

  for (int k0 = kbeg; k0 < kbeg + KS; k0 += 64) {
    float4 a4[4], b4[4];
    bf16x8 a8[2], b8[2];
    if constexpr (AF32) {
      const int rr = t >> 4, c4 = (t & 15) * 4;
#pragma unroll
      for (int i = 0; i < 4; ++i)
        a4[i] = *(const float4*)(A32 + (size_t)(m0 + rr + 16 * i) * K + k0 + c4);
    } else {
      const int rr = t >> 2, c8 = (t & 3) * 8;
#pragma unroll
      for (int i = 0; i < 2; ++i)
        a8[i] = *(const bf16x8*)(A16 + (size_t)(m0 + rr) * K + k0 + c8 + 32 * i);
    }
    if constexpr (BF32) {
      const int rr = t >> 4, c4 = (t & 15) * 4;
#pragma unroll
      for (int i = 0; i < 4; ++i)
        b4[i] = *(const float4*)(B32 + (size_t)(n0 + rr + 16 * i) * K + k0 + c4);
    } else {
      const int rr = t >> 2, c8 = (t & 3) * 8;
#pragma unroll
      for (int i = 0; i < 2; ++i)
        b8[i] = *(const bf16x8*)(B16 + (size_t)(n0 + rr) * K + k0 + c8 + 32 * i);
    }
    __syncthreads();
    if constexpr (AF32) {
      const int rr = t >> 4, c4 = (t & 15) * 4;
#pragma unroll
      for (int i = 0; i < 4; ++i) {
        bf16x4 v = {(bf16_t)a4[i].x, (bf16_t)a4[i].y, (bf16_t)a4[i].z, (bf16_t)a4[i].w};
        *(bf16x4*)&As[rr + 16 * i][c4] = v;
      }
    } else {
      const int rr = t >> 2, c8 = (t & 3) * 8;
#pragma unroll
      for (int i = 0; i < 2; ++i) *(bf16x8*)&As[rr][c8 + 32 * i] = a8[i];
    }
    if constexpr (BF32) {
      const int rr = t >> 4, c4 = (t & 15) * 4;
#pragma unroll
      for (int i = 0; i < 4; ++i) {
        bf16x4 v = {(bf16_t)b4[i].x, (bf16_t)b4[i].y, (bf16_t)b4[i].z, (bf16_t)b4[i].w};
        *(bf16x4*)&Bs[rr + 16 * i][c4] = v;
      }
    } else {
      const int rr = t >> 2, c8 = (t & 3) * 8;
#pragma unroll
      for (int i = 0; i < 2; ++i) *(bf16x8*)&Bs[rr][c8 + 32 * i] = b8[i];
    }
    __syncthreads();
#pragma unroll
    for (int kk = 0; kk < 64; kk += 32) {
      bf16x8 af[2], bg[2];
#pragma unroll
      for (int i = 0; i < 2; ++i) {
        af[i] = *(const bf16x8*)&As[wm + 16 * i + fr][kk + kq];
        bg[i] = *(const bf16x8*)&Bs[wn + 16 * i + fr][kk + kq];
      }
#pragma unroll
      for (int i = 0; i < 2; ++i)
#pragma unroll
        for (int j = 0; j < 2; ++j)
          acc[i][j] = __builtin_amdgcn_mfma_f32_16x16x32_bf16(af[i], bg[j], acc[i][j], 0, 0, 0);
    }
    __syncthreads();
  }

  const int rh = (lane >> 4) * 4;
  const int col = lane & 15;
#pragma unroll
  for (int i = 0; i < 2; ++i)
#pragma unroll
    for (int j = 0; j < 2; ++j)
#pragma unroll
      for (int rr = 0; rr < 4; ++rr) {
        const size_t m = m0 + wm + 16 * i + rh + rr;
        const size_t n = n0 + wn + 16 * j + col;
        if constexpr (OUTMODE == 0) {
          ((float*)Cv)[(size_t)s * M * N + m * N + n] = acc[i][j][rr];
        } else {
          ((float*)Cv)[m * N + n] = acc[i][j][rr];
        }
      }
}

// ============================================================================
// gemm_attn: per-batch C(128,4096)bf16 = A(128,256)f32 @ B(256,4096)f32
// AB-form: B is [k][n]; staged with in-LDS transpose (kills the transpose pass)
// grid (N/64, 128/64, 8), 256 threads, K=256 in 4 steps of 64.
// ============================================================================
__global__ __launch_bounds__(256) void gemm_attn(
    const float* __restrict__ A, const float* __restrict__ B, bf16_t* __restrict__ C) {
  __shared__ bf16_t As[64][72];
  __shared__ bf16_t Bs[64][72];  // Bs[n][k]
  const int t = threadIdx.x;
  const int lane = t & 63;
  const int w = t >> 6;
  const int b = blockIdx.z;
  const int n0 = blockIdx.x * 64;
  const int m0 = blockIdx.y * 64;
  const float* Ab = A + (size_t)b * 32768;    // 128*256
  const float* Bb = B + (size_t)b * 1048576;  // 256*4096

  f32x4 acc[2][2];
#pragma unroll
  for (int i = 0; i < 2; ++i)
#pragma unroll
    for (int j = 0; j < 2; ++j) acc[i][j] = f32x4{0.f, 0.f, 0.f, 0.f};

  const int wm = (w & 1) * 32, wn = (w >> 1) * 32;
  const int fr = lane & 15;
  const int kq = (lane >> 4) * 8;

  for (int k0 = 0; k0 < 256; k0 += 64) {
    // A stage (ABT-style, K-contiguous)
    {
      const int rr = t >> 4, c4 = (t & 15) * 4;
      float4 a4[4];
#pragma unroll
      for (int i = 0; i < 4; ++i)
        a4[i] = *(const float4*)(Ab + (size_t)(m0 + rr + 16 * i) * 256 + k0 + c4);
      __syncthreads();
#pragma unroll
      for (int i = 0; i < 4; ++i) {
        bf16x4 v = {(bf16_t)a4[i].x, (bf16_t)a4[i].y, (bf16_t)a4[i].z, (bf16_t)a4[i].w};
        *(bf16x4*)&As[rr + 16 * i][c4] = v;
      }
    }
    // B stage with transpose: thread reads 16 n-contiguous floats of one k-row
    {
      const int kr = t >> 2, nc = (t & 3) * 16;
      float4 b4[4];
#pragma unroll
      for (int i = 0; i < 4; ++i)
        b4[i] = *(const float4*)(Bb + (size_t)(k0 + kr) * 4096 + n0 + nc + 4 * i);
#pragma unroll
      for (int i = 0; i < 4; ++i) {
        Bs[nc + 4 * i + 0][kr] = (bf16_t)b4[i].x;
        Bs[nc + 4 * i + 1][kr] = (bf16_t)b4[i].y;
        Bs[nc + 4 * i + 2][kr] = (bf16_t)b4[i].z;
        Bs[nc + 4 * i + 3][kr] = (bf16_t)b4[i].w;
      }
    }
    __syncthreads();
#pragma unroll
    for (int kk = 0; kk < 64; kk += 32) {
      bf16x8 af[2], bg[2];
#pragma unroll
      for (int i = 0; i < 2; ++i) {
        af[i] = *(const bf16x8*)&As[wm + 16 * i + fr][kk + kq];
        bg[i] = *(const bf16x8*)&Bs[wn + 16 * i + fr][kk + kq];
      }
#pragma unroll
      for (int i = 0; i < 2; ++i)
#pragma unroll
        for (int j = 0; j < 2; ++j)
          acc[i][j] = __builtin_amdgcn_mfma_f32_16x16x32_bf16(af[i], bg[j], acc[i][j], 0, 0, 0);
    }
    __syncthreads();
  }

  bf16_t* Cb = C + (size_t)b * 524288;
  const int rh = (lane >> 4) * 4, col = lane & 15;
#pragma unroll
  for (int i = 0; i < 2; ++i)
#pragma unroll
    for (int j = 0; j < 2; ++j)
#pragma unroll
      for (int rr = 0; rr < 4; ++rr)
        Cb[(size_t)(m0 + wm + 16 * i + rh + rr) * 4096 + n0 + wn + 16 * j + col] =
            (bf16_t)acc[i][j][rr];
}

// ---------------- split-K reduce + bias + silu epilogue ----------------
template <int SILU_, int BIAS_>
__global__ __launch_bounds__(256) void reduce_k(
    const float* __restrict__ part, int S, long slice,
    const float* __restrict__ bias, float scale,
    float* __restrict__ outF, bf16_t* __restrict__ outB,
    int nmask, long total4) {
  long i4 = (long)blockIdx.x * 256 + threadIdx.x;
  if (i4 >= total4) return;
  long i = i4 * 4;
  float4 v = *(const float4*)(part + i);
  for (int s = 1; s < S; ++s) {
    float4 u = *(const float4*)(part + (size_t)s * slice + i);
    v.x += u.x; v.y += u.y; v.z += u.z; v.w += u.w;
  }
  v.x *= scale; v.y *= scale; v.z *= scale; v.w *= scale;
  if (BIAS_) {
    float4 bb = *(const float4*)(bias + (i & nmask));
    v.x += bb.x; v.y += bb.y; v.z += bb.z; v.w += bb.w;
  }
  if (SILU_) { v.x = silu_f(v.x); v.y = silu_f(v.y); v.z = silu_f(v.z); v.w = silu_f(v.w); }
  if (outF) *(float4*)(outF + i) = v;
  if (outB) {
    bf16x4 o = {(bf16_t)v.x, (bf16_t)v.y, (bf16_t)v.z, (bf16_t)v.w};
    *(bf16x4*)(outB + i) = o;
  }
}

// ---------------- LayerNorm over rows = concat(X1[L1], X2[L2]) -> bf16 ----------------
__global__ __launch_bounds__(256) void ln_rows(
    const float* __restrict__ X1, const float* __restrict__ X2, int L1, int L2,
    const float* __restrict__ g, const float* __restrict__ bta, bf16_t* __restrict__ Y) {
  __shared__ float tmp[4];
  const int row = blockIdx.x;
  const int L = L1 + L2;
  const float* x1 = X1 + (size_t)row * L1;
  const float* x2 = X2 ? X2 + (size_t)row * L2 : nullptr;
  float s = 0.f, ss = 0.f;
  for (int i = threadIdx.x * 4; i < L1; i += 1024) {
    float4 v = *(const float4*)(x1 + i);
    s += v.x + v.y + v.z + v.w;
    ss += v.x * v.x + v.y * v.y + v.z * v.z + v.w * v.w;
  }
  for (int i = threadIdx.x * 4; i < L2; i += 1024) {
    float4 v = *(const float4*)(x2 + i);
    s += v.x + v.y + v.z + v.w;
    ss += v.x * v.x + v.y * v.y + v.z * v.z + v.w * v.w;
  }
  s = block_sum(s, tmp);
  ss = block_sum(ss, tmp);
  const float mu = s / (float)L;
  const float inv = rsqrtf(ss / (float)L - mu * mu + EPS);
  bf16_t* y = Y + (size_t)row * L;
  for (int i = threadIdx.x * 4; i < L1; i += 1024) {
    float4 v = *(const float4*)(x1 + i);
    float4 gv = *(const float4*)(g + i);
    float4 bv = *(const float4*)(bta + i);
    bf16x4 o = {(bf16_t)((v.x - mu) * inv * gv.x + bv.x),
                (bf16_t)((v.y - mu) * inv * gv.y + bv.y),
                (bf16_t)((v.z - mu) * inv * gv.z + bv.z),
                (bf16_t)((v.w - mu) * inv * gv.w + bv.w)};
    *(bf16x4*)(y + i) = o;
  }
  for (int i = threadIdx.x * 4; i < L2; i += 1024) {
    float4 v = *(const float4*)(x2 + i);
    float4 gv = *(const float4*)(g + L1 + i);
    float4 bv = *(const float4*)(bta + L1 + i);
    bf16x4 o = {(bf16_t)((v.x - mu) * inv * gv.x + bv.x),
                (bf16_t)((v.y - mu) * inv * gv.y + bv.y),
                (bf16_t)((v.z - mu) * inv * gv.z + bv.z),
                (bf16_t)((v.w - mu) * inv * gv.w + bv.w)};
    *(bf16x4*)(y + L1 + i) = o;
  }
}

// ---------------- QW[bk,h,c] = sum_d Q[bk,h*64+d] * kW[h*64+d, c] ----------------
__global__ __launch_bounds__(256) void qw_kernel(
    const float* __restrict__ Q, const float* __restrict__ kW, float* __restrict__ QW) {
  __shared__ float q[256];
  const int bk = blockIdx.x;
  q[threadIdx.x] = Q[(size_t)bk * 256 + threadIdx.x];
  __syncthreads();
  const int c = threadIdx.x;
#pragma unroll
  for (int h = 0; h < 4; ++h) {
    float s = 0.f;
#pragma unroll 8
    for (int d = 0; d < 64; ++d)
      s += q[(h << 6) + d] * kW[(size_t)(((h << 6) + d) << 8) + c];
    QW[((size_t)(bk * 4 + h) << 8) + c] = s;
  }
}

// ---------------- conv3x3 4->4 + bias + silu (per image, 4x4 patch/thread) ----------------
__global__ __launch_bounds__(256) void conv1_k(
    const bf16_t* __restrict__ X, const float* __restrict__ W,
    const float* __restrict__ Bi, bf16_t* __restrict__ Y) {
  __shared__ bf16_t lg[16384];
  __shared__ float wsh[144];
  const int t = threadIdx.x;
  const size_t base = (size_t)blockIdx.x * 16384;
#pragma unroll
  for (int i = 0; i < 8; ++i) {
    int o = (i * 256 + t) * 8;
    *(bf16x8*)&lg[o] = *(const bf16x8*)(X + base + o);
  }
  if (t < 144) wsh[t] = W[t];
  __syncthreads();
  const int px0 = (t & 15) * 4, py0 = (t >> 4) * 4;
  float acc[4][16];
#pragma unroll
  for (int oc = 0; oc < 4; ++oc) {
    float bb = Bi[oc];
#pragma unroll
    for (int p = 0; p < 16; ++p) acc[oc][p] = bb;
  }
#pragma unroll
  for (int c = 0; c < 4; ++c) {
    float p[6][6];
#pragma unroll
    for (int yy = 0; yy < 6; ++yy) {
      int gy = py0 + yy - 1;
#pragma unroll
      for (int xx = 0; xx < 6; ++xx) {
        int gx = px0 + xx - 1;
        p[yy][xx] = ((unsigned)gy < 64u && (unsigned)gx < 64u)
                        ? (float)lg[c * 4096 + gy * 64 + gx] : 0.f;
      }
    }
#pragma unroll
    for (int oc = 0; oc < 4; ++oc) {
      float wr[9];
#pragma unroll
      for (int k = 0; k < 9; ++k) wr[k] = wsh[oc * 36 + c * 9 + k];
#pragma unroll
      for (int y = 0; y < 4; ++y)
#pragma unroll
        for (int x = 0; x < 4; ++x) {
          float a = acc[oc][y * 4 + x];
          a += wr[0] * p[y][x] + wr[1] * p[y][x + 1] + wr[2] * p[y][x + 2]
             + wr[3] * p[y + 1][x] + wr[4] * p[y + 1][x + 1] + wr[5] * p[y + 1][x + 2]
             + wr[6] * p[y + 2][x] + wr[7] * p[y + 2][x + 1] + wr[8] * p[y + 2][x + 2];
          acc[oc][y * 4 + x] = a;
        }
    }
  }
#pragma unroll
  for (int oc = 0; oc < 4; ++oc)
#pragma unroll
    for (int y = 0; y < 4; ++y) {
      bf16x4 o;
#pragma unroll
      for (int x = 0; x < 4; ++x) o[x] = (bf16_t)silu_f(acc[oc][y * 4 + x]);
      *(bf16x4*)(Y + base + oc * 4096 + (py0 + y) * 64 + px0) = o;
    }
}

// ---------------- conv3x3 4->1 + bias, then bilinear 64->256 upsample ----------------
__global__ __launch_bounds__(256) void conv2up_k(
    const bf16_t* __restrict__ X, const float* __restrict__ W,
    const float* __restrict__ Bi, float* __restrict__ O) {
  __shared__ bf16_t md[16384];
  __shared__ float lg64[4096];
  __shared__ float wsh[36];
  const int t = threadIdx.x;
  const size_t base = (size_t)blockIdx.x * 16384;
#pragma unroll
  for (int i = 0; i < 8; ++i) {
    int o = (i * 256 + t) * 8;
    *(bf16x8*)&md[o] = *(const bf16x8*)(X + base + o);
  }
  if (t < 36) wsh[t] = W[t];
  __syncthreads();
  const int px0 = (t & 15) * 4, py0 = (t >> 4) * 4;
  float acc[16];
  {
    float bb = Bi[0];
#pragma unroll
    for (int p = 0; p < 16; ++p) acc[p] = bb;
  }
#pragma unroll
  for (int c = 0; c < 4; ++c) {
    float p[6][6];
#pragma unroll
    for (int yy = 0; yy < 6; ++yy) {
      int gy = py0 + yy - 1;
#pragma unroll
      for (int xx = 0; xx < 6; ++xx) {
        int gx = px0 + xx - 1;
        p[yy][xx] = ((unsigned)gy < 64u && (unsigned)gx < 64u)
                        ? (float)md[c * 4096 + gy * 64 + gx] : 0.f;
      }
    }
    float wr[9];
#pragma unroll
    for (int k = 0; k < 9; ++k) wr[k] = wsh[c * 9 + k];
#pragma unroll
    for (int y = 0; y < 4; ++y)
#pragma unroll
      for (int x = 0; x < 4; ++x)
        acc[y * 4 + x] += wr[0] * p[y][x] + wr[1] * p[y][x + 1] + wr[2] * p[y][x + 2]
                        + wr[3] * p[y + 1][x] + wr[4] * p[y + 1][x + 1] + wr[5] * p[y + 1][x + 2]
                        + wr[6] * p[y + 2][x] + wr[7] * p[y + 2][x + 1] + wr[8] * p[y + 2][x + 2];
  }
#pragma unroll
  for (int y = 0; y < 4; ++y)
#pragma unroll
    for (int x = 0; x < 4; ++x) lg64[(py0 + y) * 64 + px0 + x] = acc[y * 4 + x];
  __syncthreads();
  float* Ob = O + (size_t)blockIdx.x * 65536;
  for (int rr = 0; rr < 64; ++rr) {
    int p4 = rr * 256 + t;
    int oy = p4 >> 6, ox0 = (p4 & 63) * 4;
    float sy = oy * 0.25f - 0.375f;
    int y0 = (int)floorf(sy);
    float wy = sy - (float)y0;
    int y1 = min(y0 + 1, 63); y0 = max(y0, 0);
    const float* r0 = &lg64[y0 * 64];
    const float* r1 = &lg64[y1 * 64];
    float4 o;
#pragma unroll
    for (int q = 0; q < 4; ++q) {
      int ox = ox0 + q;
      float sx = ox * 0.25f - 0.375f;
      int x0 = (int)floorf(sx);
      float wx = sx - (float)x0;
      int x1 = min(x0 + 1, 63); x0 = max(x0, 0);
      float v0 = r0[x0] + wx * (r0[x1] - r0[x0]);
      float v1 = r1[x0] + wx * (r1[x1] - r1[x0]);
      ((float*)&o)[q] = v0 + wy * (v1 - v0);
    }
    *(float4*)(Ob + oy * 256 + ox0) = o;
  }
}

// ---------------- confidence: out[row] = dot(cfh_row, w2) + b2 ----------------
__global__ __launch_bounds__(256) void conf_k(
    const float* __restrict__ cfh, const float* __restrict__ w2,
    const float* __restrict__ b2, float* __restrict__ out) {
  __shared__ float tmp[4];
  const int row = blockIdx.x;
  float s = 0.f;
  for (int i = threadIdx.x; i < 2048; i += 256)
    s += cfh[(size_t)row * 2048 + i] * w2[i];
  s = block_sum(s, tmp);
  if (threadIdx.x == 0) out[row] = s + b2[0];
}

extern "C" void kernel_launch(void* const* d_in, const int* in_sizes, int n_in,
                              void* d_out, int out_size, void* d_ws, size_t ws_size,
                              hipStream_t stream) {
  const float* img    = (const float*)d_in[0];
  const float* refv   = (const float*)d_in[1];
  const float* qs     = (const float*)d_in[2];
  const float* qpw    = (const float*)d_in[3];
  const float* kpw    = (const float*)d_in[4];
  const float* fw1    = (const float*)d_in[5];
  const float* fb1    = (const float*)d_in[6];
  const float* fw2    = (const float*)d_in[7];
  const float* fb2    = (const float*)d_in[8];
  const float* qbw    = (const float*)d_in[9];
  const float* rlg    = (const float*)d_in[10];
  const float* rlb    = (const float*)d_in[11];
  const float* rlw    = (const float*)d_in[12];
  const float* rlbias = (const float*)d_in[13];
  const float* clg    = (const float*)d_in[14];
  const float* clb    = (const float*)d_in[15];
  const float* cw1    = (const float*)d_in[16];
  const float* cb1    = (const float*)d_in[17];
  const float* cw2    = (const float*)d_in[18];
  const float* cb2    = (const float*)d_in[19];
  float* out = (float*)d_out;
  char* W = (char*)d_ws;

  // --- workspace layout (bytes); lifetimes disjoint within each region ---
  float*  partF = (float*)(W + 0);           // 33.55 MB steps 3-4
  bf16_t* l64hb = (bf16_t*)(W + 0);          //  8.39 MB steps 8-9  (partF dead)
  float*  partC = (float*)(W + 0);           // 16.78 MB steps 12-13
  bf16_t* midb  = (bf16_t*)(W + 16777216);   //  8.39 MB steps 9-10
  bf16_t* catln = (bf16_t*)(W + 33554432);   //  4.19 MB steps 2-3
  float*  fus   = (float*)(W + 33554432);    //  4.19 MB steps 4-11 (reuses catln)
  float*  qb    = (float*)(W + 37748736);    //  4.19 MB steps 1-2
  bf16_t* fusb  = (bf16_t*)(W + 37748736);   //  2.10 MB steps 4-5  (reuses qb)
  bf16_t* lnf   = (bf16_t*)(W + 37748736);   //  2.10 MB steps 11-12
  float*  cfh   = (float*)(W + 39845888);    //  2.10 MB steps 13-14
  float*  part8 = (float*)(W + 46137344);    //  2.10 MB steps 5-6
  float*  Qb    = (float*)(W + 48234496);    //  0.26 MB steps 6-7
  float*  QW    = (float*)(W + 48496640);    //  1.05 MB steps 7-8

  dim3 b256(256);

  // 1. qb = querybook_slots @ qb_proj_w^T (f32 direct)
  gemm_mfma<1, 1, 1><<<dim3(64, 4, 1), b256, 0, stream>>>(
      qs, qbw, qb, 256, 4096, 512, 512, 1);
  // 2. catln = LN(concat(ref_vec, qb)) -> bf16
  ln_rows<<<dim3(256), b256, 0, stream>>>(refv, qb, 4096, 4096, rlg, rlb, catln);
  // 3. fused GEMM (split-K x8): partF[s] = catln @ rlw^T chunk
  gemm_big<<<dim3(32, 2, 8), dim3(512), 0, stream>>>(
      catln, rlw, partF, 256, 4096, 8192, 1024);
  // 4. fus = silu(sum partF + bias) -> f32 + bf16
  reduce_k<1, 1><<<dim3(1024), b256, 0, stream>>>(
      partF, 8, 1048576L, rlbias, 1.f, fus, fusb, 4095, 262144L);
  // 5. qproj GEMM (split-K x8): part8[s] = fusb @ qpw^T chunk
  gemm_mfma<0, 1, 0><<<dim3(4, 4, 8), b256, 0, stream>>>(
      fusb, qpw, part8, 256, 256, 4096, 512, 8);
  // 6. Qb = 0.125 * sum part8
  reduce_k<0, 0><<<dim3(64), b256, 0, stream>>>(
      part8, 8, 65536L, nullptr, 0.125f, Qb, nullptr, 0, 16384L);
  // 7. QW = per-head Q @ k_proj
  qw_kernel<<<dim3(256), b256, 0, stream>>>(Qb, kpw, QW);
  // 8. logits (AB-form, img read directly): l64hb[b] = QW_b @ img_b
  gemm_attn<<<dim3(64, 2, 8), b256, 0, stream>>>(QW, img, l64hb);
  // 9. midb = silu(conv3x3(l64hb, fw1) + fb1)
  conv1_k<<<dim3(256), b256, 0, stream>>>(l64hb, fw1, fb1, midb);
  // 10. out = upsample(conv3x3(midb, fw2) + fb2)
  conv2up_k<<<dim3(256), b256, 0, stream>>>(midb, fw2, fb2, out);
  // 11. lnf = LN(fus) -> bf16
  ln_rows<<<dim3(256), b256, 0, stream>>>(fus, nullptr, 4096, 0, clg, clb, lnf);
  // 12. cfh GEMM (split-K x8): partC[s] = lnf @ cw1^T chunk
  gemm_big<<<dim3(16, 2, 8), dim3(512), 0, stream>>>(
      lnf, cw1, partC, 256, 2048, 4096, 512);
  // 13. cfh = silu(sum partC + cb1)
  reduce_k<1, 1><<<dim3(512), b256, 0, stream>>>(
      partC, 8, 524288L, cb1, 1.f, cfh, nullptr, 2047, 131072L);
  // 14. conf out
  conf_k<<<dim3(256), b256, 0, stream>>>(cfh, cw2, cb2, out + 16777216);
}

// Round 6
// 204.217 us; speedup vs baseline: 6.9348x; 1.1461x over previous
//
#include <hip/hip_runtime.h>

#define EPS 1e-5f

typedef __bf16 bf16_t;
typedef __bf16 bf16x8 __attribute__((ext_vector_type(8)));
typedef __bf16 bf16x4 __attribute__((ext_vector_type(4)));
typedef float f32x4 __attribute__((ext_vector_type(4)));

__device__ __forceinline__ float silu_f(float x) { return x / (1.f + __expf(-x)); }

// ---------------- block reduction (256 threads = 4 waves) ----------------
__device__ __forceinline__ float block_sum(float v, float* tmp) {
#pragma unroll
  for (int off = 32; off > 0; off >>= 1) v += __shfl_down(v, off);
  __syncthreads();
  if ((threadIdx.x & 63) == 0) tmp[threadIdx.x >> 6] = v;
  __syncthreads();
  return tmp[0] + tmp[1] + tmp[2] + tmp[3];
}

// ---------------- cast f32 -> bf16 (small) ----------------
__global__ __launch_bounds__(256) void cast_k(
    const float* __restrict__ X, bf16_t* __restrict__ Y, int n8) {
  int i = blockIdx.x * 256 + threadIdx.x;
  if (i >= n8) return;
  float4 v0 = *(const float4*)(X + i * 8);
  float4 v1 = *(const float4*)(X + i * 8 + 4);
  bf16x8 o;
  o[0] = (bf16_t)v0.x; o[1] = (bf16_t)v0.y; o[2] = (bf16_t)v0.z; o[3] = (bf16_t)v0.w;
  o[4] = (bf16_t)v1.x; o[5] = (bf16_t)v1.y; o[6] = (bf16_t)v1.z; o[7] = (bf16_t)v1.w;
  *(bf16x8*)(Y + i * 8) = o;
}

// ============================================================================
// gemm_wide: Cpart[z] = A(256,K)bf16 @ B(N,K)^T f32  (fat weight GEMMs)
// tile 256x128 (FULL M -> B weight read exactly once), BK=64, 1024 threads
// (16 waves, wave-tile 64x32, acc = 32 VGPR). Single LDS buffer (54 KB),
// 4-deep named register pipeline (4 loads/thread/step -> ~120 VGPR, fits
// the 128-cap of __launch_bounds__(1024,4)). Pinned s_barrier + lgkmcnt(0)
// per phase; vmcnt stays counted (12 newer loads in flight at each store).
// nt = KS/64 must be a multiple of 4. Grid: (N/128, S).
// ============================================================================
__global__ __launch_bounds__(1024, 4) void gemm_wide(
    const bf16_t* __restrict__ A, const float* __restrict__ B,
    float* __restrict__ Cpart, int N, int K, int KS) {
  __shared__ bf16_t As[256][72];  // 144B rows, 16B-aligned
  __shared__ bf16_t Bs[128][72];
  const int t = threadIdx.x;
  const int lane = t & 63;
  const int w = t >> 6;  // 0..15
  const int n0 = blockIdx.x * 128;
  const int kbeg = blockIdx.y * KS;
  const int nt = KS >> 6;  // multiple of 4
  // staging: A 256x64 bf16 (16 elts/thread), B 128x64 f32 (8 f32/thread)
  const int ar = t >> 2, ac = (t & 3) * 16;
  const int br = t >> 3, bc = (t & 7) * 8;
  const bf16_t* Ap = A + (size_t)ar * K + kbeg + ac;
  const float* Bp = B + (size_t)(n0 + br) * K + kbeg + bc;

  // 4 named register sets, digit-first names (pp-token-safe member access)
  bf16x8 a0A, a1A, a0B, a1B, a0C, a1C, a0D, a1D;
  float4 b0A, b1A, b0B, b1B, b0C, b1C, b0D, b1D;

#define LOADSET(S, k0)                            \
  a0##S = *(const bf16x8*)(Ap + (k0));            \
  a1##S = *(const bf16x8*)(Ap + (k0) + 8);        \
  b0##S = *(const float4*)(Bp + (k0));            \
  b1##S = *(const float4*)(Bp + (k0) + 4);

#define STORESET(S)                                                         \
  {                                                                         \
    *(bf16x8*)&As[ar][ac] = a0##S;                                          \
    *(bf16x8*)&As[ar][ac + 8] = a1##S;                                      \
    bf16x8 wv;                                                              \
    wv[0] = (bf16_t)b0##S.x; wv[1] = (bf16_t)b0##S.y;                       \
    wv[2] = (bf16_t)b0##S.z; wv[3] = (bf16_t)b0##S.w;                       \
    wv[4] = (bf16_t)b1##S.x; wv[5] = (bf16_t)b1##S.y;                       \
    wv[6] = (bf16_t)b1##S.z; wv[7] = (bf16_t)b1##S.w;                       \
    *(bf16x8*)&Bs[br][bc] = wv;                                             \
  }

#define BARRIER_PINNED                 \
  __builtin_amdgcn_sched_barrier(0);   \
  __builtin_amdgcn_s_barrier();        \
  __builtin_amdgcn_sched_barrier(0);

#define LGKM_BARRIER                                   \
  asm volatile("s_waitcnt lgkmcnt(0)" ::: "memory");   \
  BARRIER_PINNED

  f32x4 acc[4][2];
#pragma unroll
  for (int i = 0; i < 4; ++i)
#pragma unroll
    for (int j = 0; j < 2; ++j) acc[i][j] = f32x4{0.f, 0.f, 0.f, 0.f};

  const int wm = (w & 3) * 64;   // 4 wave-rows of 64
  const int wn = (w >> 2) * 32;  // 4 wave-cols of 32
  const int fr = lane & 15;
  const int kq = (lane >> 4) * 8;

  auto COMPUTE = [&]() {
#pragma unroll
    for (int kk = 0; kk < 64; kk += 32) {
      bf16x8 af[4], bg[2];
#pragma unroll
      for (int i = 0; i < 4; ++i)
        af[i] = *(const bf16x8*)&As[wm + 16 * i + fr][kk + kq];
#pragma unroll
      for (int j = 0; j < 2; ++j)
        bg[j] = *(const bf16x8*)&Bs[wn + 16 * j + fr][kk + kq];
#pragma unroll
      for (int i = 0; i < 4; ++i)
#pragma unroll
        for (int j = 0; j < 2; ++j)
          acc[i][j] = __builtin_amdgcn_mfma_f32_16x16x32_bf16(af[i], bg[j], acc[i][j], 0, 0, 0);
    }
  };

#define PHASE(s_, SET)                                         \
  COMPUTE();                                                   \
  BARRIER_PINNED                                               \
  if ((s_) + 1 < nt) { STORESET(SET) }                         \
  if ((s_) + 5 < nt) { LOADSET(SET, ((s_) + 5) * 64) }         \
  LGKM_BARRIER

  // prologue: fill all 4 sets (steps 0..3), stage step 0, refill set A w/ step 4
  LOADSET(A, 0)
  LOADSET(B, 64)
  LOADSET(C, 128)
  LOADSET(D, 192)
  STORESET(A)
  if (4 < nt) { LOADSET(A, 256) }
  LGKM_BARRIER

  for (int s = 0; s < nt; s += 4) {
    PHASE(s, B)
    PHASE(s + 1, C)
    PHASE(s + 2, D)
    PHASE(s + 3, A)
  }
#undef LOADSET
#undef STORESET
#undef PHASE
#undef BARRIER_PINNED
#undef LGKM_BARRIER

  float* Cz = Cpart + (size_t)blockIdx.y * 256 * N;
  const int rh = (lane >> 4) * 4, col = lane & 15;
#pragma unroll
  for (int i = 0; i < 4; ++i)
#pragma unroll
    for (int j = 0; j < 2; ++j)
#pragma unroll
      for (int rr = 0; rr < 4; ++rr)
        Cz[(size_t)(wm + 16 * i + rh + rr) * N + n0 + wn + 16 * j + col] = acc[i][j][rr];
}

// ============================================================================
// generic MFMA GEMM (64x64 tile) -- only used for the small qproj GEMM
// A bf16, B f32, f32 split-K partial out
// ============================================================================
__global__ __launch_bounds__(256) void gemm_small(
    const bf16_t* __restrict__ A16, const float* __restrict__ B32, float* __restrict__ Cv,
    int M, int N, int K, int KS, int S) {
  __shared__ bf16_t As[64][72];
  __shared__ bf16_t Bs[64][72];
  const int t = threadIdx.x;
  const int lane = t & 63;
  const int w = t >> 6;
  const int s = blockIdx.z;
  const int n0 = blockIdx.x * 64;
  const int m0 = blockIdx.y * 64;
  const int kbeg = s * KS;

  f32x4 acc[2][2];
#pragma unroll
  for (int i = 0; i < 2; ++i)
#pragma unroll
    for (int j = 0; j < 2; ++j) acc[i][j] = f32x4{0.f, 0.f, 0.f, 0.f};

  const int wm = (w & 1) * 32, wn = (w >> 1) * 32;
  const int fr = lane & 15;
  const int kq = (lane >> 4) * 8;

  for (int k0 = kbeg; k0 < kbeg + KS; k0 += 64) {
    bf16x8 a8[2];
    float4 b4[4];
    {
      const int rr = t >> 2, c8 = (t & 3) * 8;
#pragma unroll
      for (int i = 0; i < 2; ++i)
        a8[i] = *(const bf16x8*)(A16 + (size_t)(m0 + rr) * K + k0 + c8 + 32 * i);
    }
    {
      const int rr = t >> 4, c4 = (t & 15) * 4;
#pragma unroll
      for (int i = 0; i < 4; ++i)
        b4[i] = *(const float4*)(B32 + (size_t)(n0 + rr + 16 * i) * K + k0 + c4);
    }
    __syncthreads();
    {
      const int rr = t >> 2, c8 = (t & 3) * 8;
#pragma unroll
      for (int i = 0; i < 2; ++i) *(bf16x8*)&As[rr][c8 + 32 * i] = a8[i];
    }
    {
      const int rr = t >> 4, c4 = (t & 15) * 4;
#pragma unroll
      for (int i = 0; i < 4; ++i) {
        bf16x4 v = {(bf16_t)b4[i].x, (bf16_t)b4[i].y, (bf16_t)b4[i].z, (bf16_t)b4[i].w};
        *(bf16x4*)&Bs[rr + 16 * i][c4] = v;
      }
    }
    __syncthreads();
#pragma unroll
    for (int kk = 0; kk < 64; kk += 32) {
      bf16x8 af[2], bg[2];
#pragma unroll
      for (int i = 0; i < 2; ++i) {
        af[i] = *(const bf16x8*)&As[wm + 16 * i + fr][kk + kq];
        bg[i] = *(const bf16x8*)&Bs[wn + 16 * i + fr][kk + kq];
      }
#pragma unroll
      for (int i = 0; i < 2; ++i)
#pragma unroll
        for (int j = 0; j < 2; ++j)
          acc[i][j] = __builtin_amdgcn_mfma_f32_16x16x32_bf16(af[i], bg[j], acc[i][j], 0, 0, 0);
    }
    __syncthreads();
  }

  const int rh = (lane >> 4) * 4;
  const int col = lane & 15;
#pragma unroll
  for (int i = 0; i < 2; ++i)
#pragma unroll
    for (int j = 0; j < 2; ++j)
#pragma unroll
      for (int rr = 0; rr < 4; ++rr)
        Cv[(size_t)s * M * N + (size_t)(m0 + wm + 16 * i + rh + rr) * N + n0 + wn + 16 * j + col] =
            acc[i][j][rr];
}

// ============================================================================
// gemm_attn: per-batch C(128,4096)bf16 = A(128,256)f32 @ B(256,4096)f32
// ============================================================================
__global__ __launch_bounds__(256) void gemm_attn(
    const float* __restrict__ A, const float* __restrict__ B, bf16_t* __restrict__ C) {
  __shared__ bf16_t As[64][72];
  __shared__ bf16_t Bs[64][72];  // Bs[n][k]
  const int t = threadIdx.x;
  const int lane = t & 63;
  const int w = t >> 6;
  const int b = blockIdx.z;
  const int n0 = blockIdx.x * 64;
  const int m0 = blockIdx.y * 64;
  const float* Ab = A + (size_t)b * 32768;
  const float* Bb = B + (size_t)b * 1048576;

  f32x4 acc[2][2];
#pragma unroll
  for (int i = 0; i < 2; ++i)
#pragma unroll
    for (int j = 0; j < 2; ++j) acc[i][j] = f32x4{0.f, 0.f, 0.f, 0.f};

  const int wm = (w & 1) * 32, wn = (w >> 1) * 32;
  const int fr = lane & 15;
  const int kq = (lane >> 4) * 8;

  for (int k0 = 0; k0 < 256; k0 += 64) {
    {
      const int rr = t >> 4, c4 = (t & 15) * 4;
      float4 a4[4];
#pragma unroll
      for (int i = 0; i < 4; ++i)
        a4[i] = *(const float4*)(Ab + (size_t)(m0 + rr + 16 * i) * 256 + k0 + c4);
      __syncthreads();
#pragma unroll
      for (int i = 0; i < 4; ++i) {
        bf16x4 v = {(bf16_t)a4[i].x, (bf16_t)a4[i].y, (bf16_t)a4[i].z, (bf16_t)a4[i].w};
        *(bf16x4*)&As[rr + 16 * i][c4] = v;
      }
    }
    {
      const int kr = t >> 2, nc = (t & 3) * 16;
      float4 b4[4];
#pragma unroll
      for (int i = 0; i < 4; ++i)
        b4[i] = *(const float4*)(Bb + (size_t)(k0 + kr) * 4096 + n0 + nc + 4 * i);
#pragma unroll
      for (int i = 0; i < 4; ++i) {
        Bs[nc + 4 * i + 0][kr] = (bf16_t)b4[i].x;
        Bs[nc + 4 * i + 1][kr] = (bf16_t)b4[i].y;
        Bs[nc + 4 * i + 2][kr] = (bf16_t)b4[i].z;
        Bs[nc + 4 * i + 3][kr] = (bf16_t)b4[i].w;
      }
    }
    __syncthreads();
#pragma unroll
    for (int kk = 0; kk < 64; kk += 32) {
      bf16x8 af[2], bg[2];
#pragma unroll
      for (int i = 0; i < 2; ++i) {
        af[i] = *(const bf16x8*)&As[wm + 16 * i + fr][kk + kq];
        bg[i] = *(const bf16x8*)&Bs[wn + 16 * i + fr][kk + kq];
      }
#pragma unroll
      for (int i = 0; i < 2; ++i)
#pragma unroll
        for (int j = 0; j < 2; ++j)
          acc[i][j] = __builtin_amdgcn_mfma_f32_16x16x32_bf16(af[i], bg[j], acc[i][j], 0, 0, 0);
    }
    __syncthreads();
  }

  bf16_t* Cb = C + (size_t)b * 524288;
  const int rh = (lane >> 4) * 4, col = lane & 15;
#pragma unroll
  for (int i = 0; i < 2; ++i)
#pragma unroll
    for (int j = 0; j < 2; ++j)
#pragma unroll
      for (int rr = 0; rr < 4; ++rr)
        Cb[(size_t)(m0 + wm + 16 * i + rh + rr) * 4096 + n0 + wn + 16 * j + col] =
            (bf16_t)acc[i][j][rr];
}

// ---------------- split-K reduce + bias + silu epilogue ----------------
template <int SILU_, int BIAS_>
__global__ __launch_bounds__(256) void reduce_k(
    const float* __restrict__ part, int S, long slice,
    const float* __restrict__ bias, float scale,
    float* __restrict__ outF, bf16_t* __restrict__ outB,
    int nmask, long total4) {
  long i4 = (long)blockIdx.x * 256 + threadIdx.x;
  if (i4 >= total4) return;
  long i = i4 * 4;
  float4 v = *(const float4*)(part + i);
  for (int s = 1; s < S; ++s) {
    float4 u = *(const float4*)(part + (size_t)s * slice + i);
    v.x += u.x; v.y += u.y; v.z += u.z; v.w += u.w;
  }
  v.x *= scale; v.y *= scale; v.z *= scale; v.w *= scale;
  if (BIAS_) {
    float4 bb = *(const float4*)(bias + (i & nmask));
    v.x += bb.x; v.y += bb.y; v.z += bb.z; v.w += bb.w;
  }
  if (SILU_) { v.x = silu_f(v.x); v.y = silu_f(v.y); v.z = silu_f(v.z); v.w = silu_f(v.w); }
  if (outF) *(float4*)(outF + i) = v;
  if (outB) {
    bf16x4 o = {(bf16_t)v.x, (bf16_t)v.y, (bf16_t)v.z, (bf16_t)v.w};
    *(bf16x4*)(outB + i) = o;
  }
}

// ---------------- LayerNorm over rows = concat(X1[L1], X2[L2]) -> bf16 ----------------
__global__ __launch_bounds__(256) void ln_rows(
    const float* __restrict__ X1, const float* __restrict__ X2, int L1, int L2,
    const float* __restrict__ g, const float* __restrict__ bta, bf16_t* __restrict__ Y) {
  __shared__ float tmp[4];
  const int row = blockIdx.x;
  const int L = L1 + L2;
  const float* x1 = X1 + (size_t)row * L1;
  const float* x2 = X2 ? X2 + (size_t)row * L2 : nullptr;
  float s = 0.f, ss = 0.f;
  for (int i = threadIdx.x * 4; i < L1; i += 1024) {
    float4 v = *(const float4*)(x1 + i);
    s += v.x + v.y + v.z + v.w;
    ss += v.x * v.x + v.y * v.y + v.z * v.z + v.w * v.w;
  }
  for (int i = threadIdx.x * 4; i < L2; i += 1024) {
    float4 v = *(const float4*)(x2 + i);
    s += v.x + v.y + v.z + v.w;
    ss += v.x * v.x + v.y * v.y + v.z * v.z + v.w * v.w;
  }
  s = block_sum(s, tmp);
  ss = block_sum(ss, tmp);
  const float mu = s / (float)L;
  const float inv = rsqrtf(ss / (float)L - mu * mu + EPS);
  bf16_t* y = Y + (size_t)row * L;
  for (int i = threadIdx.x * 4; i < L1; i += 1024) {
    float4 v = *(const float4*)(x1 + i);
    float4 gv = *(const float4*)(g + i);
    float4 bv = *(const float4*)(bta + i);
    bf16x4 o = {(bf16_t)((v.x - mu) * inv * gv.x + bv.x),
                (bf16_t)((v.y - mu) * inv * gv.y + bv.y),
                (bf16_t)((v.z - mu) * inv * gv.z + bv.z),
                (bf16_t)((v.w - mu) * inv * gv.w + bv.w)};
    *(bf16x4*)(y + i) = o;
  }
  for (int i = threadIdx.x * 4; i < L2; i += 1024) {
    float4 v = *(const float4*)(x2 + i);
    float4 gv = *(const float4*)(g + L1 + i);
    float4 bv = *(const float4*)(bta + L1 + i);
    bf16x4 o = {(bf16_t)((v.x - mu) * inv * gv.x + bv.x),
                (bf16_t)((v.y - mu) * inv * gv.y + bv.y),
                (bf16_t)((v.z - mu) * inv * gv.z + bv.z),
                (bf16_t)((v.w - mu) * inv * gv.w + bv.w)};
    *(bf16x4*)(y + L1 + i) = o;
  }
}

// ---------------- QW[bk,h,c] = sum_d Q[bk,h*64+d] * kW[h*64+d, c] ----------------
__global__ __launch_bounds__(256) void qw_kernel(
    const float* __restrict__ Q, const float* __restrict__ kW, float* __restrict__ QW) {
  __shared__ float q[256];
  const int bk = blockIdx.x;
  q[threadIdx.x] = Q[(size_t)bk * 256 + threadIdx.x];
  __syncthreads();
  const int c = threadIdx.x;
#pragma unroll
  for (int h = 0; h < 4; ++h) {
    float s = 0.f;
#pragma unroll 8
    for (int d = 0; d < 64; ++d)
      s += q[(h << 6) + d] * kW[(size_t)(((h << 6) + d) << 8) + c];
    QW[((size_t)(bk * 4 + h) << 8) + c] = s;
  }
}

// ---------------- fused conv1(4->4,silu) + conv2(4->1) + bilinear up 64->256 ----------------
__global__ __launch_bounds__(256) void conv_fused(
    const bf16_t* __restrict__ X, const float* __restrict__ W1,
    const float* __restrict__ B1, const float* __restrict__ W2,
    const float* __restrict__ B2, float* __restrict__ O) {
  __shared__ bf16_t lg[16384];
  __shared__ bf16_t mid[16384];
  __shared__ float lg64[4096];
  __shared__ float wsh[180];
  const int t = threadIdx.x;
  const size_t base = (size_t)blockIdx.x * 16384;
#pragma unroll
  for (int i = 0; i < 8; ++i) {
    int o = (i * 256 + t) * 8;
    *(bf16x8*)&lg[o] = *(const bf16x8*)(X + base + o);
  }
  if (t < 144) wsh[t] = W1[t];
  else if (t < 180) wsh[t] = W2[t - 144];
  __syncthreads();
  const int px0 = (t & 15) * 4, py0 = (t >> 4) * 4;
  // ---- conv1: 4->4 + bias + silu ----
  {
    float acc1[4][16];
#pragma unroll
    for (int oc = 0; oc < 4; ++oc) {
      float bb = B1[oc];
#pragma unroll
      for (int p = 0; p < 16; ++p) acc1[oc][p] = bb;
    }
#pragma unroll
    for (int c = 0; c < 4; ++c) {
      float p[6][6];
#pragma unroll
      for (int yy = 0; yy < 6; ++yy) {
        int gy = py0 + yy - 1;
#pragma unroll
        for (int xx = 0; xx < 6; ++xx) {
          int gx = px0 + xx - 1;
          p[yy][xx] = ((unsigned)gy < 64u && (unsigned)gx < 64u)
                          ? (float)lg[c * 4096 + gy * 64 + gx] : 0.f;
        }
      }
#pragma unroll
      for (int oc = 0; oc < 4; ++oc) {
        float wr[9];
#pragma unroll
        for (int k = 0; k < 9; ++k) wr[k] = wsh[oc * 36 + c * 9 + k];
#pragma unroll
        for (int y = 0; y < 4; ++y)
#pragma unroll
          for (int x = 0; x < 4; ++x)
            acc1[oc][y * 4 + x] +=
                wr[0] * p[y][x] + wr[1] * p[y][x + 1] + wr[2] * p[y][x + 2]
              + wr[3] * p[y + 1][x] + wr[4] * p[y + 1][x + 1] + wr[5] * p[y + 1][x + 2]
              + wr[6] * p[y + 2][x] + wr[7] * p[y + 2][x + 1] + wr[8] * p[y + 2][x + 2];
      }
    }
#pragma unroll
    for (int oc = 0; oc < 4; ++oc)
#pragma unroll
      for (int y = 0; y < 4; ++y) {
        bf16x4 o;
#pragma unroll
        for (int x = 0; x < 4; ++x) o[x] = (bf16_t)silu_f(acc1[oc][y * 4 + x]);
        *(bf16x4*)&mid[oc * 4096 + (py0 + y) * 64 + px0] = o;
      }
  }
  __syncthreads();
  // ---- conv2: 4->1 + bias ----
  {
    float acc2[16];
    float bb = B2[0];
#pragma unroll
    for (int p = 0; p < 16; ++p) acc2[p] = bb;
#pragma unroll
    for (int c = 0; c < 4; ++c) {
      float p[6][6];
#pragma unroll
      for (int yy = 0; yy < 6; ++yy) {
        int gy = py0 + yy - 1;
#pragma unroll
        for (int xx = 0; xx < 6; ++xx) {
          int gx = px0 + xx - 1;
          p[yy][xx] = ((unsigned)gy < 64u && (unsigned)gx < 64u)
                          ? (float)mid[c * 4096 + gy * 64 + gx] : 0.f;
        }
      }
      float wr[9];
#pragma unroll
      for (int k = 0; k < 9; ++k) wr[k] = wsh[144 + c * 9 + k];
#pragma unroll
      for (int y = 0; y < 4; ++y)
#pragma unroll
        for (int x = 0; x < 4; ++x)
          acc2[y * 4 + x] +=
              wr[0] * p[y][x] + wr[1] * p[y][x + 1] + wr[2] * p[y][x + 2]
            + wr[3] * p[y + 1][x] + wr[4] * p[y + 1][x + 1] + wr[5] * p[y + 1][x + 2]
            + wr[6] * p[y + 2][x] + wr[7] * p[y + 2][x + 1] + wr[8] * p[y + 2][x + 2];
    }
#pragma unroll
    for (int y = 0; y < 4; ++y)
#pragma unroll
      for (int x = 0; x < 4; ++x) lg64[(py0 + y) * 64 + px0 + x] = acc2[y * 4 + x];
  }
  __syncthreads();
  // ---- bilinear upsample 64 -> 256 (half-pixel centers, edge clamp) ----
  float* Ob = O + (size_t)blockIdx.x * 65536;
  for (int rr = 0; rr < 64; ++rr) {
    int p4 = rr * 256 + t;
    int oy = p4 >> 6, ox0 = (p4 & 63) * 4;
    float sy = oy * 0.25f - 0.375f;
    int y0 = (int)floorf(sy);
    float wy = sy - (float)y0;
    int y1 = min(y0 + 1, 63); y0 = max(y0, 0);
    const float* r0 = &lg64[y0 * 64];
    const float* r1 = &lg64[y1 * 64];
    float4 o;
#pragma unroll
    for (int q = 0; q < 4; ++q) {
      int ox = ox0 + q;
      float sx = ox * 0.25f - 0.375f;
      int x0 = (int)floorf(sx);
      float wx = sx - (float)x0;
      int x1 = min(x0 + 1, 63); x0 = max(x0, 0);
      float v0 = r0[x0] + wx * (r0[x1] - r0[x0]);
      float v1 = r1[x0] + wx * (r1[x1] - r1[x0]);
      ((float*)&o)[q] = v0 + wy * (v1 - v0);
    }
    *(float4*)(Ob + oy * 256 + ox0) = o;
  }
}

// ---------------- confidence: out[row] = dot(cfh_row, w2) + b2 ----------------
__global__ __launch_bounds__(256) void conf_k(
    const float* __restrict__ cfh, const float* __restrict__ w2,
    const float* __restrict__ b2, float* __restrict__ out) {
  __shared__ float tmp[4];
  const int row = blockIdx.x;
  float s = 0.f;
  for (int i = threadIdx.x; i < 2048; i += 256)
    s += cfh[(size_t)row * 2048 + i] * w2[i];
  s = block_sum(s, tmp);
  if (threadIdx.x == 0) out[row] = s + b2[0];
}

extern "C" void kernel_launch(void* const* d_in, const int* in_sizes, int n_in,
                              void* d_out, int out_size, void* d_ws, size_t ws_size,
                              hipStream_t stream) {
  const float* img    = (const float*)d_in[0];
  const float* refv   = (const float*)d_in[1];
  const float* qs     = (const float*)d_in[2];
  const float* qpw    = (const float*)d_in[3];
  const float* kpw    = (const float*)d_in[4];
  const float* fw1    = (const float*)d_in[5];
  const float* fb1    = (const float*)d_in[6];
  const float* fw2    = (const float*)d_in[7];
  const float* fb2    = (const float*)d_in[8];
  const float* qbw    = (const float*)d_in[9];
  const float* rlg    = (const float*)d_in[10];
  const float* rlb    = (const float*)d_in[11];
  const float* rlw    = (const float*)d_in[12];
  const float* rlbias = (const float*)d_in[13];
  const float* clg    = (const float*)d_in[14];
  const float* clb    = (const float*)d_in[15];
  const float* cw1    = (const float*)d_in[16];
  const float* cb1    = (const float*)d_in[17];
  const float* cw2    = (const float*)d_in[18];
  const float* cb2    = (const float*)d_in[19];
  float* out = (float*)d_out;
  char* W = (char*)d_ws;

  // --- workspace layout (bytes); lifetimes disjoint within each region ---
  float*  partF = (float*)(W + 0);           // 33.55 MB steps 5-6
  bf16_t* l64hb = (bf16_t*)(W + 0);          //  8.39 MB steps 10-11
  float*  partC = (float*)(W + 0);           // 33.55 MB steps 13-14
  bf16_t* catln = (bf16_t*)(W + 33554432);   //  4.19 MB steps 4-5
  float*  fus   = (float*)(W + 33554432);    //  4.19 MB steps 6-12 (catln dead)
  float*  qbf   = (float*)(W + 37748736);    //  4.19 MB steps 3-4
  bf16_t* fusb  = (bf16_t*)(W + 37748736);   //  2.10 MB steps 6-7 (qbf dead)
  bf16_t* lnf   = (bf16_t*)(W + 37748736);   //  2.10 MB steps 12-13 (fusb dead)
  float*  partQ = (float*)(W + 41943040);    //  8.39 MB steps 2-3
  float*  part8 = (float*)(W + 41943040);    //  2.10 MB steps 7-8 (partQ dead)
  float*  Qb    = (float*)(W + 44040192);    //  0.26 MB steps 8-9
  float*  QW    = (float*)(W + 44302336);    //  1.05 MB steps 9-10
  float*  cfh   = (float*)(W + 45350912);    //  2.10 MB steps 14-15
  bf16_t* qsb   = (bf16_t*)(W + 47448064);   //  0.26 MB steps 1-2

  dim3 b256(256);
  dim3 b1024(1024);

  // 1. qsb = bf16(querybook_slots)
  cast_k<<<dim3(64), b256, 0, stream>>>(qs, qsb, 16384);
  // 2. qb GEMM (split-K x2): partQ[s] = qsb @ qbw^T chunk
  gemm_wide<<<dim3(32, 2), b1024, 0, stream>>>(qsb, qbw, partQ, 4096, 512, 256);
  // 3. qbf = sum partQ
  reduce_k<0, 0><<<dim3(1024), b256, 0, stream>>>(
      partQ, 2, 1048576L, nullptr, 1.f, qbf, nullptr, 0, 262144L);
  // 4. catln = LN(concat(ref_vec, qbf)) -> bf16
  ln_rows<<<dim3(256), b256, 0, stream>>>(refv, qbf, 4096, 4096, rlg, rlb, catln);
  // 5. fused GEMM (split-K x8): partF[s] = catln @ rlw^T chunk
  gemm_wide<<<dim3(32, 8), b1024, 0, stream>>>(catln, rlw, partF, 4096, 8192, 1024);
  // 6. fus = silu(sum partF + bias) -> f32 + bf16
  reduce_k<1, 1><<<dim3(1024), b256, 0, stream>>>(
      partF, 8, 1048576L, rlbias, 1.f, fus, fusb, 4095, 262144L);
  // 7. qproj GEMM (split-K x8): part8[s] = fusb @ qpw^T chunk
  gemm_small<<<dim3(4, 4, 8), b256, 0, stream>>>(fusb, qpw, part8, 256, 256, 4096, 512, 8);
  // 8. Qb = 0.125 * sum part8
  reduce_k<0, 0><<<dim3(64), b256, 0, stream>>>(
      part8, 8, 65536L, nullptr, 0.125f, Qb, nullptr, 0, 16384L);
  // 9. QW = per-head Q @ k_proj
  qw_kernel<<<dim3(256), b256, 0, stream>>>(Qb, kpw, QW);
  // 10. logits: l64hb[b] = QW_b @ img_b
  gemm_attn<<<dim3(64, 2, 8), b256, 0, stream>>>(QW, img, l64hb);
  // 11. out = upsample(conv2(silu(conv1(l64hb))))
  conv_fused<<<dim3(256), b256, 0, stream>>>(l64hb, fw1, fb1, fw2, fb2, out);
  // 12. lnf = LN(fus) -> bf16
  ln_rows<<<dim3(256), b256, 0, stream>>>(fus, nullptr, 4096, 0, clg, clb, lnf);
  // 13. cfh GEMM (split-K x16): partC[s] = lnf @ cw1^T chunk
  gemm_wide<<<dim3(16, 16), b1024, 0, stream>>>(lnf, cw1, partC, 2048, 4096, 256);
  // 14. cfh = silu(sum partC + cb1)
  reduce_k<1, 1><<<dim3(512), b256, 0, stream>>>(
      partC, 16, 524288L, cb1, 1.f, cfh, nullptr, 2047, 131072L);
  // 15. conf out
  conf_k<<<dim3(256), b256, 0, stream>>>(cfh, cw2, cb2, out + 16777216);
}

// Round 7
// 195.027 us; speedup vs baseline: 7.2616x; 1.0471x over previous
//
#include <hip/hip_runtime.h>

#define EPS 1e-5f

typedef __bf16 bf16_t;
typedef __bf16 bf16x8 __attribute__((ext_vector_type(8)));
typedef __bf16 bf16x4 __attribute__((ext_vector_type(4)));
typedef float f32x4 __attribute__((ext_vector_type(4)));

__device__ __forceinline__ float silu_f(float x) { return x / (1.f + __expf(-x)); }

// ---------------- block reduction (256 threads = 4 waves) ----------------
__device__ __forceinline__ float block_sum(float v, float* tmp) {
#pragma unroll
  for (int off = 32; off > 0; off >>= 1) v += __shfl_down(v, off);
  __syncthreads();
  if ((threadIdx.x & 63) == 0) tmp[threadIdx.x >> 6] = v;
  __syncthreads();
  return tmp[0] + tmp[1] + tmp[2] + tmp[3];
}

// ============================================================================
// gemm_wide: Cpart[z](bf16) = A(256,K)bf16 @ B(N,K)^T f32  (fat weight GEMMs)
// tile 256x128 (FULL M -> B read exactly once), BK=64, 1024 threads (16 waves,
// wave-tile 64x32). Single 54KB LDS buffer, 4-deep named register pipeline,
// pinned s_barrier + lgkmcnt(0) phases (vmcnt stays counted). nt = KS/64 must
// be a multiple of 4 (>=4). Grid: (N/128, S). Partials written as bf16.
// ============================================================================
__global__ __launch_bounds__(1024, 4) void gemm_wide(
    const bf16_t* __restrict__ A, const float* __restrict__ B,
    bf16_t* __restrict__ Cpart, int N, int K, int KS) {
  __shared__ bf16_t As[256][72];
  __shared__ bf16_t Bs[128][72];
  const int t = threadIdx.x;
  const int lane = t & 63;
  const int w = t >> 6;  // 0..15
  const int n0 = blockIdx.x * 128;
  const int kbeg = blockIdx.y * KS;
  const int nt = KS >> 6;
  const int ar = t >> 2, ac = (t & 3) * 16;
  const int br = t >> 3, bc = (t & 7) * 8;
  const bf16_t* Ap = A + (size_t)ar * K + kbeg + ac;
  const float* Bp = B + (size_t)(n0 + br) * K + kbeg + bc;

  bf16x8 a0A, a1A, a0B, a1B, a0C, a1C, a0D, a1D;
  float4 b0A, b1A, b0B, b1B, b0C, b1C, b0D, b1D;

#define LOADSET(S, k0)                            \
  a0##S = *(const bf16x8*)(Ap + (k0));            \
  a1##S = *(const bf16x8*)(Ap + (k0) + 8);        \
  b0##S = *(const float4*)(Bp + (k0));            \
  b1##S = *(const float4*)(Bp + (k0) + 4);

#define STORESET(S)                                                         \
  {                                                                         \
    *(bf16x8*)&As[ar][ac] = a0##S;                                          \
    *(bf16x8*)&As[ar][ac + 8] = a1##S;                                      \
    bf16x8 wv;                                                              \
    wv[0] = (bf16_t)b0##S.x; wv[1] = (bf16_t)b0##S.y;                       \
    wv[2] = (bf16_t)b0##S.z; wv[3] = (bf16_t)b0##S.w;                       \
    wv[4] = (bf16_t)b1##S.x; wv[5] = (bf16_t)b1##S.y;                       \
    wv[6] = (bf16_t)b1##S.z; wv[7] = (bf16_t)b1##S.w;                       \
    *(bf16x8*)&Bs[br][bc] = wv;                                             \
  }

#define BARRIER_PINNED                 \
  __builtin_amdgcn_sched_barrier(0);   \
  __builtin_amdgcn_s_barrier();        \
  __builtin_amdgcn_sched_barrier(0);

#define LGKM_BARRIER                                   \
  asm volatile("s_waitcnt lgkmcnt(0)" ::: "memory");   \
  BARRIER_PINNED

  f32x4 acc[4][2];
#pragma unroll
  for (int i = 0; i < 4; ++i)
#pragma unroll
    for (int j = 0; j < 2; ++j) acc[i][j] = f32x4{0.f, 0.f, 0.f, 0.f};

  const int wm = (w & 3) * 64;
  const int wn = (w >> 2) * 32;
  const int fr = lane & 15;
  const int kq = (lane >> 4) * 8;

  auto COMPUTE = [&]() {
#pragma unroll
    for (int kk = 0; kk < 64; kk += 32) {
      bf16x8 af[4], bg[2];
#pragma unroll
      for (int i = 0; i < 4; ++i)
        af[i] = *(const bf16x8*)&As[wm + 16 * i + fr][kk + kq];
#pragma unroll
      for (int j = 0; j < 2; ++j)
        bg[j] = *(const bf16x8*)&Bs[wn + 16 * j + fr][kk + kq];
#pragma unroll
      for (int i = 0; i < 4; ++i)
#pragma unroll
        for (int j = 0; j < 2; ++j)
          acc[i][j] = __builtin_amdgcn_mfma_f32_16x16x32_bf16(af[i], bg[j], acc[i][j], 0, 0, 0);
    }
  };

#define PHASE(s_, SET)                                         \
  COMPUTE();                                                   \
  BARRIER_PINNED                                               \
  if ((s_) + 1 < nt) { STORESET(SET) }                         \
  if ((s_) + 5 < nt) { LOADSET(SET, ((s_) + 5) * 64) }         \
  LGKM_BARRIER

  LOADSET(A, 0)
  LOADSET(B, 64)
  LOADSET(C, 128)
  LOADSET(D, 192)
  STORESET(A)
  if (4 < nt) { LOADSET(A, 256) }
  LGKM_BARRIER

  for (int s = 0; s < nt; s += 4) {
    PHASE(s, B)
    PHASE(s + 1, C)
    PHASE(s + 2, D)
    PHASE(s + 3, A)
  }
#undef LOADSET
#undef STORESET
#undef PHASE

  bf16_t* Cz = Cpart + (size_t)blockIdx.y * 256 * N;
  const int rh = (lane >> 4) * 4, col = lane & 15;
#pragma unroll
  for (int i = 0; i < 4; ++i)
#pragma unroll
    for (int j = 0; j < 2; ++j)
#pragma unroll
      for (int rr = 0; rr < 4; ++rr)
        Cz[(size_t)(wm + 16 * i + rh + rr) * N + n0 + wn + 16 * j + col] =
            (bf16_t)acc[i][j][rr];
}

// ============================================================================
// gemm_wide_s: simple (non-pipelined) 256x128 variant, A is f32 (qb GEMM).
// Any nt >= 1. Grid: (N/128, S). bf16 partial out.
// ============================================================================
__global__ __launch_bounds__(1024) void gemm_wide_s(
    const float* __restrict__ A, const float* __restrict__ B,
    bf16_t* __restrict__ Cpart, int N, int K, int KS) {
  __shared__ bf16_t As[256][72];
  __shared__ bf16_t Bs[128][72];
  const int t = threadIdx.x;
  const int lane = t & 63;
  const int w = t >> 6;
  const int n0 = blockIdx.x * 128;
  const int kbeg = blockIdx.y * KS;
  const int nt = KS >> 6;
  const int ar = t >> 2, ac = (t & 3) * 16;
  const int br = t >> 3, bc = (t & 7) * 8;
  const float* Ap = A + (size_t)ar * K + kbeg + ac;
  const float* Bp = B + (size_t)(n0 + br) * K + kbeg + bc;

  f32x4 acc[4][2];
#pragma unroll
  for (int i = 0; i < 4; ++i)
#pragma unroll
    for (int j = 0; j < 2; ++j) acc[i][j] = f32x4{0.f, 0.f, 0.f, 0.f};

  const int wm = (w & 3) * 64;
  const int wn = (w >> 2) * 32;
  const int fr = lane & 15;
  const int kq = (lane >> 4) * 8;

  for (int s = 0; s < nt; ++s) {
    float4 av[4], bv[2];
#pragma unroll
    for (int i = 0; i < 4; ++i) av[i] = *(const float4*)(Ap + s * 64 + 4 * i);
#pragma unroll
    for (int i = 0; i < 2; ++i) bv[i] = *(const float4*)(Bp + s * 64 + 4 * i);
    __syncthreads();
    {
      bf16x8 wa0, wa1, wb;
      wa0[0] = (bf16_t)av[0].x; wa0[1] = (bf16_t)av[0].y; wa0[2] = (bf16_t)av[0].z; wa0[3] = (bf16_t)av[0].w;
      wa0[4] = (bf16_t)av[1].x; wa0[5] = (bf16_t)av[1].y; wa0[6] = (bf16_t)av[1].z; wa0[7] = (bf16_t)av[1].w;
      wa1[0] = (bf16_t)av[2].x; wa1[1] = (bf16_t)av[2].y; wa1[2] = (bf16_t)av[2].z; wa1[3] = (bf16_t)av[2].w;
      wa1[4] = (bf16_t)av[3].x; wa1[5] = (bf16_t)av[3].y; wa1[6] = (bf16_t)av[3].z; wa1[7] = (bf16_t)av[3].w;
      wb[0] = (bf16_t)bv[0].x; wb[1] = (bf16_t)bv[0].y; wb[2] = (bf16_t)bv[0].z; wb[3] = (bf16_t)bv[0].w;
      wb[4] = (bf16_t)bv[1].x; wb[5] = (bf16_t)bv[1].y; wb[6] = (bf16_t)bv[1].z; wb[7] = (bf16_t)bv[1].w;
      *(bf16x8*)&As[ar][ac] = wa0;
      *(bf16x8*)&As[ar][ac + 8] = wa1;
      *(bf16x8*)&Bs[br][bc] = wb;
    }
    __syncthreads();
#pragma unroll
    for (int kk = 0; kk < 64; kk += 32) {
      bf16x8 af[4], bg[2];
#pragma unroll
      for (int i = 0; i < 4; ++i)
        af[i] = *(const bf16x8*)&As[wm + 16 * i + fr][kk + kq];
#pragma unroll
      for (int j = 0; j < 2; ++j)
        bg[j] = *(const bf16x8*)&Bs[wn + 16 * j + fr][kk + kq];
#pragma unroll
      for (int i = 0; i < 4; ++i)
#pragma unroll
        for (int j = 0; j < 2; ++j)
          acc[i][j] = __builtin_amdgcn_mfma_f32_16x16x32_bf16(af[i], bg[j], acc[i][j], 0, 0, 0);
    }
    __syncthreads();
  }

  bf16_t* Cz = Cpart + (size_t)blockIdx.y * 256 * N;
  const int rh = (lane >> 4) * 4, col = lane & 15;
#pragma unroll
  for (int i = 0; i < 4; ++i)
#pragma unroll
    for (int j = 0; j < 2; ++j)
#pragma unroll
      for (int rr = 0; rr < 4; ++rr)
        Cz[(size_t)(wm + 16 * i + rh + rr) * N + n0 + wn + 16 * j + col] =
            (bf16_t)acc[i][j][rr];
}

// ============================================================================
// gemm_small (64x64 tile) -- qproj GEMM. A bf16, B f32, f32 split-K partials.
// ============================================================================
__global__ __launch_bounds__(256) void gemm_small(
    const bf16_t* __restrict__ A16, const float* __restrict__ B32, float* __restrict__ Cv,
    int M, int N, int K, int KS, int S) {
  __shared__ bf16_t As[64][72];
  __shared__ bf16_t Bs[64][72];
  const int t = threadIdx.x;
  const int lane = t & 63;
  const int w = t >> 6;
  const int s = blockIdx.z;
  const int n0 = blockIdx.x * 64;
  const int m0 = blockIdx.y * 64;
  const int kbeg = s * KS;

  f32x4 acc[2][2];
#pragma unroll
  for (int i = 0; i < 2; ++i)
#pragma unroll
    for (int j = 0; j < 2; ++j) acc[i][j] = f32x4{0.f, 0.f, 0.f, 0.f};

  const int wm = (w & 1) * 32, wn = (w >> 1) * 32;
  const int fr = lane & 15;
  const int kq = (lane >> 4) * 8;

  for (int k0 = kbeg; k0 < kbeg + KS; k0 += 64) {
    bf16x8 a8[2];
    float4 b4[4];
    {
      const int rr = t >> 2, c8 = (t & 3) * 8;
#pragma unroll
      for (int i = 0; i < 2; ++i)
        a8[i] = *(const bf16x8*)(A16 + (size_t)(m0 + rr) * K + k0 + c8 + 32 * i);
    }
    {
      const int rr = t >> 4, c4 = (t & 15) * 4;
#pragma unroll
      for (int i = 0; i < 4; ++i)
        b4[i] = *(const float4*)(B32 + (size_t)(n0 + rr + 16 * i) * K + k0 + c4);
    }
    __syncthreads();
    {
      const int rr = t >> 2, c8 = (t & 3) * 8;
#pragma unroll
      for (int i = 0; i < 2; ++i) *(bf16x8*)&As[rr][c8 + 32 * i] = a8[i];
    }
    {
      const int rr = t >> 4, c4 = (t & 15) * 4;
#pragma unroll
      for (int i = 0; i < 4; ++i) {
        bf16x4 v = {(bf16_t)b4[i].x, (bf16_t)b4[i].y, (bf16_t)b4[i].z, (bf16_t)b4[i].w};
        *(bf16x4*)&Bs[rr + 16 * i][c4] = v;
      }
    }
    __syncthreads();
#pragma unroll
    for (int kk = 0; kk < 64; kk += 32) {
      bf16x8 af[2], bg[2];
#pragma unroll
      for (int i = 0; i < 2; ++i) {
        af[i] = *(const bf16x8*)&As[wm + 16 * i + fr][kk + kq];
        bg[i] = *(const bf16x8*)&Bs[wn + 16 * i + fr][kk + kq];
      }
#pragma unroll
      for (int i = 0; i < 2; ++i)
#pragma unroll
        for (int j = 0; j < 2; ++j)
          acc[i][j] = __builtin_amdgcn_mfma_f32_16x16x32_bf16(af[i], bg[j], acc[i][j], 0, 0, 0);
    }
    __syncthreads();
  }

  const int rh = (lane >> 4) * 4;
  const int col = lane & 15;
#pragma unroll
  for (int i = 0; i < 2; ++i)
#pragma unroll
    for (int j = 0; j < 2; ++j)
#pragma unroll
      for (int rr = 0; rr < 4; ++rr)
        Cv[(size_t)s * M * N + (size_t)(m0 + wm + 16 * i + rh + rr) * N + n0 + wn + 16 * j + col] =
            acc[i][j][rr];
}

// ============================================================================
// gemm_attn: per-batch C(128,4096)bf16 = A(128,256)f32 @ B(256,4096)f32
// FULL-M tile 128x64, 512 threads (8 waves, wave-tile 32x32) -> img read once.
// Grid: (4096/64, 8).
// ============================================================================
__global__ __launch_bounds__(512) void gemm_attn(
    const float* __restrict__ A, const float* __restrict__ B, bf16_t* __restrict__ C) {
  __shared__ bf16_t As[128][72];
  __shared__ bf16_t Bs[64][72];  // Bs[n][k]
  const int t = threadIdx.x;
  const int lane = t & 63;
  const int w = t >> 6;  // 0..7
  const int b = blockIdx.y;
  const int n0 = blockIdx.x * 64;
  const float* Ab = A + (size_t)b * 32768;
  const float* Bb = B + (size_t)b * 1048576;

  f32x4 acc[2][2];
#pragma unroll
  for (int i = 0; i < 2; ++i)
#pragma unroll
    for (int j = 0; j < 2; ++j) acc[i][j] = f32x4{0.f, 0.f, 0.f, 0.f};

  const int wm = (w & 3) * 32;   // 4 m-tiles of 32 over 128
  const int wn = (w >> 2) * 32;  // 2 n-tiles of 32 over 64
  const int fr = lane & 15;
  const int kq = (lane >> 4) * 8;

  for (int k0 = 0; k0 < 256; k0 += 64) {
    // A stage: r = t>>2 (0..127), 16 k-elems each
    const int r = t >> 2, c4 = (t & 3) * 16;
    float4 a4[4];
#pragma unroll
    for (int i = 0; i < 4; ++i)
      a4[i] = *(const float4*)(Ab + (size_t)r * 256 + k0 + c4 + 4 * i);
    // B stage: kr = t>>3 (0..63), 8 n-elems each (transposed store)
    const int kr = t >> 3, nc = (t & 7) * 8;
    float4 b4[2];
#pragma unroll
    for (int i = 0; i < 2; ++i)
      b4[i] = *(const float4*)(Bb + (size_t)(k0 + kr) * 4096 + n0 + nc + 4 * i);
    __syncthreads();
#pragma unroll
    for (int i = 0; i < 4; ++i) {
      bf16x4 v = {(bf16_t)a4[i].x, (bf16_t)a4[i].y, (bf16_t)a4[i].z, (bf16_t)a4[i].w};
      *(bf16x4*)&As[r][c4 + 4 * i] = v;
    }
#pragma unroll
    for (int i = 0; i < 2; ++i) {
      Bs[nc + 4 * i + 0][kr] = (bf16_t)b4[i].x;
      Bs[nc + 4 * i + 1][kr] = (bf16_t)b4[i].y;
      Bs[nc + 4 * i + 2][kr] = (bf16_t)b4[i].z;
      Bs[nc + 4 * i + 3][kr] = (bf16_t)b4[i].w;
    }
    __syncthreads();
#pragma unroll
    for (int kk = 0; kk < 64; kk += 32) {
      bf16x8 af[2], bg[2];
#pragma unroll
      for (int i = 0; i < 2; ++i) {
        af[i] = *(const bf16x8*)&As[wm + 16 * i + fr][kk + kq];
        bg[i] = *(const bf16x8*)&Bs[wn + 16 * i + fr][kk + kq];
      }
#pragma unroll
      for (int i = 0; i < 2; ++i)
#pragma unroll
        for (int j = 0; j < 2; ++j)
          acc[i][j] = __builtin_amdgcn_mfma_f32_16x16x32_bf16(af[i], bg[j], acc[i][j], 0, 0, 0);
    }
    __syncthreads();
  }

  bf16_t* Cb = C + (size_t)b * 524288;
  const int rh = (lane >> 4) * 4, col = lane & 15;
#pragma unroll
  for (int i = 0; i < 2; ++i)
#pragma unroll
    for (int j = 0; j < 2; ++j)
#pragma unroll
      for (int rr = 0; rr < 4; ++rr)
        Cb[(size_t)(wm + 16 * i + rh + rr) * 4096 + n0 + wn + 16 * j + col] =
            (bf16_t)acc[i][j][rr];
}

// ---------------- split-K reduce (bf16 partials) + bias + silu ----------------
template <int SILU_, int BIAS_>
__global__ __launch_bounds__(256) void reduce_b(
    const bf16_t* __restrict__ part, int S, long slice,
    const float* __restrict__ bias, float scale,
    float* __restrict__ outF, bf16_t* __restrict__ outB,
    long nmask, long total8) {
  long i8 = (long)blockIdx.x * 256 + threadIdx.x;
  if (i8 >= total8) return;
  long i = i8 * 8;
  float a[8] = {0.f, 0.f, 0.f, 0.f, 0.f, 0.f, 0.f, 0.f};
  for (int s = 0; s < S; ++s) {
    bf16x8 v = *(const bf16x8*)(part + (size_t)s * slice + i);
#pragma unroll
    for (int j = 0; j < 8; ++j) a[j] += (float)v[j];
  }
#pragma unroll
  for (int j = 0; j < 8; ++j) a[j] *= scale;
  if (BIAS_) {
    const float* bb = bias + (i & nmask);
#pragma unroll
    for (int j = 0; j < 8; ++j) a[j] += bb[j];
  }
  if (SILU_) {
#pragma unroll
    for (int j = 0; j < 8; ++j) a[j] = silu_f(a[j]);
  }
  if (outF) {
    float4 o0 = {a[0], a[1], a[2], a[3]}, o1 = {a[4], a[5], a[6], a[7]};
    *(float4*)(outF + i) = o0;
    *(float4*)(outF + i + 4) = o1;
  }
  if (outB) {
    bf16x8 o;
#pragma unroll
    for (int j = 0; j < 8; ++j) o[j] = (bf16_t)a[j];
    *(bf16x8*)(outB + i) = o;
  }
}

// ---------------- split-K reduce (f32 partials) ----------------
__global__ __launch_bounds__(256) void reduce_k(
    const float* __restrict__ part, int S, long slice, float scale,
    float* __restrict__ outF, long total4) {
  long i4 = (long)blockIdx.x * 256 + threadIdx.x;
  if (i4 >= total4) return;
  long i = i4 * 4;
  float4 v = *(const float4*)(part + i);
  for (int s = 1; s < S; ++s) {
    float4 u = *(const float4*)(part + (size_t)s * slice + i);
    v.x += u.x; v.y += u.y; v.z += u.z; v.w += u.w;
  }
  v.x *= scale; v.y *= scale; v.z *= scale; v.w *= scale;
  *(float4*)(outF + i) = v;
}

// ---------------- LayerNorm over rows = concat(X1[L1], X2[L2]) -> bf16 ----------------
__global__ __launch_bounds__(256) void ln_rows(
    const float* __restrict__ X1, const float* __restrict__ X2, int L1, int L2,
    const float* __restrict__ g, const float* __restrict__ bta, bf16_t* __restrict__ Y) {
  __shared__ float tmp[4];
  const int row = blockIdx.x;
  const int L = L1 + L2;
  const float* x1 = X1 + (size_t)row * L1;
  const float* x2 = X2 ? X2 + (size_t)row * L2 : nullptr;
  float s = 0.f, ss = 0.f;
  for (int i = threadIdx.x * 4; i < L1; i += 1024) {
    float4 v = *(const float4*)(x1 + i);
    s += v.x + v.y + v.z + v.w;
    ss += v.x * v.x + v.y * v.y + v.z * v.z + v.w * v.w;
  }
  for (int i = threadIdx.x * 4; i < L2; i += 1024) {
    float4 v = *(const float4*)(x2 + i);
    s += v.x + v.y + v.z + v.w;
    ss += v.x * v.x + v.y * v.y + v.z * v.z + v.w * v.w;
  }
  s = block_sum(s, tmp);
  ss = block_sum(ss, tmp);
  const float mu = s / (float)L;
  const float inv = rsqrtf(ss / (float)L - mu * mu + EPS);
  bf16_t* y = Y + (size_t)row * L;
  for (int i = threadIdx.x * 4; i < L1; i += 1024) {
    float4 v = *(const float4*)(x1 + i);
    float4 gv = *(const float4*)(g + i);
    float4 bv = *(const float4*)(bta + i);
    bf16x4 o = {(bf16_t)((v.x - mu) * inv * gv.x + bv.x),
                (bf16_t)((v.y - mu) * inv * gv.y + bv.y),
                (bf16_t)((v.z - mu) * inv * gv.z + bv.z),
                (bf16_t)((v.w - mu) * inv * gv.w + bv.w)};
    *(bf16x4*)(y + i) = o;
  }
  for (int i = threadIdx.x * 4; i < L2; i += 1024) {
    float4 v = *(const float4*)(x2 + i);
    float4 gv = *(const float4*)(g + L1 + i);
    float4 bv = *(const float4*)(bta + L1 + i);
    bf16x4 o = {(bf16_t)((v.x - mu) * inv * gv.x + bv.x),
                (bf16_t)((v.y - mu) * inv * gv.y + bv.y),
                (bf16_t)((v.z - mu) * inv * gv.z + bv.z),
                (bf16_t)((v.w - mu) * inv * gv.w + bv.w)};
    *(bf16x4*)(y + L1 + i) = o;
  }
}

// ---------------- QW[bk,h,c] = sum_d Q[bk,h*64+d] * kW[h*64+d, c] ----------------
__global__ __launch_bounds__(256) void qw_kernel(
    const float* __restrict__ Q, const float* __restrict__ kW, float* __restrict__ QW) {
  __shared__ float q[256];
  const int bk = blockIdx.x;
  q[threadIdx.x] = Q[(size_t)bk * 256 + threadIdx.x];
  __syncthreads();
  const int c = threadIdx.x;
#pragma unroll
  for (int h = 0; h < 4; ++h) {
    float s = 0.f;
#pragma unroll 8
    for (int d = 0; d < 64; ++d)
      s += q[(h << 6) + d] * kW[(size_t)(((h << 6) + d) << 8) + c];
    QW[((size_t)(bk * 4 + h) << 8) + c] = s;
  }
}

// ---------------- fused conv1(4->4,silu) + conv2(4->1) + bilinear up 64->256 ----------------
__global__ __launch_bounds__(256) void conv_fused(
    const bf16_t* __restrict__ X, const float* __restrict__ W1,
    const float* __restrict__ B1, const float* __restrict__ W2,
    const float* __restrict__ B2, float* __restrict__ O) {
  __shared__ bf16_t lg[16384];
  __shared__ bf16_t mid[16384];
  __shared__ float lg64[4096];
  __shared__ float wsh[180];
  const int t = threadIdx.x;
  const size_t base = (size_t)blockIdx.x * 16384;
#pragma unroll
  for (int i = 0; i < 8; ++i) {
    int o = (i * 256 + t) * 8;
    *(bf16x8*)&lg[o] = *(const bf16x8*)(X + base + o);
  }
  if (t < 144) wsh[t] = W1[t];
  else if (t < 180) wsh[t] = W2[t - 144];
  __syncthreads();
  const int px0 = (t & 15) * 4, py0 = (t >> 4) * 4;
  {
    float acc1[4][16];
#pragma unroll
    for (int oc = 0; oc < 4; ++oc) {
      float bb = B1[oc];
#pragma unroll
      for (int p = 0; p < 16; ++p) acc1[oc][p] = bb;
    }
#pragma unroll
    for (int c = 0; c < 4; ++c) {
      float p[6][6];
#pragma unroll
      for (int yy = 0; yy < 6; ++yy) {
        int gy = py0 + yy - 1;
#pragma unroll
        for (int xx = 0; xx < 6; ++xx) {
          int gx = px0 + xx - 1;
          p[yy][xx] = ((unsigned)gy < 64u && (unsigned)gx < 64u)
                          ? (float)lg[c * 4096 + gy * 64 + gx] : 0.f;
        }
      }
#pragma unroll
      for (int oc = 0; oc < 4; ++oc) {
        float wr[9];
#pragma unroll
        for (int k = 0; k < 9; ++k) wr[k] = wsh[oc * 36 + c * 9 + k];
#pragma unroll
        for (int y = 0; y < 4; ++y)
#pragma unroll
          for (int x = 0; x < 4; ++x)
            acc1[oc][y * 4 + x] +=
                wr[0] * p[y][x] + wr[1] * p[y][x + 1] + wr[2] * p[y][x + 2]
              + wr[3] * p[y + 1][x] + wr[4] * p[y + 1][x + 1] + wr[5] * p[y + 1][x + 2]
              + wr[6] * p[y + 2][x] + wr[7] * p[y + 2][x + 1] + wr[8] * p[y + 2][x + 2];
      }
    }
#pragma unroll
    for (int oc = 0; oc < 4; ++oc)
#pragma unroll
      for (int y = 0; y < 4; ++y) {
        bf16x4 o;
#pragma unroll
        for (int x = 0; x < 4; ++x) o[x] = (bf16_t)silu_f(acc1[oc][y * 4 + x]);
        *(bf16x4*)&mid[oc * 4096 + (py0 + y) * 64 + px0] = o;
      }
  }
  __syncthreads();
  {
    float acc2[16];
    float bb = B2[0];
#pragma unroll
    for (int p = 0; p < 16; ++p) acc2[p] = bb;
#pragma unroll
    for (int c = 0; c < 4; ++c) {
      float p[6][6];
#pragma unroll
      for (int yy = 0; yy < 6; ++yy) {
        int gy = py0 + yy - 1;
#pragma unroll
        for (int xx = 0; xx < 6; ++xx) {
          int gx = px0 + xx - 1;
          p[yy][xx] = ((unsigned)gy < 64u && (unsigned)gx < 64u)
                          ? (float)mid[c * 4096 + gy * 64 + gx] : 0.f;
        }
      }
      float wr[9];
#pragma unroll
      for (int k = 0; k < 9; ++k) wr[k] = wsh[144 + c * 9 + k];
#pragma unroll
      for (int y = 0; y < 4; ++y)
#pragma unroll
        for (int x = 0; x < 4; ++x)
          acc2[y * 4 + x] +=
              wr[0] * p[y][x] + wr[1] * p[y][x + 1] + wr[2] * p[y][x + 2]
            + wr[3] * p[y + 1][x] + wr[4] * p[y + 1][x + 1] + wr[5] * p[y + 1][x + 2]
            + wr[6] * p[y + 2][x] + wr[7] * p[y + 2][x + 1] + wr[8] * p[y + 2][x + 2];
    }
#pragma unroll
    for (int y = 0; y < 4; ++y)
#pragma unroll
      for (int x = 0; x < 4; ++x) lg64[(py0 + y) * 64 + px0 + x] = acc2[y * 4 + x];
  }
  __syncthreads();
  float* Ob = O + (size_t)blockIdx.x * 65536;
  for (int rr = 0; rr < 64; ++rr) {
    int p4 = rr * 256 + t;
    int oy = p4 >> 6, ox0 = (p4 & 63) * 4;
    float sy = oy * 0.25f - 0.375f;
    int y0 = (int)floorf(sy);
    float wy = sy - (float)y0;
    int y1 = min(y0 + 1, 63); y0 = max(y0, 0);
    const float* r0 = &lg64[y0 * 64];
    const float* r1 = &lg64[y1 * 64];
    float4 o;
#pragma unroll
    for (int q = 0; q < 4; ++q) {
      int ox = ox0 + q;
      float sx = ox * 0.25f - 0.375f;
      int x0 = (int)floorf(sx);
      float wx = sx - (float)x0;
      int x1 = min(x0 + 1, 63); x0 = max(x0, 0);
      float v0 = r0[x0] + wx * (r0[x1] - r0[x0]);
      float v1 = r1[x0] + wx * (r1[x1] - r1[x0]);
      ((float*)&o)[q] = v0 + wy * (v1 - v0);
    }
    *(float4*)(Ob + oy * 256 + ox0) = o;
  }
}

// ---------------- confidence: out[row] = dot(cfh_row, w2) + b2 ----------------
__global__ __launch_bounds__(256) void conf_k(
    const float* __restrict__ cfh, const float* __restrict__ w2,
    const float* __restrict__ b2, float* __restrict__ out) {
  __shared__ float tmp[4];
  const int row = blockIdx.x;
  float s = 0.f;
  for (int i = threadIdx.x; i < 2048; i += 256)
    s += cfh[(size_t)row * 2048 + i] * w2[i];
  s = block_sum(s, tmp);
  if (threadIdx.x == 0) out[row] = s + b2[0];
}

extern "C" void kernel_launch(void* const* d_in, const int* in_sizes, int n_in,
                              void* d_out, int out_size, void* d_ws, size_t ws_size,
                              hipStream_t stream) {
  const float* img    = (const float*)d_in[0];
  const float* refv   = (const float*)d_in[1];
  const float* qs     = (const float*)d_in[2];
  const float* qpw    = (const float*)d_in[3];
  const float* kpw    = (const float*)d_in[4];
  const float* fw1    = (const float*)d_in[5];
  const float* fb1    = (const float*)d_in[6];
  const float* fw2    = (const float*)d_in[7];
  const float* fb2    = (const float*)d_in[8];
  const float* qbw    = (const float*)d_in[9];
  const float* rlg    = (const float*)d_in[10];
  const float* rlb    = (const float*)d_in[11];
  const float* rlw    = (const float*)d_in[12];
  const float* rlbias = (const float*)d_in[13];
  const float* clg    = (const float*)d_in[14];
  const float* clb    = (const float*)d_in[15];
  const float* cw1    = (const float*)d_in[16];
  const float* cb1    = (const float*)d_in[17];
  const float* cw2    = (const float*)d_in[18];
  const float* cb2    = (const float*)d_in[19];
  float* out = (float*)d_out;
  char* W = (char*)d_ws;

  // --- workspace layout (bytes); lifetimes disjoint within each region ---
  bf16_t* partF = (bf16_t*)(W + 0);          // 16.8 MB steps 4-5
  bf16_t* l64hb = (bf16_t*)(W + 0);          //  8.4 MB steps 9-10
  bf16_t* partC = (bf16_t*)(W + 0);          // 16.8 MB steps 12-13
  bf16_t* catln = (bf16_t*)(W + 16777216);   //  4.2 MB steps 3-4
  float*  fus   = (float*)(W + 16777216);    //  4.2 MB steps 5-11 (catln dead)
  float*  qbf   = (float*)(W + 20971520);    //  4.2 MB steps 2-3
  bf16_t* fusb  = (bf16_t*)(W + 20971520);   //  2.1 MB steps 5-6 (qbf dead)
  bf16_t* lnf   = (bf16_t*)(W + 20971520);   //  2.1 MB steps 11-12 (fusb dead)
  bf16_t* partQ = (bf16_t*)(W + 25165824);   // 16.8 MB steps 1-2
  float*  part8 = (float*)(W + 25165824);    //  2.1 MB steps 6-7 (partQ dead)
  float*  Qb    = (float*)(W + 44040192);    //  0.26 MB steps 7-8
  float*  QW    = (float*)(W + 44302336);    //  1.05 MB steps 8-9
  float*  cfh   = (float*)(W + 45350912);    //  2.1 MB steps 13-14

  dim3 b256(256);

  // 1. qb GEMM (split-K x8, simple path): partQ[s] = qs @ qbw^T chunk
  gemm_wide_s<<<dim3(32, 8), dim3(1024), 0, stream>>>(qs, qbw, partQ, 4096, 512, 64);
  // 2. qbf = sum partQ
  reduce_b<0, 0><<<dim3(512), b256, 0, stream>>>(
      partQ, 8, 1048576L, nullptr, 1.f, qbf, nullptr, 0L, 131072L);
  // 3. catln = LN(concat(ref_vec, qbf)) -> bf16
  ln_rows<<<dim3(256), b256, 0, stream>>>(refv, qbf, 4096, 4096, rlg, rlb, catln);
  // 4. fused GEMM (split-K x8, pipelined): partF[s] = catln @ rlw^T chunk
  gemm_wide<<<dim3(32, 8), dim3(1024), 0, stream>>>(catln, rlw, partF, 4096, 8192, 1024);
  // 5. fus = silu(sum partF + bias) -> f32 + bf16
  reduce_b<1, 1><<<dim3(512), b256, 0, stream>>>(
      partF, 8, 1048576L, rlbias, 1.f, fus, fusb, 4095L, 131072L);
  // 6. qproj GEMM (split-K x8): part8[s] = fusb @ qpw^T chunk (f32 partials)
  gemm_small<<<dim3(4, 4, 8), b256, 0, stream>>>(fusb, qpw, part8, 256, 256, 4096, 512, 8);
  // 7. Qb = 0.125 * sum part8
  reduce_k<<<dim3(64), b256, 0, stream>>>(part8, 8, 65536L, 0.125f, Qb, 16384L);
  // 8. QW = per-head Q @ k_proj
  qw_kernel<<<dim3(256), b256, 0, stream>>>(Qb, kpw, QW);
  // 9. logits (full-M): l64hb[b] = QW_b @ img_b
  gemm_attn<<<dim3(64, 8), dim3(512), 0, stream>>>(QW, img, l64hb);
  // 10. out = upsample(conv2(silu(conv1(l64hb))))
  conv_fused<<<dim3(256), b256, 0, stream>>>(l64hb, fw1, fb1, fw2, fb2, out);
  // 11. lnf = LN(fus) -> bf16
  ln_rows<<<dim3(256), b256, 0, stream>>>(fus, nullptr, 4096, 0, clg, clb, lnf);
  // 12. cfh GEMM (split-K x16, pipelined nt=4): partC[s] = lnf @ cw1^T chunk
  gemm_wide<<<dim3(16, 16), dim3(1024), 0, stream>>>(lnf, cw1, partC, 2048, 4096, 256);
  // 13. cfh = silu(sum partC + cb1) -> f32
  reduce_b<1, 1><<<dim3(256), b256, 0, stream>>>(
      partC, 16, 524288L, cb1, 1.f, cfh, nullptr, 2047L, 65536L);
  // 14. conf out
  conf_k<<<dim3(256), b256, 0, stream>>>(cfh, cw2, cb2, out + 16777216);
}

// Round 8
// 187.891 us; speedup vs baseline: 7.5374x; 1.0380x over previous
//
#include <hip/hip_runtime.h>

#define EPS 1e-5f

typedef __bf16 bf16_t;
typedef __bf16 bf16x8 __attribute__((ext_vector_type(8)));
typedef __bf16 bf16x4 __attribute__((ext_vector_type(4)));
typedef float f32x4 __attribute__((ext_vector_type(4)));

__device__ __forceinline__ float silu_f(float x) { return x / (1.f + __expf(-x)); }

// ---------------- block reduction (256 threads = 4 waves) ----------------
__device__ __forceinline__ float block_sum(float v, float* tmp) {
#pragma unroll
  for (int off = 32; off > 0; off >>= 1) v += __shfl_down(v, off);
  __syncthreads();
  if ((threadIdx.x & 63) == 0) tmp[threadIdx.x >> 6] = v;
  __syncthreads();
  return tmp[0] + tmp[1] + tmp[2] + tmp[3];
}

// ============================================================================
// gemm_wide v3: Cpart[z](bf16) = A(256,K)bf16 @ B(N,K)^T f32 (fat weight GEMMs)
// tile 256x128 (full M -> B read once), BK=64, 1024 threads (16 waves,
// wave-tile 64x32). DOUBLE-buffered LDS (110 KB, 1 block/CU), 3-deep named
// register pipeline, ONE barrier per K-step: phase s = { issue loads(s+3);
// ds_write set(s+1) -> buf^1 (counted vmcnt(8)); MFMA buf; lgkmcnt(0)+barrier }.
// Grid: (N/128, S). Any nt >= 1 (guards); our uses have nt in {4,16}.
// ============================================================================
__global__ __launch_bounds__(1024) void gemm_wide(
    const bf16_t* __restrict__ A, const float* __restrict__ B,
    bf16_t* __restrict__ Cpart, int N, int K, int KS) {
  __shared__ bf16_t As[2][256][72];
  __shared__ bf16_t Bs[2][128][72];
  const int t = threadIdx.x;
  const int lane = t & 63;
  const int w = t >> 6;  // 0..15
  const int n0 = blockIdx.x * 128;
  const int kbeg = blockIdx.y * KS;
  const int nt = KS >> 6;
  const int ar = t >> 2, ac = (t & 3) * 16;  // A stage: 4 thr/row x 16 elts
  const int br = t >> 3, bc = (t & 7) * 8;   // B stage: 8 thr/row x 8 f32
  const bf16_t* Ap = A + (size_t)ar * K + kbeg + ac;
  const float* Bp = B + (size_t)(n0 + br) * K + kbeg + bc;

  // 3 named register sets (X,Y,Z), static indexing
  bf16x8 a0X, a1X, a0Y, a1Y, a0Z, a1Z;
  float4 b0X, b1X, b0Y, b1Y, b0Z, b1Z;

#define LOADSET(S, k0)                            \
  a0##S = *(const bf16x8*)(Ap + (k0));            \
  a1##S = *(const bf16x8*)(Ap + (k0) + 8);        \
  b0##S = *(const float4*)(Bp + (k0));            \
  b1##S = *(const float4*)(Bp + (k0) + 4);

#define STORESET(S, buf)                                                    \
  {                                                                         \
    *(bf16x8*)&As[buf][ar][ac] = a0##S;                                     \
    *(bf16x8*)&As[buf][ar][ac + 8] = a1##S;                                 \
    bf16x8 wv;                                                              \
    wv[0] = (bf16_t)b0##S.x; wv[1] = (bf16_t)b0##S.y;                       \
    wv[2] = (bf16_t)b0##S.z; wv[3] = (bf16_t)b0##S.w;                       \
    wv[4] = (bf16_t)b1##S.x; wv[5] = (bf16_t)b1##S.y;                       \
    wv[6] = (bf16_t)b1##S.z; wv[7] = (bf16_t)b1##S.w;                       \
    *(bf16x8*)&Bs[buf][br][bc] = wv;                                        \
  }

  f32x4 acc[4][2];
#pragma unroll
  for (int i = 0; i < 4; ++i)
#pragma unroll
    for (int j = 0; j < 2; ++j) acc[i][j] = f32x4{0.f, 0.f, 0.f, 0.f};

  const int wm = (w & 3) * 64;
  const int wn = (w >> 2) * 32;
  const int fr = lane & 15;
  const int kq = (lane >> 4) * 8;

  auto COMPUTE = [&](int buf) {
#pragma unroll
    for (int kk = 0; kk < 64; kk += 32) {
      bf16x8 af[4], bg[2];
#pragma unroll
      for (int i = 0; i < 4; ++i)
        af[i] = *(const bf16x8*)&As[buf][wm + 16 * i + fr][kk + kq];
#pragma unroll
      for (int j = 0; j < 2; ++j)
        bg[j] = *(const bf16x8*)&Bs[buf][wn + 16 * j + fr][kk + kq];
#pragma unroll
      for (int i = 0; i < 4; ++i)
#pragma unroll
        for (int j = 0; j < 2; ++j)
          acc[i][j] = __builtin_amdgcn_mfma_f32_16x16x32_bf16(af[i], bg[j], acc[i][j], 0, 0, 0);
    }
  };

#define SB __builtin_amdgcn_sched_barrier(0);
#define END_PHASE                                      \
  asm volatile("s_waitcnt lgkmcnt(0)" ::: "memory");   \
  SB __builtin_amdgcn_s_barrier(); SB

  // phase s: load set[s%3] with step s+3; store set[(s+1)%3] -> buf (s+1)&1;
  // compute buf s&1. One barrier per phase.
#define PHASE(s_, LS, SS, bufc)                              \
  if ((s_) < nt) {                                           \
    if ((s_) + 3 < nt) { LOADSET(LS, ((s_) + 3) * 64) }      \
    SB                                                       \
    if ((s_) + 1 < nt) { STORESET(SS, bufc ^ 1) }            \
    COMPUTE(bufc);                                           \
    END_PHASE                                                \
  }

  // prologue: steps 0..2 into X,Y,Z; stage step0 -> buf0 (vmcnt(8) counted)
  LOADSET(X, 0)
  if (1 < nt) { LOADSET(Y, 64) }
  if (2 < nt) { LOADSET(Z, 128) }
  SB
  STORESET(X, 0)
  END_PHASE

  for (int s6 = 0; s6 < nt; s6 += 6) {
    PHASE(s6 + 0, X, Y, 0)
    PHASE(s6 + 1, Y, Z, 1)
    PHASE(s6 + 2, Z, X, 0)
    PHASE(s6 + 3, X, Y, 1)
    PHASE(s6 + 4, Y, Z, 0)
    PHASE(s6 + 5, Z, X, 1)
  }
#undef LOADSET
#undef STORESET
#undef PHASE
#undef END_PHASE
#undef SB

  bf16_t* Cz = Cpart + (size_t)blockIdx.y * 256 * N;
  const int rh = (lane >> 4) * 4, col = lane & 15;
#pragma unroll
  for (int i = 0; i < 4; ++i)
#pragma unroll
    for (int j = 0; j < 2; ++j)
#pragma unroll
      for (int rr = 0; rr < 4; ++rr)
        Cz[(size_t)(wm + 16 * i + rh + rr) * N + n0 + wn + 16 * j + col] =
            (bf16_t)acc[i][j][rr];
}

// ============================================================================
// gemm_wide_s: simple (non-pipelined) 256x128 variant, A f32 (qb GEMM).
// ============================================================================
__global__ __launch_bounds__(1024) void gemm_wide_s(
    const float* __restrict__ A, const float* __restrict__ B,
    bf16_t* __restrict__ Cpart, int N, int K, int KS) {
  __shared__ bf16_t As[256][72];
  __shared__ bf16_t Bs[128][72];
  const int t = threadIdx.x;
  const int lane = t & 63;
  const int w = t >> 6;
  const int n0 = blockIdx.x * 128;
  const int kbeg = blockIdx.y * KS;
  const int nt = KS >> 6;
  const int ar = t >> 2, ac = (t & 3) * 16;
  const int br = t >> 3, bc = (t & 7) * 8;
  const float* Ap = A + (size_t)ar * K + kbeg + ac;
  const float* Bp = B + (size_t)(n0 + br) * K + kbeg + bc;

  f32x4 acc[4][2];
#pragma unroll
  for (int i = 0; i < 4; ++i)
#pragma unroll
    for (int j = 0; j < 2; ++j) acc[i][j] = f32x4{0.f, 0.f, 0.f, 0.f};

  const int wm = (w & 3) * 64;
  const int wn = (w >> 2) * 32;
  const int fr = lane & 15;
  const int kq = (lane >> 4) * 8;

  for (int s = 0; s < nt; ++s) {
    float4 av[4], bv[2];
#pragma unroll
    for (int i = 0; i < 4; ++i) av[i] = *(const float4*)(Ap + s * 64 + 4 * i);
#pragma unroll
    for (int i = 0; i < 2; ++i) bv[i] = *(const float4*)(Bp + s * 64 + 4 * i);
    __syncthreads();
    {
      bf16x8 wa0, wa1, wb;
      wa0[0] = (bf16_t)av[0].x; wa0[1] = (bf16_t)av[0].y; wa0[2] = (bf16_t)av[0].z; wa0[3] = (bf16_t)av[0].w;
      wa0[4] = (bf16_t)av[1].x; wa0[5] = (bf16_t)av[1].y; wa0[6] = (bf16_t)av[1].z; wa0[7] = (bf16_t)av[1].w;
      wa1[0] = (bf16_t)av[2].x; wa1[1] = (bf16_t)av[2].y; wa1[2] = (bf16_t)av[2].z; wa1[3] = (bf16_t)av[2].w;
      wa1[4] = (bf16_t)av[3].x; wa1[5] = (bf16_t)av[3].y; wa1[6] = (bf16_t)av[3].z; wa1[7] = (bf16_t)av[3].w;
      wb[0] = (bf16_t)bv[0].x; wb[1] = (bf16_t)bv[0].y; wb[2] = (bf16_t)bv[0].z; wb[3] = (bf16_t)bv[0].w;
      wb[4] = (bf16_t)bv[1].x; wb[5] = (bf16_t)bv[1].y; wb[6] = (bf16_t)bv[1].z; wb[7] = (bf16_t)bv[1].w;
      *(bf16x8*)&As[ar][ac] = wa0;
      *(bf16x8*)&As[ar][ac + 8] = wa1;
      *(bf16x8*)&Bs[br][bc] = wb;
    }
    __syncthreads();
#pragma unroll
    for (int kk = 0; kk < 64; kk += 32) {
      bf16x8 af[4], bg[2];
#pragma unroll
      for (int i = 0; i < 4; ++i)
        af[i] = *(const bf16x8*)&As[wm + 16 * i + fr][kk + kq];
#pragma unroll
      for (int j = 0; j < 2; ++j)
        bg[j] = *(const bf16x8*)&Bs[wn + 16 * j + fr][kk + kq];
#pragma unroll
      for (int i = 0; i < 4; ++i)
#pragma unroll
        for (int j = 0; j < 2; ++j)
          acc[i][j] = __builtin_amdgcn_mfma_f32_16x16x32_bf16(af[i], bg[j], acc[i][j], 0, 0, 0);
    }
    __syncthreads();
  }

  bf16_t* Cz = Cpart + (size_t)blockIdx.y * 256 * N;
  const int rh = (lane >> 4) * 4, col = lane & 15;
#pragma unroll
  for (int i = 0; i < 4; ++i)
#pragma unroll
    for (int j = 0; j < 2; ++j)
#pragma unroll
      for (int rr = 0; rr < 4; ++rr)
        Cz[(size_t)(wm + 16 * i + rh + rr) * N + n0 + wn + 16 * j + col] =
            (bf16_t)acc[i][j][rr];
}

// ============================================================================
// gemm_small (64x64 tile) -- qproj GEMM. A bf16, B f32, f32 split-K partials.
// ============================================================================
__global__ __launch_bounds__(256) void gemm_small(
    const bf16_t* __restrict__ A16, const float* __restrict__ B32, float* __restrict__ Cv,
    int M, int N, int K, int KS, int S) {
  __shared__ bf16_t As[64][72];
  __shared__ bf16_t Bs[64][72];
  const int t = threadIdx.x;
  const int lane = t & 63;
  const int w = t >> 6;
  const int s = blockIdx.z;
  const int n0 = blockIdx.x * 64;
  const int m0 = blockIdx.y * 64;
  const int kbeg = s * KS;

  f32x4 acc[2][2];
#pragma unroll
  for (int i = 0; i < 2; ++i)
#pragma unroll
    for (int j = 0; j < 2; ++j) acc[i][j] = f32x4{0.f, 0.f, 0.f, 0.f};

  const int wm = (w & 1) * 32, wn = (w >> 1) * 32;
  const int fr = lane & 15;
  const int kq = (lane >> 4) * 8;

  for (int k0 = kbeg; k0 < kbeg + KS; k0 += 64) {
    bf16x8 a8[2];
    float4 b4[4];
    {
      const int rr = t >> 2, c8 = (t & 3) * 8;
#pragma unroll
      for (int i = 0; i < 2; ++i)
        a8[i] = *(const bf16x8*)(A16 + (size_t)(m0 + rr) * K + k0 + c8 + 32 * i);
    }
    {
      const int rr = t >> 4, c4 = (t & 15) * 4;
#pragma unroll
      for (int i = 0; i < 4; ++i)
        b4[i] = *(const float4*)(B32 + (size_t)(n0 + rr + 16 * i) * K + k0 + c4);
    }
    __syncthreads();
    {
      const int rr = t >> 2, c8 = (t & 3) * 8;
#pragma unroll
      for (int i = 0; i < 2; ++i) *(bf16x8*)&As[rr][c8 + 32 * i] = a8[i];
    }
    {
      const int rr = t >> 4, c4 = (t & 15) * 4;
#pragma unroll
      for (int i = 0; i < 4; ++i) {
        bf16x4 v = {(bf16_t)b4[i].x, (bf16_t)b4[i].y, (bf16_t)b4[i].z, (bf16_t)b4[i].w};
        *(bf16x4*)&Bs[rr + 16 * i][c4] = v;
      }
    }
    __syncthreads();
#pragma unroll
    for (int kk = 0; kk < 64; kk += 32) {
      bf16x8 af[2], bg[2];
#pragma unroll
      for (int i = 0; i < 2; ++i) {
        af[i] = *(const bf16x8*)&As[wm + 16 * i + fr][kk + kq];
        bg[i] = *(const bf16x8*)&Bs[wn + 16 * i + fr][kk + kq];
      }
#pragma unroll
      for (int i = 0; i < 2; ++i)
#pragma unroll
        for (int j = 0; j < 2; ++j)
          acc[i][j] = __builtin_amdgcn_mfma_f32_16x16x32_bf16(af[i], bg[j], acc[i][j], 0, 0, 0);
    }
    __syncthreads();
  }

  const int rh = (lane >> 4) * 4;
  const int col = lane & 15;
#pragma unroll
  for (int i = 0; i < 2; ++i)
#pragma unroll
    for (int j = 0; j < 2; ++j)
#pragma unroll
      for (int rr = 0; rr < 4; ++rr)
        Cv[(size_t)s * M * N + (size_t)(m0 + wm + 16 * i + rh + rr) * N + n0 + wn + 16 * j + col] =
            acc[i][j][rr];
}

// ============================================================================
// gemm_attn: per-batch C(128,4096)bf16 = A(128,256)f32 @ B(256,4096)f32
// full-M tile 128x64, 512 threads. Grid: (64, 8).
// ============================================================================
__global__ __launch_bounds__(512) void gemm_attn(
    const float* __restrict__ A, const float* __restrict__ B, bf16_t* __restrict__ C) {
  __shared__ bf16_t As[128][72];
  __shared__ bf16_t Bs[64][72];  // Bs[n][k]
  const int t = threadIdx.x;
  const int lane = t & 63;
  const int w = t >> 6;
  const int b = blockIdx.y;
  const int n0 = blockIdx.x * 64;
  const float* Ab = A + (size_t)b * 32768;
  const float* Bb = B + (size_t)b * 1048576;

  f32x4 acc[2][2];
#pragma unroll
  for (int i = 0; i < 2; ++i)
#pragma unroll
    for (int j = 0; j < 2; ++j) acc[i][j] = f32x4{0.f, 0.f, 0.f, 0.f};

  const int wm = (w & 3) * 32;
  const int wn = (w >> 2) * 32;
  const int fr = lane & 15;
  const int kq = (lane >> 4) * 8;

  for (int k0 = 0; k0 < 256; k0 += 64) {
    const int r = t >> 2, c4 = (t & 3) * 16;
    float4 a4[4];
#pragma unroll
    for (int i = 0; i < 4; ++i)
      a4[i] = *(const float4*)(Ab + (size_t)r * 256 + k0 + c4 + 4 * i);
    const int kr = t >> 3, nc = (t & 7) * 8;
    float4 b4[2];
#pragma unroll
    for (int i = 0; i < 2; ++i)
      b4[i] = *(const float4*)(Bb + (size_t)(k0 + kr) * 4096 + n0 + nc + 4 * i);
    __syncthreads();
#pragma unroll
    for (int i = 0; i < 4; ++i) {
      bf16x4 v = {(bf16_t)a4[i].x, (bf16_t)a4[i].y, (bf16_t)a4[i].z, (bf16_t)a4[i].w};
      *(bf16x4*)&As[r][c4 + 4 * i] = v;
    }
#pragma unroll
    for (int i = 0; i < 2; ++i) {
      Bs[nc + 4 * i + 0][kr] = (bf16_t)b4[i].x;
      Bs[nc + 4 * i + 1][kr] = (bf16_t)b4[i].y;
      Bs[nc + 4 * i + 2][kr] = (bf16_t)b4[i].z;
      Bs[nc + 4 * i + 3][kr] = (bf16_t)b4[i].w;
    }
    __syncthreads();
#pragma unroll
    for (int kk = 0; kk < 64; kk += 32) {
      bf16x8 af[2], bg[2];
#pragma unroll
      for (int i = 0; i < 2; ++i) {
        af[i] = *(const bf16x8*)&As[wm + 16 * i + fr][kk + kq];
        bg[i] = *(const bf16x8*)&Bs[wn + 16 * i + fr][kk + kq];
      }
#pragma unroll
      for (int i = 0; i < 2; ++i)
#pragma unroll
        for (int j = 0; j < 2; ++j)
          acc[i][j] = __builtin_amdgcn_mfma_f32_16x16x32_bf16(af[i], bg[j], acc[i][j], 0, 0, 0);
    }
    __syncthreads();
  }

  bf16_t* Cb = C + (size_t)b * 524288;
  const int rh = (lane >> 4) * 4, col = lane & 15;
#pragma unroll
  for (int i = 0; i < 2; ++i)
#pragma unroll
    for (int j = 0; j < 2; ++j)
#pragma unroll
      for (int rr = 0; rr < 4; ++rr)
        Cb[(size_t)(wm + 16 * i + rh + rr) * 4096 + n0 + wn + 16 * j + col] =
            (bf16_t)acc[i][j][rr];
}

// ---------------- split-K reduce (bf16 partials) + bias + silu ----------------
template <int SILU_, int BIAS_>
__global__ __launch_bounds__(256) void reduce_b(
    const bf16_t* __restrict__ part, int S, long slice,
    const float* __restrict__ bias, float scale,
    float* __restrict__ outF, bf16_t* __restrict__ outB,
    long nmask, long total8) {
  long i8 = (long)blockIdx.x * 256 + threadIdx.x;
  if (i8 >= total8) return;
  long i = i8 * 8;
  float a[8] = {0.f, 0.f, 0.f, 0.f, 0.f, 0.f, 0.f, 0.f};
  for (int s = 0; s < S; ++s) {
    bf16x8 v = *(const bf16x8*)(part + (size_t)s * slice + i);
#pragma unroll
    for (int j = 0; j < 8; ++j) a[j] += (float)v[j];
  }
#pragma unroll
  for (int j = 0; j < 8; ++j) a[j] *= scale;
  if (BIAS_) {
    const float* bb = bias + (i & nmask);
#pragma unroll
    for (int j = 0; j < 8; ++j) a[j] += bb[j];
  }
  if (SILU_) {
#pragma unroll
    for (int j = 0; j < 8; ++j) a[j] = silu_f(a[j]);
  }
  if (outF) {
    float4 o0 = {a[0], a[1], a[2], a[3]}, o1 = {a[4], a[5], a[6], a[7]};
    *(float4*)(outF + i) = o0;
    *(float4*)(outF + i + 4) = o1;
  }
  if (outB) {
    bf16x8 o;
#pragma unroll
    for (int j = 0; j < 8; ++j) o[j] = (bf16_t)a[j];
    *(bf16x8*)(outB + i) = o;
  }
}

// ---------------- fused partQ-reduce + LayerNorm(concat(refv, qb)) -> bf16 ---
// one block per row; thread t owns qb elements [t*16, t*16+16)
__global__ __launch_bounds__(256) void ln_fuse(
    const float* __restrict__ refv, const bf16_t* __restrict__ partQ, int S,
    const float* __restrict__ g, const float* __restrict__ bta, bf16_t* __restrict__ Y) {
  __shared__ float tmp[4];
  const int row = blockIdx.x;
  const int t = threadIdx.x;
  const long i0 = t * 16;
  // reduce qb = sum_s partQ[s][row][i0..i0+16)
  float q[16];
#pragma unroll
  for (int j = 0; j < 16; ++j) q[j] = 0.f;
  for (int s = 0; s < S; ++s) {
    const bf16_t* p = partQ + (size_t)s * 1048576 + (size_t)row * 4096 + i0;
    bf16x8 v0 = *(const bf16x8*)(p);
    bf16x8 v1 = *(const bf16x8*)(p + 8);
#pragma unroll
    for (int j = 0; j < 8; ++j) { q[j] += (float)v0[j]; q[8 + j] += (float)v1[j]; }
  }
  // refv part
  const float* xr = refv + (size_t)row * 4096 + i0;
  float r[16];
#pragma unroll
  for (int j = 0; j < 4; ++j) {
    float4 v = *(const float4*)(xr + 4 * j);
    r[4 * j] = v.x; r[4 * j + 1] = v.y; r[4 * j + 2] = v.z; r[4 * j + 3] = v.w;
  }
  float s1 = 0.f, s2 = 0.f;
#pragma unroll
  for (int j = 0; j < 16; ++j) { s1 += r[j] + q[j]; s2 += r[j] * r[j] + q[j] * q[j]; }
  s1 = block_sum(s1, tmp);
  s2 = block_sum(s2, tmp);
  const float mu = s1 / 8192.f;
  const float inv = rsqrtf(s2 / 8192.f - mu * mu + EPS);
  bf16_t* y = Y + (size_t)row * 8192;
  bf16x8 o0, o1;
#pragma unroll
  for (int j = 0; j < 8; ++j) {
    o0[j] = (bf16_t)((r[j] - mu) * inv * g[i0 + j] + bta[i0 + j]);
    o1[j] = (bf16_t)((r[8 + j] - mu) * inv * g[i0 + 8 + j] + bta[i0 + 8 + j]);
  }
  *(bf16x8*)(y + i0) = o0;
  *(bf16x8*)(y + i0 + 8) = o1;
#pragma unroll
  for (int j = 0; j < 8; ++j) {
    o0[j] = (bf16_t)((q[j] - mu) * inv * g[4096 + i0 + j] + bta[4096 + i0 + j]);
    o1[j] = (bf16_t)((q[8 + j] - mu) * inv * g[4096 + i0 + 8 + j] + bta[4096 + i0 + 8 + j]);
  }
  *(bf16x8*)(y + 4096 + i0) = o0;
  *(bf16x8*)(y + 4096 + i0 + 8) = o1;
}

// ---------------- LayerNorm over rows (single f32 input) -> bf16 ----------------
__global__ __launch_bounds__(256) void ln_rows(
    const float* __restrict__ X1, int L1,
    const float* __restrict__ g, const float* __restrict__ bta, bf16_t* __restrict__ Y) {
  __shared__ float tmp[4];
  const int row = blockIdx.x;
  const float* x1 = X1 + (size_t)row * L1;
  float s = 0.f, ss = 0.f;
  for (int i = threadIdx.x * 4; i < L1; i += 1024) {
    float4 v = *(const float4*)(x1 + i);
    s += v.x + v.y + v.z + v.w;
    ss += v.x * v.x + v.y * v.y + v.z * v.z + v.w * v.w;
  }
  s = block_sum(s, tmp);
  ss = block_sum(ss, tmp);
  const float mu = s / (float)L1;
  const float inv = rsqrtf(ss / (float)L1 - mu * mu + EPS);
  bf16_t* y = Y + (size_t)row * L1;
  for (int i = threadIdx.x * 4; i < L1; i += 1024) {
    float4 v = *(const float4*)(x1 + i);
    float4 gv = *(const float4*)(g + i);
    float4 bv = *(const float4*)(bta + i);
    bf16x4 o = {(bf16_t)((v.x - mu) * inv * gv.x + bv.x),
                (bf16_t)((v.y - mu) * inv * gv.y + bv.y),
                (bf16_t)((v.z - mu) * inv * gv.z + bv.z),
                (bf16_t)((v.w - mu) * inv * gv.w + bv.w)};
    *(bf16x4*)(y + i) = o;
  }
}

// ---------------- fused part8-reduce + QW: QW[bk,h,c] = sum_d Q[..]*kW[..] ----
__global__ __launch_bounds__(256) void qw_fuse(
    const float* __restrict__ part8, const float* __restrict__ kW, float* __restrict__ QW) {
  __shared__ float q[256];
  const int bk = blockIdx.x;
  const int c = threadIdx.x;
  float sq = 0.f;
#pragma unroll
  for (int s = 0; s < 8; ++s) sq += part8[(size_t)s * 65536 + (size_t)bk * 256 + c];
  q[c] = 0.125f * sq;
  __syncthreads();
#pragma unroll
  for (int h = 0; h < 4; ++h) {
    float s = 0.f;
#pragma unroll 8
    for (int d = 0; d < 64; ++d)
      s += q[(h << 6) + d] * kW[(size_t)(((h << 6) + d) << 8) + c];
    QW[((size_t)(bk * 4 + h) << 8) + c] = s;
  }
}

// ---------------- fused conv1(4->4,silu) + conv2(4->1) + bilinear up ----------
__global__ __launch_bounds__(256) void conv_fused(
    const bf16_t* __restrict__ X, const float* __restrict__ W1,
    const float* __restrict__ B1, const float* __restrict__ W2,
    const float* __restrict__ B2, float* __restrict__ O) {
  __shared__ bf16_t lg[16384];
  __shared__ bf16_t mid[16384];
  __shared__ float lg64[4096];
  __shared__ float wsh[180];
  const int t = threadIdx.x;
  const size_t base = (size_t)blockIdx.x * 16384;
#pragma unroll
  for (int i = 0; i < 8; ++i) {
    int o = (i * 256 + t) * 8;
    *(bf16x8*)&lg[o] = *(const bf16x8*)(X + base + o);
  }
  if (t < 144) wsh[t] = W1[t];
  else if (t < 180) wsh[t] = W2[t - 144];
  __syncthreads();
  const int px0 = (t & 15) * 4, py0 = (t >> 4) * 4;
  {
    float acc1[4][16];
#pragma unroll
    for (int oc = 0; oc < 4; ++oc) {
      float bb = B1[oc];
#pragma unroll
      for (int p = 0; p < 16; ++p) acc1[oc][p] = bb;
    }
#pragma unroll
    for (int c = 0; c < 4; ++c) {
      float p[6][6];
#pragma unroll
      for (int yy = 0; yy < 6; ++yy) {
        int gy = py0 + yy - 1;
#pragma unroll
        for (int xx = 0; xx < 6; ++xx) {
          int gx = px0 + xx - 1;
          p[yy][xx] = ((unsigned)gy < 64u && (unsigned)gx < 64u)
                          ? (float)lg[c * 4096 + gy * 64 + gx] : 0.f;
        }
      }
#pragma unroll
      for (int oc = 0; oc < 4; ++oc) {
        float wr[9];
#pragma unroll
        for (int k = 0; k < 9; ++k) wr[k] = wsh[oc * 36 + c * 9 + k];
#pragma unroll
        for (int y = 0; y < 4; ++y)
#pragma unroll
          for (int x = 0; x < 4; ++x)
            acc1[oc][y * 4 + x] +=
                wr[0] * p[y][x] + wr[1] * p[y][x + 1] + wr[2] * p[y][x + 2]
              + wr[3] * p[y + 1][x] + wr[4] * p[y + 1][x + 1] + wr[5] * p[y + 1][x + 2]
              + wr[6] * p[y + 2][x] + wr[7] * p[y + 2][x + 1] + wr[8] * p[y + 2][x + 2];
      }
    }
#pragma unroll
    for (int oc = 0; oc < 4; ++oc)
#pragma unroll
      for (int y = 0; y < 4; ++y) {
        bf16x4 o;
#pragma unroll
        for (int x = 0; x < 4; ++x) o[x] = (bf16_t)silu_f(acc1[oc][y * 4 + x]);
        *(bf16x4*)&mid[oc * 4096 + (py0 + y) * 64 + px0] = o;
      }
  }
  __syncthreads();
  {
    float acc2[16];
    float bb = B2[0];
#pragma unroll
    for (int p = 0; p < 16; ++p) acc2[p] = bb;
#pragma unroll
    for (int c = 0; c < 4; ++c) {
      float p[6][6];
#pragma unroll
      for (int yy = 0; yy < 6; ++yy) {
        int gy = py0 + yy - 1;
#pragma unroll
        for (int xx = 0; xx < 6; ++xx) {
          int gx = px0 + xx - 1;
          p[yy][xx] = ((unsigned)gy < 64u && (unsigned)gx < 64u)
                          ? (float)mid[c * 4096 + gy * 64 + gx] : 0.f;
        }
      }
      float wr[9];
#pragma unroll
      for (int k = 0; k < 9; ++k) wr[k] = wsh[144 + c * 9 + k];
#pragma unroll
      for (int y = 0; y < 4; ++y)
#pragma unroll
        for (int x = 0; x < 4; ++x)
          acc2[y * 4 + x] +=
              wr[0] * p[y][x] + wr[1] * p[y][x + 1] + wr[2] * p[y][x + 2]
            + wr[3] * p[y + 1][x] + wr[4] * p[y + 1][x + 1] + wr[5] * p[y + 1][x + 2]
            + wr[6] * p[y + 2][x] + wr[7] * p[y + 2][x + 1] + wr[8] * p[y + 2][x + 2];
    }
#pragma unroll
    for (int y = 0; y < 4; ++y)
#pragma unroll
      for (int x = 0; x < 4; ++x) lg64[(py0 + y) * 64 + px0 + x] = acc2[y * 4 + x];
  }
  __syncthreads();
  float* Ob = O + (size_t)blockIdx.x * 65536;
  for (int rr = 0; rr < 64; ++rr) {
    int p4 = rr * 256 + t;
    int oy = p4 >> 6, ox0 = (p4 & 63) * 4;
    float sy = oy * 0.25f - 0.375f;
    int y0 = (int)floorf(sy);
    float wy = sy - (float)y0;
    int y1 = min(y0 + 1, 63); y0 = max(y0, 0);
    const float* r0 = &lg64[y0 * 64];
    const float* r1 = &lg64[y1 * 64];
    float4 o;
#pragma unroll
    for (int q = 0; q < 4; ++q) {
      int ox = ox0 + q;
      float sx = ox * 0.25f - 0.375f;
      int x0 = (int)floorf(sx);
      float wx = sx - (float)x0;
      int x1 = min(x0 + 1, 63); x0 = max(x0, 0);
      float v0 = r0[x0] + wx * (r0[x1] - r0[x0]);
      float v1 = r1[x0] + wx * (r1[x1] - r1[x0]);
      ((float*)&o)[q] = v0 + wy * (v1 - v0);
    }
    *(float4*)(Ob + oy * 256 + ox0) = o;
  }
}

// ---------------- confidence: out[row] = dot(cfh_row, w2) + b2 ----------------
__global__ __launch_bounds__(256) void conf_k(
    const float* __restrict__ cfh, const float* __restrict__ w2,
    const float* __restrict__ b2, float* __restrict__ out) {
  __shared__ float tmp[4];
  const int row = blockIdx.x;
  float s = 0.f;
  for (int i = threadIdx.x; i < 2048; i += 256)
    s += cfh[(size_t)row * 2048 + i] * w2[i];
  s = block_sum(s, tmp);
  if (threadIdx.x == 0) out[row] = s + b2[0];
}

extern "C" void kernel_launch(void* const* d_in, const int* in_sizes, int n_in,
                              void* d_out, int out_size, void* d_ws, size_t ws_size,
                              hipStream_t stream) {
  const float* img    = (const float*)d_in[0];
  const float* refv   = (const float*)d_in[1];
  const float* qs     = (const float*)d_in[2];
  const float* qpw    = (const float*)d_in[3];
  const float* kpw    = (const float*)d_in[4];
  const float* fw1    = (const float*)d_in[5];
  const float* fb1    = (const float*)d_in[6];
  const float* fw2    = (const float*)d_in[7];
  const float* fb2    = (const float*)d_in[8];
  const float* qbw    = (const float*)d_in[9];
  const float* rlg    = (const float*)d_in[10];
  const float* rlb    = (const float*)d_in[11];
  const float* rlw    = (const float*)d_in[12];
  const float* rlbias = (const float*)d_in[13];
  const float* clg    = (const float*)d_in[14];
  const float* clb    = (const float*)d_in[15];
  const float* cw1    = (const float*)d_in[16];
  const float* cb1    = (const float*)d_in[17];
  const float* cw2    = (const float*)d_in[18];
  const float* cb2    = (const float*)d_in[19];
  float* out = (float*)d_out;
  char* W = (char*)d_ws;

  // --- workspace layout (bytes); disjoint lifetimes per region ---
  bf16_t* partQ = (bf16_t*)(W + 0);          // 16.8 MB steps 1-2
  bf16_t* partF = (bf16_t*)(W + 0);          // 16.8 MB steps 3-4 (partQ dead)
  bf16_t* l64hb = (bf16_t*)(W + 0);          //  8.4 MB steps 7-8 (partF dead)
  bf16_t* partC = (bf16_t*)(W + 0);          // 16.8 MB steps 10-11
  bf16_t* catln = (bf16_t*)(W + 16777216);   //  4.2 MB steps 2-3
  float*  fus   = (float*)(W + 16777216);    //  4.2 MB steps 4-9 (catln dead)
  bf16_t* fusb  = (bf16_t*)(W + 20971520);   //  2.1 MB steps 4-5
  bf16_t* lnf   = (bf16_t*)(W + 20971520);   //  2.1 MB steps 9-10 (fusb dead)
  float*  part8 = (float*)(W + 23068672);    //  2.1 MB steps 5-6
  float*  QW    = (float*)(W + 25165824);    //  1.1 MB steps 6-7
  float*  cfh   = (float*)(W + 26214400);    //  2.1 MB steps 11-12

  dim3 b256(256);

  // 1. qb GEMM (split-K x8): partQ[s] = qs @ qbw^T chunk
  gemm_wide_s<<<dim3(32, 8), dim3(1024), 0, stream>>>(qs, qbw, partQ, 4096, 512, 64);
  // 2. catln = LN(concat(refv, sum partQ)) -> bf16  (fused reduce+LN)
  ln_fuse<<<dim3(256), b256, 0, stream>>>(refv, partQ, 8, rlg, rlb, catln);
  // 3. fused GEMM (split-K x8, dbuf pipelined): partF[s] = catln @ rlw^T chunk
  gemm_wide<<<dim3(32, 8), dim3(1024), 0, stream>>>(catln, rlw, partF, 4096, 8192, 1024);
  // 4. fus = silu(sum partF + bias) -> f32 + bf16
  reduce_b<1, 1><<<dim3(512), b256, 0, stream>>>(
      partF, 8, 1048576L, rlbias, 1.f, fus, fusb, 4095L, 131072L);
  // 5. qproj GEMM (split-K x8): part8[s] = fusb @ qpw^T chunk (f32 partials)
  gemm_small<<<dim3(4, 4, 8), b256, 0, stream>>>(fusb, qpw, part8, 256, 256, 4096, 512, 8);
  // 6. QW = per-head (0.125 * sum part8) @ k_proj  (fused reduce+qw)
  qw_fuse<<<dim3(256), b256, 0, stream>>>(part8, kpw, QW);
  // 7. logits (full-M): l64hb[b] = QW_b @ img_b
  gemm_attn<<<dim3(64, 8), dim3(512), 0, stream>>>(QW, img, l64hb);
  // 8. out = upsample(conv2(silu(conv1(l64hb))))
  conv_fused<<<dim3(256), b256, 0, stream>>>(l64hb, fw1, fb1, fw2, fb2, out);
  // 9. lnf = LN(fus) -> bf16
  ln_rows<<<dim3(256), b256, 0, stream>>>(fus, 4096, clg, clb, lnf);
  // 10. cfh GEMM (split-K x16, dbuf pipelined nt=4): partC[s] = lnf @ cw1^T chunk
  gemm_wide<<<dim3(16, 16), dim3(1024), 0, stream>>>(lnf, cw1, partC, 2048, 4096, 256);
  // 11. cfh = silu(sum partC + cb1) -> f32
  reduce_b<1, 1><<<dim3(256), b256, 0, stream>>>(
      partC, 16, 524288L, cb1, 1.f, cfh, nullptr, 2047L, 65536L);
  // 12. conf out
  conf_k<<<dim3(256), b256, 0, stream>>>(cfh, cw2, cb2, out + 16777216);
}

// Round 9
// 184.704 us; speedup vs baseline: 7.6674x; 1.0173x over previous
//
#include <hip/hip_runtime.h>

#define EPS 1e-5f

typedef __bf16 bf16_t;
typedef __bf16 bf16x8 __attribute__((ext_vector_type(8)));
typedef __bf16 bf16x4 __attribute__((ext_vector_type(4)));
typedef float f32x4 __attribute__((ext_vector_type(4)));

__device__ __forceinline__ float silu_f(float x) { return x / (1.f + __expf(-x)); }

__device__ __forceinline__ void gll16(const void* g, void* l) {
  __builtin_amdgcn_global_load_lds(
      (const __attribute__((address_space(1))) unsigned int*)g,
      (__attribute__((address_space(3))) unsigned int*)l, 16, 0, 0);
}

// ---------------- block reduction (256 threads = 4 waves) ----------------
__device__ __forceinline__ float block_sum(float v, float* tmp) {
#pragma unroll
  for (int off = 32; off > 0; off >>= 1) v += __shfl_down(v, off);
  __syncthreads();
  if ((threadIdx.x & 63) == 0) tmp[threadIdx.x >> 6] = v;
  __syncthreads();
  return tmp[0] + tmp[1] + tmp[2] + tmp[3];
}

// ============================================================================
// gemm_gll: Cpart[z](bf16) = A(256,K)bf16 @ B(N,K)^T f32 via global_load_lds.
// tile 256x128, BK=64, 1024 threads (16 waves, wave-tile 64x32).
// Double-buffered LINEAR LDS (A bf16 32KB + B f32 32KB per buf = 128 KB);
// staging via global_load_lds width=16 (zero VGPR: ~8 loads/wave in flight ->
// ~64-128 KB/CU outstanding, HBM-saturating). XOR chunk-swizzle applied on the
// GLOBAL source (per-lane addr) and on the ds_read side; LDS dest stays linear
// (rule: both-sides-or-neither). Counted vmcnt(4) at each phase head (never 0
// mid-loop). B stored f32 in LDS, converted to bf16 at frag assembly.
// Grid: (N/128, S), KS = K/S, nt = KS/64 >= 1.
// ============================================================================
__global__ __launch_bounds__(1024) void gemm_gll(
    const bf16_t* __restrict__ A, const float* __restrict__ B,
    bf16_t* __restrict__ Cpart, int N, int K, int KS) {
  __shared__ bf16_t AsL[2][16384];  // 256 rows x 64 bf16 (128 B rows, 8 chunks)
  __shared__ float BsL[2][8192];    // 128 rows x 64 f32  (256 B rows, 16 chunks)
  const int t = threadIdx.x;
  const int lane = t & 63;
  const int w = t >> 6;  // 0..15
  const int n0 = blockIdx.x * 128;
  const int kbeg = blockIdx.y * KS;
  const int nt = KS >> 6;

  // ---- loader geometry (per-lane global src, swizzled; wave-uniform LDS dest)
  // A chunk c=2w+i covers rows 16w+8i..+8. lane -> row +(lane>>3), slot lane&7,
  // data-chunk = slot ^ (row&7); row&7 == lane>>3.
  const int arow0 = 16 * w + (lane >> 3);
  const int adch = (lane & 7) ^ (lane >> 3);
  const bf16_t* gA0 = A + (size_t)arow0 * K + kbeg + adch * 8;
  const bf16_t* gA1 = gA0 + (size_t)8 * K;
  // B chunk c=2w+i covers rows 8w+4i..+4. lane -> row +(lane>>4), slot lane&15,
  // data-chunk = slot ^ (row&15).
  const int brow0 = 8 * w + (lane >> 4);
  const int brow1 = brow0 + 4;
  const int bd0 = (lane & 15) ^ (brow0 & 15);
  const int bd1 = (lane & 15) ^ (brow1 & 15);
  const float* gB0 = B + (size_t)(n0 + brow0) * K + kbeg + bd0 * 4;
  const float* gB1 = B + (size_t)(n0 + brow1) * K + kbeg + bd1 * 4;

  f32x4 acc[4][2];
#pragma unroll
  for (int i = 0; i < 4; ++i)
#pragma unroll
    for (int j = 0; j < 2; ++j) acc[i][j] = f32x4{0.f, 0.f, 0.f, 0.f};

  const int wm = (w & 3) * 64;
  const int wn = (w >> 2) * 32;
  const int fr = lane & 15;
  const int kq = (lane >> 4) * 8;

  auto ISSUE = [&](int s, int p) {
    const int koff = s * 64;
    char* ab = (char*)&AsL[p][0] + 2 * w * 1024;
    char* bb = (char*)&BsL[p][0] + 2 * w * 1024;
    gll16(gA0 + koff, ab);
    gll16(gA1 + koff, ab + 1024);
    gll16(gB0 + koff, bb);
    gll16(gB1 + koff, bb + 1024);
  };

  auto COMPUTE = [&](int p) {
    const char* Ab = (const char*)&AsL[p][0];
    const char* Bb = (const char*)&BsL[p][0];
#pragma unroll
    for (int kk = 0; kk < 64; kk += 32) {
      const int col = kk + kq;
      bf16x8 af[4], bg[2];
#pragma unroll
      for (int i = 0; i < 4; ++i) {
        const int ra = wm + 16 * i + fr;
        const int sa = (col >> 3) ^ (ra & 7);
        af[i] = *(const bf16x8*)(Ab + ra * 128 + sa * 16);
      }
#pragma unroll
      for (int j = 0; j < 2; ++j) {
        const int rb = wn + 16 * j + fr;
        const int c0 = col >> 2;  // even 16B-chunk of the 8-f32 run
        const int s0 = c0 ^ (rb & 15);
        const int s1 = (c0 + 1) ^ (rb & 15);
        f32x4 u0 = *(const f32x4*)(Bb + rb * 256 + s0 * 16);
        f32x4 u1 = *(const f32x4*)(Bb + rb * 256 + s1 * 16);
        bf16x8 bv;
        bv[0] = (bf16_t)u0[0]; bv[1] = (bf16_t)u0[1];
        bv[2] = (bf16_t)u0[2]; bv[3] = (bf16_t)u0[3];
        bv[4] = (bf16_t)u1[0]; bv[5] = (bf16_t)u1[1];
        bv[6] = (bf16_t)u1[2]; bv[7] = (bf16_t)u1[3];
        bg[j] = bv;
      }
#pragma unroll
      for (int i = 0; i < 4; ++i)
#pragma unroll
        for (int j = 0; j < 2; ++j)
          acc[i][j] = __builtin_amdgcn_mfma_f32_16x16x32_bf16(af[i], bg[j], acc[i][j], 0, 0, 0);
    }
  };

#define SB __builtin_amdgcn_sched_barrier(0);

  // prologue: steps 0,1 in flight (8 gll/wave outstanding)
  ISSUE(0, 0);
  if (nt > 1) ISSUE(1, 1);
  for (int s = 0; s < nt; ++s) {
    const int p = s & 1;
    if (s + 1 < nt) {
      asm volatile("s_waitcnt vmcnt(4)" ::: "memory");  // step-s glls done
    } else {
      asm volatile("s_waitcnt vmcnt(0)" ::: "memory");
    }
    SB __builtin_amdgcn_s_barrier(); SB
    COMPUTE(p);
    if (s + 2 < nt) {
      asm volatile("s_waitcnt lgkmcnt(0)" ::: "memory");
      SB __builtin_amdgcn_s_barrier(); SB  // all waves done reading buf p
      ISSUE(s + 2, p);
    }
  }
#undef SB

  bf16_t* Cz = Cpart + (size_t)blockIdx.y * 256 * N;
  const int rh = (lane >> 4) * 4, col = lane & 15;
#pragma unroll
  for (int i = 0; i < 4; ++i)
#pragma unroll
    for (int j = 0; j < 2; ++j)
#pragma unroll
      for (int rr = 0; rr < 4; ++rr)
        Cz[(size_t)(wm + 16 * i + rh + rr) * N + n0 + wn + 16 * j + col] =
            (bf16_t)acc[i][j][rr];
}

// ============================================================================
// gemm_wide_s: simple 256x128 variant, A f32 (qb GEMM). Grid: (N/128, S).
// ============================================================================
__global__ __launch_bounds__(1024) void gemm_wide_s(
    const float* __restrict__ A, const float* __restrict__ B,
    bf16_t* __restrict__ Cpart, int N, int K, int KS) {
  __shared__ bf16_t As[256][72];
  __shared__ bf16_t Bs[128][72];
  const int t = threadIdx.x;
  const int lane = t & 63;
  const int w = t >> 6;
  const int n0 = blockIdx.x * 128;
  const int kbeg = blockIdx.y * KS;
  const int nt = KS >> 6;
  const int ar = t >> 2, ac = (t & 3) * 16;
  const int br = t >> 3, bc = (t & 7) * 8;
  const float* Ap = A + (size_t)ar * K + kbeg + ac;
  const float* Bp = B + (size_t)(n0 + br) * K + kbeg + bc;

  f32x4 acc[4][2];
#pragma unroll
  for (int i = 0; i < 4; ++i)
#pragma unroll
    for (int j = 0; j < 2; ++j) acc[i][j] = f32x4{0.f, 0.f, 0.f, 0.f};

  const int wm = (w & 3) * 64;
  const int wn = (w >> 2) * 32;
  const int fr = lane & 15;
  const int kq = (lane >> 4) * 8;

  for (int s = 0; s < nt; ++s) {
    float4 av[4], bv[2];
#pragma unroll
    for (int i = 0; i < 4; ++i) av[i] = *(const float4*)(Ap + s * 64 + 4 * i);
#pragma unroll
    for (int i = 0; i < 2; ++i) bv[i] = *(const float4*)(Bp + s * 64 + 4 * i);
    __syncthreads();
    {
      bf16x8 wa0, wa1, wb;
      wa0[0] = (bf16_t)av[0].x; wa0[1] = (bf16_t)av[0].y; wa0[2] = (bf16_t)av[0].z; wa0[3] = (bf16_t)av[0].w;
      wa0[4] = (bf16_t)av[1].x; wa0[5] = (bf16_t)av[1].y; wa0[6] = (bf16_t)av[1].z; wa0[7] = (bf16_t)av[1].w;
      wa1[0] = (bf16_t)av[2].x; wa1[1] = (bf16_t)av[2].y; wa1[2] = (bf16_t)av[2].z; wa1[3] = (bf16_t)av[2].w;
      wa1[4] = (bf16_t)av[3].x; wa1[5] = (bf16_t)av[3].y; wa1[6] = (bf16_t)av[3].z; wa1[7] = (bf16_t)av[3].w;
      wb[0] = (bf16_t)bv[0].x; wb[1] = (bf16_t)bv[0].y; wb[2] = (bf16_t)bv[0].z; wb[3] = (bf16_t)bv[0].w;
      wb[4] = (bf16_t)bv[1].x; wb[5] = (bf16_t)bv[1].y; wb[6] = (bf16_t)bv[1].z; wb[7] = (bf16_t)bv[1].w;
      *(bf16x8*)&As[ar][ac] = wa0;
      *(bf16x8*)&As[ar][ac + 8] = wa1;
      *(bf16x8*)&Bs[br][bc] = wb;
    }
    __syncthreads();
#pragma unroll
    for (int kk = 0; kk < 64; kk += 32) {
      bf16x8 af[4], bg[2];
#pragma unroll
      for (int i = 0; i < 4; ++i)
        af[i] = *(const bf16x8*)&As[wm + 16 * i + fr][kk + kq];
#pragma unroll
      for (int j = 0; j < 2; ++j)
        bg[j] = *(const bf16x8*)&Bs[wn + 16 * j + fr][kk + kq];
#pragma unroll
      for (int i = 0; i < 4; ++i)
#pragma unroll
        for (int j = 0; j < 2; ++j)
          acc[i][j] = __builtin_amdgcn_mfma_f32_16x16x32_bf16(af[i], bg[j], acc[i][j], 0, 0, 0);
    }
    __syncthreads();
  }

  bf16_t* Cz = Cpart + (size_t)blockIdx.y * 256 * N;
  const int rh = (lane >> 4) * 4, col = lane & 15;
#pragma unroll
  for (int i = 0; i < 4; ++i)
#pragma unroll
    for (int j = 0; j < 2; ++j)
#pragma unroll
      for (int rr = 0; rr < 4; ++rr)
        Cz[(size_t)(wm + 16 * i + rh + rr) * N + n0 + wn + 16 * j + col] =
            (bf16_t)acc[i][j][rr];
}

// ============================================================================
// gemm_small (64x64 tile) -- qproj GEMM. A bf16, B f32, f32 split-K partials.
// ============================================================================
__global__ __launch_bounds__(256) void gemm_small(
    const bf16_t* __restrict__ A16, const float* __restrict__ B32, float* __restrict__ Cv,
    int M, int N, int K, int KS, int S) {
  __shared__ bf16_t As[64][72];
  __shared__ bf16_t Bs[64][72];
  const int t = threadIdx.x;
  const int lane = t & 63;
  const int w = t >> 6;
  const int s = blockIdx.z;
  const int n0 = blockIdx.x * 64;
  const int m0 = blockIdx.y * 64;
  const int kbeg = s * KS;

  f32x4 acc[2][2];
#pragma unroll
  for (int i = 0; i < 2; ++i)
#pragma unroll
    for (int j = 0; j < 2; ++j) acc[i][j] = f32x4{0.f, 0.f, 0.f, 0.f};

  const int wm = (w & 1) * 32, wn = (w >> 1) * 32;
  const int fr = lane & 15;
  const int kq = (lane >> 4) * 8;

  for (int k0 = kbeg; k0 < kbeg + KS; k0 += 64) {
    bf16x8 a8[2];
    float4 b4[4];
    {
      const int rr = t >> 2, c8 = (t & 3) * 8;
#pragma unroll
      for (int i = 0; i < 2; ++i)
        a8[i] = *(const bf16x8*)(A16 + (size_t)(m0 + rr) * K + k0 + c8 + 32 * i);
    }
    {
      const int rr = t >> 4, c4 = (t & 15) * 4;
#pragma unroll
      for (int i = 0; i < 4; ++i)
        b4[i] = *(const float4*)(B32 + (size_t)(n0 + rr + 16 * i) * K + k0 + c4);
    }
    __syncthreads();
    {
      const int rr = t >> 2, c8 = (t & 3) * 8;
#pragma unroll
      for (int i = 0; i < 2; ++i) *(bf16x8*)&As[rr][c8 + 32 * i] = a8[i];
    }
    {
      const int rr = t >> 4, c4 = (t & 15) * 4;
#pragma unroll
      for (int i = 0; i < 4; ++i) {
        bf16x4 v = {(bf16_t)b4[i].x, (bf16_t)b4[i].y, (bf16_t)b4[i].z, (bf16_t)b4[i].w};
        *(bf16x4*)&Bs[rr + 16 * i][c4] = v;
      }
    }
    __syncthreads();
#pragma unroll
    for (int kk = 0; kk < 64; kk += 32) {
      bf16x8 af[2], bg[2];
#pragma unroll
      for (int i = 0; i < 2; ++i) {
        af[i] = *(const bf16x8*)&As[wm + 16 * i + fr][kk + kq];
        bg[i] = *(const bf16x8*)&Bs[wn + 16 * i + fr][kk + kq];
      }
#pragma unroll
      for (int i = 0; i < 2; ++i)
#pragma unroll
        for (int j = 0; j < 2; ++j)
          acc[i][j] = __builtin_amdgcn_mfma_f32_16x16x32_bf16(af[i], bg[j], acc[i][j], 0, 0, 0);
    }
    __syncthreads();
  }

  const int rh = (lane >> 4) * 4;
  const int col = lane & 15;
#pragma unroll
  for (int i = 0; i < 2; ++i)
#pragma unroll
    for (int j = 0; j < 2; ++j)
#pragma unroll
      for (int rr = 0; rr < 4; ++rr)
        Cv[(size_t)s * M * N + (size_t)(m0 + wm + 16 * i + rh + rr) * N + n0 + wn + 16 * j + col] =
            acc[i][j][rr];
}

// ============================================================================
// gemm_attn: per-batch C(128,4096)bf16 = A(128,256)f32 @ B(256,4096)f32
// ============================================================================
__global__ __launch_bounds__(512) void gemm_attn(
    const float* __restrict__ A, const float* __restrict__ B, bf16_t* __restrict__ C) {
  __shared__ bf16_t As[128][72];
  __shared__ bf16_t Bs[64][72];  // Bs[n][k]
  const int t = threadIdx.x;
  const int lane = t & 63;
  const int w = t >> 6;
  const int b = blockIdx.y;
  const int n0 = blockIdx.x * 64;
  const float* Ab = A + (size_t)b * 32768;
  const float* Bb = B + (size_t)b * 1048576;

  f32x4 acc[2][2];
#pragma unroll
  for (int i = 0; i < 2; ++i)
#pragma unroll
    for (int j = 0; j < 2; ++j) acc[i][j] = f32x4{0.f, 0.f, 0.f, 0.f};

  const int wm = (w & 3) * 32;
  const int wn = (w >> 2) * 32;
  const int fr = lane & 15;
  const int kq = (lane >> 4) * 8;

  for (int k0 = 0; k0 < 256; k0 += 64) {
    const int r = t >> 2, c4 = (t & 3) * 16;
    float4 a4[4];
#pragma unroll
    for (int i = 0; i < 4; ++i)
      a4[i] = *(const float4*)(Ab + (size_t)r * 256 + k0 + c4 + 4 * i);
    const int kr = t >> 3, nc = (t & 7) * 8;
    float4 b4[2];
#pragma unroll
    for (int i = 0; i < 2; ++i)
      b4[i] = *(const float4*)(Bb + (size_t)(k0 + kr) * 4096 + n0 + nc + 4 * i);
    __syncthreads();
#pragma unroll
    for (int i = 0; i < 4; ++i) {
      bf16x4 v = {(bf16_t)a4[i].x, (bf16_t)a4[i].y, (bf16_t)a4[i].z, (bf16_t)a4[i].w};
      *(bf16x4*)&As[r][c4 + 4 * i] = v;
    }
#pragma unroll
    for (int i = 0; i < 2; ++i) {
      Bs[nc + 4 * i + 0][kr] = (bf16_t)b4[i].x;
      Bs[nc + 4 * i + 1][kr] = (bf16_t)b4[i].y;
      Bs[nc + 4 * i + 2][kr] = (bf16_t)b4[i].z;
      Bs[nc + 4 * i + 3][kr] = (bf16_t)b4[i].w;
    }
    __syncthreads();
#pragma unroll
    for (int kk = 0; kk < 64; kk += 32) {
      bf16x8 af[2], bg[2];
#pragma unroll
      for (int i = 0; i < 2; ++i) {
        af[i] = *(const bf16x8*)&As[wm + 16 * i + fr][kk + kq];
        bg[i] = *(const bf16x8*)&Bs[wn + 16 * i + fr][kk + kq];
      }
#pragma unroll
      for (int i = 0; i < 2; ++i)
#pragma unroll
        for (int j = 0; j < 2; ++j)
          acc[i][j] = __builtin_amdgcn_mfma_f32_16x16x32_bf16(af[i], bg[j], acc[i][j], 0, 0, 0);
    }
    __syncthreads();
  }

  bf16_t* Cb = C + (size_t)b * 524288;
  const int rh = (lane >> 4) * 4, col = lane & 15;
#pragma unroll
  for (int i = 0; i < 2; ++i)
#pragma unroll
    for (int j = 0; j < 2; ++j)
#pragma unroll
      for (int rr = 0; rr < 4; ++rr)
        Cb[(size_t)(wm + 16 * i + rh + rr) * 4096 + n0 + wn + 16 * j + col] =
            (bf16_t)acc[i][j][rr];
}

// ---------------- split-K reduce (bf16 partials) + bias + silu ----------------
template <int SILU_, int BIAS_>
__global__ __launch_bounds__(256) void reduce_b(
    const bf16_t* __restrict__ part, int S, long slice,
    const float* __restrict__ bias, float scale,
    float* __restrict__ outF, bf16_t* __restrict__ outB,
    long nmask, long total8) {
  long i8 = (long)blockIdx.x * 256 + threadIdx.x;
  if (i8 >= total8) return;
  long i = i8 * 8;
  float a[8] = {0.f, 0.f, 0.f, 0.f, 0.f, 0.f, 0.f, 0.f};
  for (int s = 0; s < S; ++s) {
    bf16x8 v = *(const bf16x8*)(part + (size_t)s * slice + i);
#pragma unroll
    for (int j = 0; j < 8; ++j) a[j] += (float)v[j];
  }
#pragma unroll
  for (int j = 0; j < 8; ++j) a[j] *= scale;
  if (BIAS_) {
    const float* bb = bias + (i & nmask);
#pragma unroll
    for (int j = 0; j < 8; ++j) a[j] += bb[j];
  }
  if (SILU_) {
#pragma unroll
    for (int j = 0; j < 8; ++j) a[j] = silu_f(a[j]);
  }
  if (outF) {
    float4 o0 = {a[0], a[1], a[2], a[3]}, o1 = {a[4], a[5], a[6], a[7]};
    *(float4*)(outF + i) = o0;
    *(float4*)(outF + i + 4) = o1;
  }
  if (outB) {
    bf16x8 o;
#pragma unroll
    for (int j = 0; j < 8; ++j) o[j] = (bf16_t)a[j];
    *(bf16x8*)(outB + i) = o;
  }
}

// ---------------- fused partQ-reduce + LayerNorm(concat(refv, qb)) -> bf16 ---
__global__ __launch_bounds__(256) void ln_fuse(
    const float* __restrict__ refv, const bf16_t* __restrict__ partQ, int S,
    const float* __restrict__ g, const float* __restrict__ bta, bf16_t* __restrict__ Y) {
  __shared__ float tmp[4];
  const int row = blockIdx.x;
  const int t = threadIdx.x;
  const long i0 = t * 16;
  float q[16];
#pragma unroll
  for (int j = 0; j < 16; ++j) q[j] = 0.f;
  for (int s = 0; s < S; ++s) {
    const bf16_t* p = partQ + (size_t)s * 1048576 + (size_t)row * 4096 + i0;
    bf16x8 v0 = *(const bf16x8*)(p);
    bf16x8 v1 = *(const bf16x8*)(p + 8);
#pragma unroll
    for (int j = 0; j < 8; ++j) { q[j] += (float)v0[j]; q[8 + j] += (float)v1[j]; }
  }
  const float* xr = refv + (size_t)row * 4096 + i0;
  float r[16];
#pragma unroll
  for (int j = 0; j < 4; ++j) {
    float4 v = *(const float4*)(xr + 4 * j);
    r[4 * j] = v.x; r[4 * j + 1] = v.y; r[4 * j + 2] = v.z; r[4 * j + 3] = v.w;
  }
  float s1 = 0.f, s2 = 0.f;
#pragma unroll
  for (int j = 0; j < 16; ++j) { s1 += r[j] + q[j]; s2 += r[j] * r[j] + q[j] * q[j]; }
  s1 = block_sum(s1, tmp);
  s2 = block_sum(s2, tmp);
  const float mu = s1 / 8192.f;
  const float inv = rsqrtf(s2 / 8192.f - mu * mu + EPS);
  bf16_t* y = Y + (size_t)row * 8192;
  bf16x8 o0, o1;
#pragma unroll
  for (int j = 0; j < 8; ++j) {
    o0[j] = (bf16_t)((r[j] - mu) * inv * g[i0 + j] + bta[i0 + j]);
    o1[j] = (bf16_t)((r[8 + j] - mu) * inv * g[i0 + 8 + j] + bta[i0 + 8 + j]);
  }
  *(bf16x8*)(y + i0) = o0;
  *(bf16x8*)(y + i0 + 8) = o1;
#pragma unroll
  for (int j = 0; j < 8; ++j) {
    o0[j] = (bf16_t)((q[j] - mu) * inv * g[4096 + i0 + j] + bta[4096 + i0 + j]);
    o1[j] = (bf16_t)((q[8 + j] - mu) * inv * g[4096 + i0 + 8 + j] + bta[4096 + i0 + 8 + j]);
  }
  *(bf16x8*)(y + 4096 + i0) = o0;
  *(bf16x8*)(y + 4096 + i0 + 8) = o1;
}

// ---------------- LayerNorm over rows (single f32 input) -> bf16 ----------------
__global__ __launch_bounds__(256) void ln_rows(
    const float* __restrict__ X1, int L1,
    const float* __restrict__ g, const float* __restrict__ bta, bf16_t* __restrict__ Y) {
  __shared__ float tmp[4];
  const int row = blockIdx.x;
  const float* x1 = X1 + (size_t)row * L1;
  float s = 0.f, ss = 0.f;
  for (int i = threadIdx.x * 4; i < L1; i += 1024) {
    float4 v = *(const float4*)(x1 + i);
    s += v.x + v.y + v.z + v.w;
    ss += v.x * v.x + v.y * v.y + v.z * v.z + v.w * v.w;
  }
  s = block_sum(s, tmp);
  ss = block_sum(ss, tmp);
  const float mu = s / (float)L1;
  const float inv = rsqrtf(ss / (float)L1 - mu * mu + EPS);
  bf16_t* y = Y + (size_t)row * L1;
  for (int i = threadIdx.x * 4; i < L1; i += 1024) {
    float4 v = *(const float4*)(x1 + i);
    float4 gv = *(const float4*)(g + i);
    float4 bv = *(const float4*)(bta + i);
    bf16x4 o = {(bf16_t)((v.x - mu) * inv * gv.x + bv.x),
                (bf16_t)((v.y - mu) * inv * gv.y + bv.y),
                (bf16_t)((v.z - mu) * inv * gv.z + bv.z),
                (bf16_t)((v.w - mu) * inv * gv.w + bv.w)};
    *(bf16x4*)(y + i) = o;
  }
}

// ---------------- fused part8-reduce + QW ----------------
__global__ __launch_bounds__(256) void qw_fuse(
    const float* __restrict__ part8, const float* __restrict__ kW, float* __restrict__ QW) {
  __shared__ float q[256];
  const int bk = blockIdx.x;
  const int c = threadIdx.x;
  float sq = 0.f;
#pragma unroll
  for (int s = 0; s < 8; ++s) sq += part8[(size_t)s * 65536 + (size_t)bk * 256 + c];
  q[c] = 0.125f * sq;
  __syncthreads();
#pragma unroll
  for (int h = 0; h < 4; ++h) {
    float s = 0.f;
#pragma unroll 8
    for (int d = 0; d < 64; ++d)
      s += q[(h << 6) + d] * kW[(size_t)(((h << 6) + d) << 8) + c];
    QW[((size_t)(bk * 4 + h) << 8) + c] = s;
  }
}

// ---------------- fused conv1(4->4,silu) + conv2(4->1) + bilinear up ----------
__global__ __launch_bounds__(256) void conv_fused(
    const bf16_t* __restrict__ X, const float* __restrict__ W1,
    const float* __restrict__ B1, const float* __restrict__ W2,
    const float* __restrict__ B2, float* __restrict__ O) {
  __shared__ bf16_t lg[16384];
  __shared__ bf16_t mid[16384];
  __shared__ float lg64[4096];
  __shared__ float wsh[180];
  const int t = threadIdx.x;
  const size_t base = (size_t)blockIdx.x * 16384;
#pragma unroll
  for (int i = 0; i < 8; ++i) {
    int o = (i * 256 + t) * 8;
    *(bf16x8*)&lg[o] = *(const bf16x8*)(X + base + o);
  }
  if (t < 144) wsh[t] = W1[t];
  else if (t < 180) wsh[t] = W2[t - 144];
  __syncthreads();
  const int px0 = (t & 15) * 4, py0 = (t >> 4) * 4;
  {
    float acc1[4][16];
#pragma unroll
    for (int oc = 0; oc < 4; ++oc) {
      float bb = B1[oc];
#pragma unroll
      for (int p = 0; p < 16; ++p) acc1[oc][p] = bb;
    }
#pragma unroll
    for (int c = 0; c < 4; ++c) {
      float p[6][6];
#pragma unroll
      for (int yy = 0; yy < 6; ++yy) {
        int gy = py0 + yy - 1;
#pragma unroll
        for (int xx = 0; xx < 6; ++xx) {
          int gx = px0 + xx - 1;
          p[yy][xx] = ((unsigned)gy < 64u && (unsigned)gx < 64u)
                          ? (float)lg[c * 4096 + gy * 64 + gx] : 0.f;
        }
      }
#pragma unroll
      for (int oc = 0; oc < 4; ++oc) {
        float wr[9];
#pragma unroll
        for (int k = 0; k < 9; ++k) wr[k] = wsh[oc * 36 + c * 9 + k];
#pragma unroll
        for (int y = 0; y < 4; ++y)
#pragma unroll
          for (int x = 0; x < 4; ++x)
            acc1[oc][y * 4 + x] +=
                wr[0] * p[y][x] + wr[1] * p[y][x + 1] + wr[2] * p[y][x + 2]
              + wr[3] * p[y + 1][x] + wr[4] * p[y + 1][x + 1] + wr[5] * p[y + 1][x + 2]
              + wr[6] * p[y + 2][x] + wr[7] * p[y + 2][x + 1] + wr[8] * p[y + 2][x + 2];
      }
    }
#pragma unroll
    for (int oc = 0; oc < 4; ++oc)
#pragma unroll
      for (int y = 0; y < 4; ++y) {
        bf16x4 o;
#pragma unroll
        for (int x = 0; x < 4; ++x) o[x] = (bf16_t)silu_f(acc1[oc][y * 4 + x]);
        *(bf16x4*)&mid[oc * 4096 + (py0 + y) * 64 + px0] = o;
      }
  }
  __syncthreads();
  {
    float acc2[16];
    float bb = B2[0];
#pragma unroll
    for (int p = 0; p < 16; ++p) acc2[p] = bb;
#pragma unroll
    for (int c = 0; c < 4; ++c) {
      float p[6][6];
#pragma unroll
      for (int yy = 0; yy < 6; ++yy) {
        int gy = py0 + yy - 1;
#pragma unroll
        for (int xx = 0; xx < 6; ++xx) {
          int gx = px0 + xx - 1;
          p[yy][xx] = ((unsigned)gy < 64u && (unsigned)gx < 64u)
                          ? (float)mid[c * 4096 + gy * 64 + gx] : 0.f;
        }
      }
      float wr[9];
#pragma unroll
      for (int k = 0; k < 9; ++k) wr[k] = wsh[144 + c * 9 + k];
#pragma unroll
      for (int y = 0; y < 4; ++y)
#pragma unroll
        for (int x = 0; x < 4; ++x)
          acc2[y * 4 + x] +=
              wr[0] * p[y][x] + wr[1] * p[y][x + 1] + wr[2] * p[y][x + 2]
            + wr[3] * p[y + 1][x] + wr[4] * p[y + 1][x + 1] + wr[5] * p[y + 1][x + 2]
            + wr[6] * p[y + 2][x] + wr[7] * p[y + 2][x + 1] + wr[8] * p[y + 2][x + 2];
    }
#pragma unroll
    for (int y = 0; y < 4; ++y)
#pragma unroll
      for (int x = 0; x < 4; ++x) lg64[(py0 + y) * 64 + px0 + x] = acc2[y * 4 + x];
  }
  __syncthreads();
  float* Ob = O + (size_t)blockIdx.x * 65536;
  for (int rr = 0; rr < 64; ++rr) {
    int p4 = rr * 256 + t;
    int oy = p4 >> 6, ox0 = (p4 & 63) * 4;
    float sy = oy * 0.25f - 0.375f;
    int y0 = (int)floorf(sy);
    float wy = sy - (float)y0;
    int y1 = min(y0 + 1, 63); y0 = max(y0, 0);
    const float* r0 = &lg64[y0 * 64];
    const float* r1 = &lg64[y1 * 64];
    float4 o;
#pragma unroll
    for (int q = 0; q < 4; ++q) {
      int ox = ox0 + q;
      float sx = ox * 0.25f - 0.375f;
      int x0 = (int)floorf(sx);
      float wx = sx - (float)x0;
      int x1 = min(x0 + 1, 63); x0 = max(x0, 0);
      float v0 = r0[x0] + wx * (r0[x1] - r0[x0]);
      float v1 = r1[x0] + wx * (r1[x1] - r1[x0]);
      ((float*)&o)[q] = v0 + wy * (v1 - v0);
    }
    *(float4*)(Ob + oy * 256 + ox0) = o;
  }
}

// ---------------- confidence: out[row] = dot(cfh_row, w2) + b2 ----------------
__global__ __launch_bounds__(256) void conf_k(
    const float* __restrict__ cfh, const float* __restrict__ w2,
    const float* __restrict__ b2, float* __restrict__ out) {
  __shared__ float tmp[4];
  const int row = blockIdx.x;
  float s = 0.f;
  for (int i = threadIdx.x; i < 2048; i += 256)
    s += cfh[(size_t)row * 2048 + i] * w2[i];
  s = block_sum(s, tmp);
  if (threadIdx.x == 0) out[row] = s + b2[0];
}

extern "C" void kernel_launch(void* const* d_in, const int* in_sizes, int n_in,
                              void* d_out, int out_size, void* d_ws, size_t ws_size,
                              hipStream_t stream) {
  const float* img    = (const float*)d_in[0];
  const float* refv   = (const float*)d_in[1];
  const float* qs     = (const float*)d_in[2];
  const float* qpw    = (const float*)d_in[3];
  const float* kpw    = (const float*)d_in[4];
  const float* fw1    = (const float*)d_in[5];
  const float* fb1    = (const float*)d_in[6];
  const float* fw2    = (const float*)d_in[7];
  const float* fb2    = (const float*)d_in[8];
  const float* qbw    = (const float*)d_in[9];
  const float* rlg    = (const float*)d_in[10];
  const float* rlb    = (const float*)d_in[11];
  const float* rlw    = (const float*)d_in[12];
  const float* rlbias = (const float*)d_in[13];
  const float* clg    = (const float*)d_in[14];
  const float* clb    = (const float*)d_in[15];
  const float* cw1    = (const float*)d_in[16];
  const float* cb1    = (const float*)d_in[17];
  const float* cw2    = (const float*)d_in[18];
  const float* cb2    = (const float*)d_in[19];
  float* out = (float*)d_out;
  char* W = (char*)d_ws;

  // --- workspace layout (bytes); disjoint lifetimes per region ---
  bf16_t* partQ = (bf16_t*)(W + 0);          // 16.8 MB steps 1-2
  bf16_t* partF = (bf16_t*)(W + 0);          // 16.8 MB steps 3-4 (partQ dead)
  bf16_t* l64hb = (bf16_t*)(W + 0);          //  8.4 MB steps 7-8 (partF dead)
  bf16_t* partC = (bf16_t*)(W + 0);          //  8.4 MB steps 10-11
  bf16_t* catln = (bf16_t*)(W + 16777216);   //  4.2 MB steps 2-3
  float*  fus   = (float*)(W + 16777216);    //  4.2 MB steps 4-9 (catln dead)
  bf16_t* fusb  = (bf16_t*)(W + 20971520);   //  2.1 MB steps 4-5
  bf16_t* lnf   = (bf16_t*)(W + 20971520);   //  2.1 MB steps 9-10 (fusb dead)
  float*  part8 = (float*)(W + 23068672);    //  2.1 MB steps 5-6
  float*  QW    = (float*)(W + 25165824);    //  1.1 MB steps 6-7
  float*  cfh   = (float*)(W + 26214400);    //  2.1 MB steps 11-12

  dim3 b256(256);

  // 1. qb GEMM (split-K x8): partQ[s] = qs @ qbw^T chunk
  gemm_wide_s<<<dim3(32, 8), dim3(1024), 0, stream>>>(qs, qbw, partQ, 4096, 512, 64);
  // 2. catln = LN(concat(refv, sum partQ)) -> bf16
  ln_fuse<<<dim3(256), b256, 0, stream>>>(refv, partQ, 8, rlg, rlb, catln);
  // 3. fused GEMM (split-K x8, global_load_lds): partF[s] = catln @ rlw^T chunk
  gemm_gll<<<dim3(32, 8), dim3(1024), 0, stream>>>(catln, rlw, partF, 4096, 8192, 1024);
  // 4. fus = silu(sum partF + bias) -> f32 + bf16
  reduce_b<1, 1><<<dim3(512), b256, 0, stream>>>(
      partF, 8, 1048576L, rlbias, 1.f, fus, fusb, 4095L, 131072L);
  // 5. qproj GEMM (split-K x8): part8[s] = fusb @ qpw^T chunk
  gemm_small<<<dim3(4, 4, 8), b256, 0, stream>>>(fusb, qpw, part8, 256, 256, 4096, 512, 8);
  // 6. QW = per-head (0.125 * sum part8) @ k_proj
  qw_fuse<<<dim3(256), b256, 0, stream>>>(part8, kpw, QW);
  // 7. logits (full-M): l64hb[b] = QW_b @ img_b
  gemm_attn<<<dim3(64, 8), dim3(512), 0, stream>>>(QW, img, l64hb);
  // 8. out = upsample(conv2(silu(conv1(l64hb))))
  conv_fused<<<dim3(256), b256, 0, stream>>>(l64hb, fw1, fb1, fw2, fb2, out);
  // 9. lnf = LN(fus) -> bf16
  ln_rows<<<dim3(256), b256, 0, stream>>>(fus, 4096, clg, clb, lnf);
  // 10. cfh GEMM (split-K x8, global_load_lds): partC[s] = lnf @ cw1^T chunk
  gemm_gll<<<dim3(16, 8), dim3(1024), 0, stream>>>(lnf, cw1, partC, 2048, 4096, 512);
  // 11. cfh = silu(sum partC + cb1) -> f32
  reduce_b<1, 1><<<dim3(256), b256, 0, stream>>>(
      partC, 8, 524288L, cb1, 1.f, cfh, nullptr, 2047L, 65536L);
  // 12. conf out
  conf_k<<<dim3(256), b256, 0, stream>>>(cfh, cw2, cb2, out + 16777216);
}

// Round 10
// 178.039 us; speedup vs baseline: 7.9545x; 1.0374x over previous
//
#include <hip/hip_runtime.h>

#define EPS 1e-5f

typedef __bf16 bf16_t;
typedef __bf16 bf16x8 __attribute__((ext_vector_type(8)));
typedef __bf16 bf16x4 __attribute__((ext_vector_type(4)));
typedef float f32x4 __attribute__((ext_vector_type(4)));

__device__ __forceinline__ float silu_f(float x) { return x / (1.f + __expf(-x)); }

__device__ __forceinline__ void gll16(const void* g, void* l) {
  __builtin_amdgcn_global_load_lds(
      (const __attribute__((address_space(1))) unsigned int*)g,
      (__attribute__((address_space(3))) unsigned int*)l, 16, 0, 0);
}

// ---------------- block reduction (256 threads = 4 waves) ----------------
__device__ __forceinline__ float block_sum(float v, float* tmp) {
#pragma unroll
  for (int off = 32; off > 0; off >>= 1) v += __shfl_down(v, off);
  __syncthreads();
  if ((threadIdx.x & 63) == 0) tmp[threadIdx.x >> 6] = v;
  __syncthreads();
  return tmp[0] + tmp[1] + tmp[2] + tmp[3];
}

// ============================================================================
// gemm_gll: Cpart[z](bf16) = A(256,K)bf16 @ B(N,K)^T f32 via global_load_lds.
// tile 256x128, BK=64, 1024 threads (16 waves, wave-tile 64x32).
// Double-buffered LINEAR LDS; staging via global_load_lds width=16 (zero VGPR,
// ~8KB/wave in flight). XOR chunk-swizzle on the GLOBAL source + on the
// ds_read side; LDS dest linear. Counted vmcnt(4) mid-loop (never 0).
// Grid: (N/128, S), KS = K/S, nt = KS/64 >= 1.
// ============================================================================
__global__ __launch_bounds__(1024) void gemm_gll(
    const bf16_t* __restrict__ A, const float* __restrict__ B,
    bf16_t* __restrict__ Cpart, int N, int K, int KS) {
  __shared__ bf16_t AsL[2][16384];  // 256 rows x 64 bf16 (128 B rows, 8 chunks)
  __shared__ float BsL[2][8192];    // 128 rows x 64 f32  (256 B rows, 16 chunks)
  const int t = threadIdx.x;
  const int lane = t & 63;
  const int w = t >> 6;  // 0..15
  const int n0 = blockIdx.x * 128;
  const int kbeg = blockIdx.y * KS;
  const int nt = KS >> 6;

  const int arow0 = 16 * w + (lane >> 3);
  const int adch = (lane & 7) ^ (lane >> 3);
  const bf16_t* gA0 = A + (size_t)arow0 * K + kbeg + adch * 8;
  const bf16_t* gA1 = gA0 + (size_t)8 * K;
  const int brow0 = 8 * w + (lane >> 4);
  const int brow1 = brow0 + 4;
  const int bd0 = (lane & 15) ^ (brow0 & 15);
  const int bd1 = (lane & 15) ^ (brow1 & 15);
  const float* gB0 = B + (size_t)(n0 + brow0) * K + kbeg + bd0 * 4;
  const float* gB1 = B + (size_t)(n0 + brow1) * K + kbeg + bd1 * 4;

  f32x4 acc[4][2];
#pragma unroll
  for (int i = 0; i < 4; ++i)
#pragma unroll
    for (int j = 0; j < 2; ++j) acc[i][j] = f32x4{0.f, 0.f, 0.f, 0.f};

  const int wm = (w & 3) * 64;
  const int wn = (w >> 2) * 32;
  const int fr = lane & 15;
  const int kq = (lane >> 4) * 8;

  auto ISSUE = [&](int s, int p) {
    const int koff = s * 64;
    char* ab = (char*)&AsL[p][0] + 2 * w * 1024;
    char* bb = (char*)&BsL[p][0] + 2 * w * 1024;
    gll16(gA0 + koff, ab);
    gll16(gA1 + koff, ab + 1024);
    gll16(gB0 + koff, bb);
    gll16(gB1 + koff, bb + 1024);
  };

  auto COMPUTE = [&](int p) {
    const char* Ab = (const char*)&AsL[p][0];
    const char* Bb = (const char*)&BsL[p][0];
#pragma unroll
    for (int kk = 0; kk < 64; kk += 32) {
      const int col = kk + kq;
      bf16x8 af[4], bg[2];
#pragma unroll
      for (int i = 0; i < 4; ++i) {
        const int ra = wm + 16 * i + fr;
        const int sa = (col >> 3) ^ (ra & 7);
        af[i] = *(const bf16x8*)(Ab + ra * 128 + sa * 16);
      }
#pragma unroll
      for (int j = 0; j < 2; ++j) {
        const int rb = wn + 16 * j + fr;
        const int c0 = col >> 2;
        const int s0 = c0 ^ (rb & 15);
        const int s1 = (c0 + 1) ^ (rb & 15);
        f32x4 u0 = *(const f32x4*)(Bb + rb * 256 + s0 * 16);
        f32x4 u1 = *(const f32x4*)(Bb + rb * 256 + s1 * 16);
        bf16x8 bv;
        bv[0] = (bf16_t)u0[0]; bv[1] = (bf16_t)u0[1];
        bv[2] = (bf16_t)u0[2]; bv[3] = (bf16_t)u0[3];
        bv[4] = (bf16_t)u1[0]; bv[5] = (bf16_t)u1[1];
        bv[6] = (bf16_t)u1[2]; bv[7] = (bf16_t)u1[3];
        bg[j] = bv;
      }
#pragma unroll
      for (int i = 0; i < 4; ++i)
#pragma unroll
        for (int j = 0; j < 2; ++j)
          acc[i][j] = __builtin_amdgcn_mfma_f32_16x16x32_bf16(af[i], bg[j], acc[i][j], 0, 0, 0);
    }
  };

#define SB __builtin_amdgcn_sched_barrier(0);

  ISSUE(0, 0);
  if (nt > 1) ISSUE(1, 1);
  for (int s = 0; s < nt; ++s) {
    const int p = s & 1;
    if (s + 1 < nt) {
      asm volatile("s_waitcnt vmcnt(4)" ::: "memory");
    } else {
      asm volatile("s_waitcnt vmcnt(0)" ::: "memory");
    }
    SB __builtin_amdgcn_s_barrier(); SB
    COMPUTE(p);
    if (s + 2 < nt) {
      asm volatile("s_waitcnt lgkmcnt(0)" ::: "memory");
      SB __builtin_amdgcn_s_barrier(); SB
      ISSUE(s + 2, p);
    }
  }
#undef SB

  bf16_t* Cz = Cpart + (size_t)blockIdx.y * 256 * N;
  const int rh = (lane >> 4) * 4, col = lane & 15;
#pragma unroll
  for (int i = 0; i < 4; ++i)
#pragma unroll
    for (int j = 0; j < 2; ++j)
#pragma unroll
      for (int rr = 0; rr < 4; ++rr)
        Cz[(size_t)(wm + 16 * i + rh + rr) * N + n0 + wn + 16 * j + col] =
            (bf16_t)acc[i][j][rr];
}

// ============================================================================
// gemm_wide_s: simple 256x128 variant, A f32 (qb GEMM). Grid: (N/128, S).
// ============================================================================
__global__ __launch_bounds__(1024) void gemm_wide_s(
    const float* __restrict__ A, const float* __restrict__ B,
    bf16_t* __restrict__ Cpart, int N, int K, int KS) {
  __shared__ bf16_t As[256][72];
  __shared__ bf16_t Bs[128][72];
  const int t = threadIdx.x;
  const int lane = t & 63;
  const int w = t >> 6;
  const int n0 = blockIdx.x * 128;
  const int kbeg = blockIdx.y * KS;
  const int nt = KS >> 6;
  const int ar = t >> 2, ac = (t & 3) * 16;
  const int br = t >> 3, bc = (t & 7) * 8;
  const float* Ap = A + (size_t)ar * K + kbeg + ac;
  const float* Bp = B + (size_t)(n0 + br) * K + kbeg + bc;

  f32x4 acc[4][2];
#pragma unroll
  for (int i = 0; i < 4; ++i)
#pragma unroll
    for (int j = 0; j < 2; ++j) acc[i][j] = f32x4{0.f, 0.f, 0.f, 0.f};

  const int wm = (w & 3) * 64;
  const int wn = (w >> 2) * 32;
  const int fr = lane & 15;
  const int kq = (lane >> 4) * 8;

  for (int s = 0; s < nt; ++s) {
    float4 av[4], bv[2];
#pragma unroll
    for (int i = 0; i < 4; ++i) av[i] = *(const float4*)(Ap + s * 64 + 4 * i);
#pragma unroll
    for (int i = 0; i < 2; ++i) bv[i] = *(const float4*)(Bp + s * 64 + 4 * i);
    __syncthreads();
    {
      bf16x8 wa0, wa1, wb;
      wa0[0] = (bf16_t)av[0].x; wa0[1] = (bf16_t)av[0].y; wa0[2] = (bf16_t)av[0].z; wa0[3] = (bf16_t)av[0].w;
      wa0[4] = (bf16_t)av[1].x; wa0[5] = (bf16_t)av[1].y; wa0[6] = (bf16_t)av[1].z; wa0[7] = (bf16_t)av[1].w;
      wa1[0] = (bf16_t)av[2].x; wa1[1] = (bf16_t)av[2].y; wa1[2] = (bf16_t)av[2].z; wa1[3] = (bf16_t)av[2].w;
      wa1[4] = (bf16_t)av[3].x; wa1[5] = (bf16_t)av[3].y; wa1[6] = (bf16_t)av[3].z; wa1[7] = (bf16_t)av[3].w;
      wb[0] = (bf16_t)bv[0].x; wb[1] = (bf16_t)bv[0].y; wb[2] = (bf16_t)bv[0].z; wb[3] = (bf16_t)bv[0].w;
      wb[4] = (bf16_t)bv[1].x; wb[5] = (bf16_t)bv[1].y; wb[6] = (bf16_t)bv[1].z; wb[7] = (bf16_t)bv[1].w;
      *(bf16x8*)&As[ar][ac] = wa0;
      *(bf16x8*)&As[ar][ac + 8] = wa1;
      *(bf16x8*)&Bs[br][bc] = wb;
    }
    __syncthreads();
#pragma unroll
    for (int kk = 0; kk < 64; kk += 32) {
      bf16x8 af[4], bg[2];
#pragma unroll
      for (int i = 0; i < 4; ++i)
        af[i] = *(const bf16x8*)&As[wm + 16 * i + fr][kk + kq];
#pragma unroll
      for (int j = 0; j < 2; ++j)
        bg[j] = *(const bf16x8*)&Bs[wn + 16 * j + fr][kk + kq];
#pragma unroll
      for (int i = 0; i < 4; ++i)
#pragma unroll
        for (int j = 0; j < 2; ++j)
          acc[i][j] = __builtin_amdgcn_mfma_f32_16x16x32_bf16(af[i], bg[j], acc[i][j], 0, 0, 0);
    }
    __syncthreads();
  }

  bf16_t* Cz = Cpart + (size_t)blockIdx.y * 256 * N;
  const int rh = (lane >> 4) * 4, col = lane & 15;
#pragma unroll
  for (int i = 0; i < 4; ++i)
#pragma unroll
    for (int j = 0; j < 2; ++j)
#pragma unroll
      for (int rr = 0; rr < 4; ++rr)
        Cz[(size_t)(wm + 16 * i + rh + rr) * N + n0 + wn + 16 * j + col] =
            (bf16_t)acc[i][j][rr];
}

// ============================================================================
// gemm_small (64x64 tile) -- qproj GEMM. A bf16, B f32, f32 split-K partials.
// ============================================================================
__global__ __launch_bounds__(256) void gemm_small(
    const bf16_t* __restrict__ A16, const float* __restrict__ B32, float* __restrict__ Cv,
    int M, int N, int K, int KS, int S) {
  __shared__ bf16_t As[64][72];
  __shared__ bf16_t Bs[64][72];
  const int t = threadIdx.x;
  const int lane = t & 63;
  const int w = t >> 6;
  const int s = blockIdx.z;
  const int n0 = blockIdx.x * 64;
  const int m0 = blockIdx.y * 64;
  const int kbeg = s * KS;

  f32x4 acc[2][2];
#pragma unroll
  for (int i = 0; i < 2; ++i)
#pragma unroll
    for (int j = 0; j < 2; ++j) acc[i][j] = f32x4{0.f, 0.f, 0.f, 0.f};

  const int wm = (w & 1) * 32, wn = (w >> 1) * 32;
  const int fr = lane & 15;
  const int kq = (lane >> 4) * 8;

  for (int k0 = kbeg; k0 < kbeg + KS; k0 += 64) {
    bf16x8 a8[2];
    float4 b4[4];
    {
      const int rr = t >> 2, c8 = (t & 3) * 8;
#pragma unroll
      for (int i = 0; i < 2; ++i)
        a8[i] = *(const bf16x8*)(A16 + (size_t)(m0 + rr) * K + k0 + c8 + 32 * i);
    }
    {
      const int rr = t >> 4, c4 = (t & 15) * 4;
#pragma unroll
      for (int i = 0; i < 4; ++i)
        b4[i] = *(const float4*)(B32 + (size_t)(n0 + rr + 16 * i) * K + k0 + c4);
    }
    __syncthreads();
    {
      const int rr = t >> 2, c8 = (t & 3) * 8;
#pragma unroll
      for (int i = 0; i < 2; ++i) *(bf16x8*)&As[rr][c8 + 32 * i] = a8[i];
    }
    {
      const int rr = t >> 4, c4 = (t & 15) * 4;
#pragma unroll
      for (int i = 0; i < 4; ++i) {
        bf16x4 v = {(bf16_t)b4[i].x, (bf16_t)b4[i].y, (bf16_t)b4[i].z, (bf16_t)b4[i].w};
        *(bf16x4*)&Bs[rr + 16 * i][c4] = v;
      }
    }
    __syncthreads();
#pragma unroll
    for (int kk = 0; kk < 64; kk += 32) {
      bf16x8 af[2], bg[2];
#pragma unroll
      for (int i = 0; i < 2; ++i) {
        af[i] = *(const bf16x8*)&As[wm + 16 * i + fr][kk + kq];
        bg[i] = *(const bf16x8*)&Bs[wn + 16 * i + fr][kk + kq];
      }
#pragma unroll
      for (int i = 0; i < 2; ++i)
#pragma unroll
        for (int j = 0; j < 2; ++j)
          acc[i][j] = __builtin_amdgcn_mfma_f32_16x16x32_bf16(af[i], bg[j], acc[i][j], 0, 0, 0);
    }
    __syncthreads();
  }

  const int rh = (lane >> 4) * 4;
  const int col = lane & 15;
#pragma unroll
  for (int i = 0; i < 2; ++i)
#pragma unroll
    for (int j = 0; j < 2; ++j)
#pragma unroll
      for (int rr = 0; rr < 4; ++rr)
        Cv[(size_t)s * M * N + (size_t)(m0 + wm + 16 * i + rh + rr) * N + n0 + wn + 16 * j + col] =
            acc[i][j][rr];
}

// ============================================================================
// gemm_attn: per-batch C(128,4096)bf16 = A(128,256)f32 @ B(256,4096)f32
// ============================================================================
__global__ __launch_bounds__(512) void gemm_attn(
    const float* __restrict__ A, const float* __restrict__ B, bf16_t* __restrict__ C) {
  __shared__ bf16_t As[128][72];
  __shared__ bf16_t Bs[64][72];  // Bs[n][k]
  const int t = threadIdx.x;
  const int lane = t & 63;
  const int w = t >> 6;
  const int b = blockIdx.y;
  const int n0 = blockIdx.x * 64;
  const float* Ab = A + (size_t)b * 32768;
  const float* Bb = B + (size_t)b * 1048576;

  f32x4 acc[2][2];
#pragma unroll
  for (int i = 0; i < 2; ++i)
#pragma unroll
    for (int j = 0; j < 2; ++j) acc[i][j] = f32x4{0.f, 0.f, 0.f, 0.f};

  const int wm = (w & 3) * 32;
  const int wn = (w >> 2) * 32;
  const int fr = lane & 15;
  const int kq = (lane >> 4) * 8;

  for (int k0 = 0; k0 < 256; k0 += 64) {
    const int r = t >> 2, c4 = (t & 3) * 16;
    float4 a4[4];
#pragma unroll
    for (int i = 0; i < 4; ++i)
      a4[i] = *(const float4*)(Ab + (size_t)r * 256 + k0 + c4 + 4 * i);
    const int kr = t >> 3, nc = (t & 7) * 8;
    float4 b4[2];
#pragma unroll
    for (int i = 0; i < 2; ++i)
      b4[i] = *(const float4*)(Bb + (size_t)(k0 + kr) * 4096 + n0 + nc + 4 * i);
    __syncthreads();
#pragma unroll
    for (int i = 0; i < 4; ++i) {
      bf16x4 v = {(bf16_t)a4[i].x, (bf16_t)a4[i].y, (bf16_t)a4[i].z, (bf16_t)a4[i].w};
      *(bf16x4*)&As[r][c4 + 4 * i] = v;
    }
#pragma unroll
    for (int i = 0; i < 2; ++i) {
      Bs[nc + 4 * i + 0][kr] = (bf16_t)b4[i].x;
      Bs[nc + 4 * i + 1][kr] = (bf16_t)b4[i].y;
      Bs[nc + 4 * i + 2][kr] = (bf16_t)b4[i].z;
      Bs[nc + 4 * i + 3][kr] = (bf16_t)b4[i].w;
    }
    __syncthreads();
#pragma unroll
    for (int kk = 0; kk < 64; kk += 32) {
      bf16x8 af[2], bg[2];
#pragma unroll
      for (int i = 0; i < 2; ++i) {
        af[i] = *(const bf16x8*)&As[wm + 16 * i + fr][kk + kq];
        bg[i] = *(const bf16x8*)&Bs[wn + 16 * i + fr][kk + kq];
      }
#pragma unroll
      for (int i = 0; i < 2; ++i)
#pragma unroll
        for (int j = 0; j < 2; ++j)
          acc[i][j] = __builtin_amdgcn_mfma_f32_16x16x32_bf16(af[i], bg[j], acc[i][j], 0, 0, 0);
    }
    __syncthreads();
  }

  bf16_t* Cb = C + (size_t)b * 524288;
  const int rh = (lane >> 4) * 4, col = lane & 15;
#pragma unroll
  for (int i = 0; i < 2; ++i)
#pragma unroll
    for (int j = 0; j < 2; ++j)
#pragma unroll
      for (int rr = 0; rr < 4; ++rr)
        Cb[(size_t)(wm + 16 * i + rh + rr) * 4096 + n0 + wn + 16 * j + col] =
            (bf16_t)acc[i][j][rr];
}

// ---------------- fused partF reduce + bias + silu -> fusb, then LN -> lnf ---
// one block per row (256 rows); thread t owns cols [t*16, t*16+16)
__global__ __launch_bounds__(256) void red_ln(
    const bf16_t* __restrict__ partF, int S,
    const float* __restrict__ bias,
    const float* __restrict__ g, const float* __restrict__ bta,
    bf16_t* __restrict__ fusb, bf16_t* __restrict__ lnf) {
  __shared__ float tmp[4];
  const int row = blockIdx.x;
  const int t = threadIdx.x;
  const long i0 = t * 16;
  float a[16];
#pragma unroll
  for (int j = 0; j < 16; ++j) a[j] = 0.f;
  for (int s = 0; s < S; ++s) {
    const bf16_t* p = partF + (size_t)s * 1048576 + (size_t)row * 4096 + i0;
    bf16x8 v0 = *(const bf16x8*)(p);
    bf16x8 v1 = *(const bf16x8*)(p + 8);
#pragma unroll
    for (int j = 0; j < 8; ++j) { a[j] += (float)v0[j]; a[8 + j] += (float)v1[j]; }
  }
#pragma unroll
  for (int j = 0; j < 16; ++j) a[j] = silu_f(a[j] + bias[i0 + j]);
  // write fusb
  {
    bf16x8 o0, o1;
#pragma unroll
    for (int j = 0; j < 8; ++j) { o0[j] = (bf16_t)a[j]; o1[j] = (bf16_t)a[8 + j]; }
    *(bf16x8*)(fusb + (size_t)row * 4096 + i0) = o0;
    *(bf16x8*)(fusb + (size_t)row * 4096 + i0 + 8) = o1;
  }
  // LN over the row
  float s1 = 0.f, s2 = 0.f;
#pragma unroll
  for (int j = 0; j < 16; ++j) { s1 += a[j]; s2 += a[j] * a[j]; }
  s1 = block_sum(s1, tmp);
  s2 = block_sum(s2, tmp);
  const float mu = s1 / 4096.f;
  const float inv = rsqrtf(s2 / 4096.f - mu * mu + EPS);
  bf16x8 o0, o1;
#pragma unroll
  for (int j = 0; j < 8; ++j) {
    o0[j] = (bf16_t)((a[j] - mu) * inv * g[i0 + j] + bta[i0 + j]);
    o1[j] = (bf16_t)((a[8 + j] - mu) * inv * g[i0 + 8 + j] + bta[i0 + 8 + j]);
  }
  *(bf16x8*)(lnf + (size_t)row * 4096 + i0) = o0;
  *(bf16x8*)(lnf + (size_t)row * 4096 + i0 + 8) = o1;
}

// ---------------- fused partQ-reduce + LayerNorm(concat(refv, qb)) -> bf16 ---
__global__ __launch_bounds__(256) void ln_fuse(
    const float* __restrict__ refv, const bf16_t* __restrict__ partQ, int S,
    const float* __restrict__ g, const float* __restrict__ bta, bf16_t* __restrict__ Y) {
  __shared__ float tmp[4];
  const int row = blockIdx.x;
  const int t = threadIdx.x;
  const long i0 = t * 16;
  float q[16];
#pragma unroll
  for (int j = 0; j < 16; ++j) q[j] = 0.f;
  for (int s = 0; s < S; ++s) {
    const bf16_t* p = partQ + (size_t)s * 1048576 + (size_t)row * 4096 + i0;
    bf16x8 v0 = *(const bf16x8*)(p);
    bf16x8 v1 = *(const bf16x8*)(p + 8);
#pragma unroll
    for (int j = 0; j < 8; ++j) { q[j] += (float)v0[j]; q[8 + j] += (float)v1[j]; }
  }
  const float* xr = refv + (size_t)row * 4096 + i0;
  float r[16];
#pragma unroll
  for (int j = 0; j < 4; ++j) {
    float4 v = *(const float4*)(xr + 4 * j);
    r[4 * j] = v.x; r[4 * j + 1] = v.y; r[4 * j + 2] = v.z; r[4 * j + 3] = v.w;
  }
  float s1 = 0.f, s2 = 0.f;
#pragma unroll
  for (int j = 0; j < 16; ++j) { s1 += r[j] + q[j]; s2 += r[j] * r[j] + q[j] * q[j]; }
  s1 = block_sum(s1, tmp);
  s2 = block_sum(s2, tmp);
  const float mu = s1 / 8192.f;
  const float inv = rsqrtf(s2 / 8192.f - mu * mu + EPS);
  bf16_t* y = Y + (size_t)row * 8192;
  bf16x8 o0, o1;
#pragma unroll
  for (int j = 0; j < 8; ++j) {
    o0[j] = (bf16_t)((r[j] - mu) * inv * g[i0 + j] + bta[i0 + j]);
    o1[j] = (bf16_t)((r[8 + j] - mu) * inv * g[i0 + 8 + j] + bta[i0 + 8 + j]);
  }
  *(bf16x8*)(y + i0) = o0;
  *(bf16x8*)(y + i0 + 8) = o1;
#pragma unroll
  for (int j = 0; j < 8; ++j) {
    o0[j] = (bf16_t)((q[j] - mu) * inv * g[4096 + i0 + j] + bta[4096 + i0 + j]);
    o1[j] = (bf16_t)((q[8 + j] - mu) * inv * g[4096 + i0 + 8 + j] + bta[4096 + i0 + 8 + j]);
  }
  *(bf16x8*)(y + 4096 + i0) = o0;
  *(bf16x8*)(y + 4096 + i0 + 8) = o1;
}

// ---------------- fused part8-reduce + QW ----------------
__global__ __launch_bounds__(256) void qw_fuse(
    const float* __restrict__ part8, const float* __restrict__ kW, float* __restrict__ QW) {
  __shared__ float q[256];
  const int bk = blockIdx.x;
  const int c = threadIdx.x;
  float sq = 0.f;
#pragma unroll
  for (int s = 0; s < 8; ++s) sq += part8[(size_t)s * 65536 + (size_t)bk * 256 + c];
  q[c] = 0.125f * sq;
  __syncthreads();
#pragma unroll
  for (int h = 0; h < 4; ++h) {
    float s = 0.f;
#pragma unroll 8
    for (int d = 0; d < 64; ++d)
      s += q[(h << 6) + d] * kW[(size_t)(((h << 6) + d) << 8) + c];
    QW[((size_t)(bk * 4 + h) << 8) + c] = s;
  }
}

// ---------------- fused conv1(4->4,silu) + conv2(4->1) + bilinear up ----------
__global__ __launch_bounds__(256) void conv_fused(
    const bf16_t* __restrict__ X, const float* __restrict__ W1,
    const float* __restrict__ B1, const float* __restrict__ W2,
    const float* __restrict__ B2, float* __restrict__ O) {
  __shared__ bf16_t lg[16384];
  __shared__ bf16_t mid[16384];
  __shared__ float lg64[4096];
  __shared__ float wsh[180];
  const int t = threadIdx.x;
  const size_t base = (size_t)blockIdx.x * 16384;
#pragma unroll
  for (int i = 0; i < 8; ++i) {
    int o = (i * 256 + t) * 8;
    *(bf16x8*)&lg[o] = *(const bf16x8*)(X + base + o);
  }
  if (t < 144) wsh[t] = W1[t];
  else if (t < 180) wsh[t] = W2[t - 144];
  __syncthreads();
  const int px0 = (t & 15) * 4, py0 = (t >> 4) * 4;
  {
    float acc1[4][16];
#pragma unroll
    for (int oc = 0; oc < 4; ++oc) {
      float bb = B1[oc];
#pragma unroll
      for (int p = 0; p < 16; ++p) acc1[oc][p] = bb;
    }
#pragma unroll
    for (int c = 0; c < 4; ++c) {
      float p[6][6];
#pragma unroll
      for (int yy = 0; yy < 6; ++yy) {
        int gy = py0 + yy - 1;
#pragma unroll
        for (int xx = 0; xx < 6; ++xx) {
          int gx = px0 + xx - 1;
          p[yy][xx] = ((unsigned)gy < 64u && (unsigned)gx < 64u)
                          ? (float)lg[c * 4096 + gy * 64 + gx] : 0.f;
        }
      }
#pragma unroll
      for (int oc = 0; oc < 4; ++oc) {
        float wr[9];
#pragma unroll
        for (int k = 0; k < 9; ++k) wr[k] = wsh[oc * 36 + c * 9 + k];
#pragma unroll
        for (int y = 0; y < 4; ++y)
#pragma unroll
          for (int x = 0; x < 4; ++x)
            acc1[oc][y * 4 + x] +=
                wr[0] * p[y][x] + wr[1] * p[y][x + 1] + wr[2] * p[y][x + 2]
              + wr[3] * p[y + 1][x] + wr[4] * p[y + 1][x + 1] + wr[5] * p[y + 1][x + 2]
              + wr[6] * p[y + 2][x] + wr[7] * p[y + 2][x + 1] + wr[8] * p[y + 2][x + 2];
      }
    }
#pragma unroll
    for (int oc = 0; oc < 4; ++oc)
#pragma unroll
      for (int y = 0; y < 4; ++y) {
        bf16x4 o;
#pragma unroll
        for (int x = 0; x < 4; ++x) o[x] = (bf16_t)silu_f(acc1[oc][y * 4 + x]);
        *(bf16x4*)&mid[oc * 4096 + (py0 + y) * 64 + px0] = o;
      }
  }
  __syncthreads();
  {
    float acc2[16];
    float bb = B2[0];
#pragma unroll
    for (int p = 0; p < 16; ++p) acc2[p] = bb;
#pragma unroll
    for (int c = 0; c < 4; ++c) {
      float p[6][6];
#pragma unroll
      for (int yy = 0; yy < 6; ++yy) {
        int gy = py0 + yy - 1;
#pragma unroll
        for (int xx = 0; xx < 6; ++xx) {
          int gx = px0 + xx - 1;
          p[yy][xx] = ((unsigned)gy < 64u && (unsigned)gx < 64u)
                          ? (float)mid[c * 4096 + gy * 64 + gx] : 0.f;
        }
      }
      float wr[9];
#pragma unroll
      for (int k = 0; k < 9; ++k) wr[k] = wsh[144 + c * 9 + k];
#pragma unroll
      for (int y = 0; y < 4; ++y)
#pragma unroll
        for (int x = 0; x < 4; ++x)
          acc2[y * 4 + x] +=
              wr[0] * p[y][x] + wr[1] * p[y][x + 1] + wr[2] * p[y][x + 2]
            + wr[3] * p[y + 1][x] + wr[4] * p[y + 1][x + 1] + wr[5] * p[y + 1][x + 2]
            + wr[6] * p[y + 2][x] + wr[7] * p[y + 2][x + 1] + wr[8] * p[y + 2][x + 2];
    }
#pragma unroll
    for (int y = 0; y < 4; ++y)
#pragma unroll
      for (int x = 0; x < 4; ++x) lg64[(py0 + y) * 64 + px0 + x] = acc2[y * 4 + x];
  }
  __syncthreads();
  float* Ob = O + (size_t)blockIdx.x * 65536;
  for (int rr = 0; rr < 64; ++rr) {
    int p4 = rr * 256 + t;
    int oy = p4 >> 6, ox0 = (p4 & 63) * 4;
    float sy = oy * 0.25f - 0.375f;
    int y0 = (int)floorf(sy);
    float wy = sy - (float)y0;
    int y1 = min(y0 + 1, 63); y0 = max(y0, 0);
    const float* r0 = &lg64[y0 * 64];
    const float* r1 = &lg64[y1 * 64];
    float4 o;
#pragma unroll
    for (int q = 0; q < 4; ++q) {
      int ox = ox0 + q;
      float sx = ox * 0.25f - 0.375f;
      int x0 = (int)floorf(sx);
      float wx = sx - (float)x0;
      int x1 = min(x0 + 1, 63); x0 = max(x0, 0);
      float v0 = r0[x0] + wx * (r0[x1] - r0[x0]);
      float v1 = r1[x0] + wx * (r1[x1] - r1[x0]);
      ((float*)&o)[q] = v0 + wy * (v1 - v0);
    }
    *(float4*)(Ob + oy * 256 + ox0) = o;
  }
}

// ---------------- fused partC reduce + bias + silu + dot(w2) + b2 ------------
// one block per row (256 rows); thread t owns cols [t*8, t*8+8) of 2048
__global__ __launch_bounds__(256) void conf_fuse(
    const bf16_t* __restrict__ partC, int S,
    const float* __restrict__ cb1, const float* __restrict__ w2,
    const float* __restrict__ b2, float* __restrict__ out) {
  __shared__ float tmp[4];
  const int row = blockIdx.x;
  const int t = threadIdx.x;
  const long i0 = t * 8;
  float a[8];
#pragma unroll
  for (int j = 0; j < 8; ++j) a[j] = 0.f;
  for (int s = 0; s < S; ++s) {
    bf16x8 v = *(const bf16x8*)(partC + (size_t)s * 524288 + (size_t)row * 2048 + i0);
#pragma unroll
    for (int j = 0; j < 8; ++j) a[j] += (float)v[j];
  }
  float dot = 0.f;
#pragma unroll
  for (int j = 0; j < 8; ++j) dot += silu_f(a[j] + cb1[i0 + j]) * w2[i0 + j];
  dot = block_sum(dot, tmp);
  if (t == 0) out[row] = dot + b2[0];
}

extern "C" void kernel_launch(void* const* d_in, const int* in_sizes, int n_in,
                              void* d_out, int out_size, void* d_ws, size_t ws_size,
                              hipStream_t stream) {
  const float* img    = (const float*)d_in[0];
  const float* refv   = (const float*)d_in[1];
  const float* qs     = (const float*)d_in[2];
  const float* qpw    = (const float*)d_in[3];
  const float* kpw    = (const float*)d_in[4];
  const float* fw1    = (const float*)d_in[5];
  const float* fb1    = (const float*)d_in[6];
  const float* fw2    = (const float*)d_in[7];
  const float* fb2    = (const float*)d_in[8];
  const float* qbw    = (const float*)d_in[9];
  const float* rlg    = (const float*)d_in[10];
  const float* rlb    = (const float*)d_in[11];
  const float* rlw    = (const float*)d_in[12];
  const float* rlbias = (const float*)d_in[13];
  const float* clg    = (const float*)d_in[14];
  const float* clb    = (const float*)d_in[15];
  const float* cw1    = (const float*)d_in[16];
  const float* cb1    = (const float*)d_in[17];
  const float* cw2    = (const float*)d_in[18];
  const float* cb2    = (const float*)d_in[19];
  float* out = (float*)d_out;
  char* W = (char*)d_ws;

  // --- workspace layout (bytes); disjoint lifetimes per region ---
  bf16_t* partQ = (bf16_t*)(W + 0);          // 16.8 MB steps 1-2
  bf16_t* partF = (bf16_t*)(W + 0);          // 16.8 MB steps 3-4 (partQ dead)
  bf16_t* l64hb = (bf16_t*)(W + 0);          //  8.4 MB steps 7-8 (partF dead)
  bf16_t* partC = (bf16_t*)(W + 0);          // 16.8 MB steps 9-10 (l64hb dead)
  bf16_t* catln = (bf16_t*)(W + 16777216);   //  4.2 MB steps 2-3
  bf16_t* fusb  = (bf16_t*)(W + 20971520);   //  2.1 MB steps 4-5
  bf16_t* lnf   = (bf16_t*)(W + 23068672);   //  2.1 MB steps 4-9
  float*  part8 = (float*)(W + 25165824);    //  2.1 MB steps 5-6
  float*  QW    = (float*)(W + 27262976);    //  1.1 MB steps 6-7

  dim3 b256(256);

  // 1. qb GEMM (split-K x8): partQ[s] = qs @ qbw^T chunk
  gemm_wide_s<<<dim3(32, 8), dim3(1024), 0, stream>>>(qs, qbw, partQ, 4096, 512, 64);
  // 2. catln = LN(concat(refv, sum partQ)) -> bf16
  ln_fuse<<<dim3(256), b256, 0, stream>>>(refv, partQ, 8, rlg, rlb, catln);
  // 3. fused GEMM (split-K x8, global_load_lds): partF[s] = catln @ rlw^T chunk
  gemm_gll<<<dim3(32, 8), dim3(1024), 0, stream>>>(catln, rlw, partF, 4096, 8192, 1024);
  // 4. fusb = silu(sum partF + bias); lnf = LN(fusb)   (single fused pass)
  red_ln<<<dim3(256), b256, 0, stream>>>(partF, 8, rlbias, clg, clb, fusb, lnf);
  // 5. qproj GEMM (split-K x8): part8[s] = fusb @ qpw^T chunk
  gemm_small<<<dim3(4, 4, 8), b256, 0, stream>>>(fusb, qpw, part8, 256, 256, 4096, 512, 8);
  // 6. QW = per-head (0.125 * sum part8) @ k_proj
  qw_fuse<<<dim3(256), b256, 0, stream>>>(part8, kpw, QW);
  // 7. logits (full-M): l64hb[b] = QW_b @ img_b
  gemm_attn<<<dim3(64, 8), dim3(512), 0, stream>>>(QW, img, l64hb);
  // 8. out = upsample(conv2(silu(conv1(l64hb))))
  conv_fused<<<dim3(256), b256, 0, stream>>>(l64hb, fw1, fb1, fw2, fb2, out);
  // 9. cfh GEMM (split-K x16, full CU count): partC[s] = lnf @ cw1^T chunk
  gemm_gll<<<dim3(16, 16), dim3(1024), 0, stream>>>(lnf, cw1, partC, 2048, 4096, 256);
  // 10. conf out = silu(sum partC + cb1) . w2 + b2   (single fused pass)
  conf_fuse<<<dim3(256), b256, 0, stream>>>(partC, 16, cb1, cw2, cb2, out + 16777216);
}